// Round 1
// baseline (4562.154 us; speedup 1.0000x reference)
//
#include <hip/hip_runtime.h>
#include <stdint.h>

#define BB 2
#define SS 2048
#define DD 1024
#define HH 16
#define HDD 64
#define MEMM 512
#define KTOT 2560   // MEMM + SS
#define QT 16       // q rows per attention workgroup

// ---------- helpers ----------
__device__ __forceinline__ float bf2f(uint16_t u) {
    return __uint_as_float(((uint32_t)u) << 16);
}
__device__ __forceinline__ uint16_t f2bf(float f) {
    uint32_t u = __float_as_uint(f);
    uint32_t r = (u + 0x7FFFu + ((u >> 16) & 1u)) >> 16;
    return (uint16_t)r;
}
__device__ __forceinline__ uint32_t mapkey(uint16_t u) {
    return (u & 0x8000u) ? (uint32_t)(0xFFFFu ^ (uint32_t)u)
                         : (uint32_t)((uint32_t)u | 0x8000u);
}
__device__ __forceinline__ uint16_t unmapkey(uint32_t k) {
    return (k & 0x8000u) ? (uint16_t)(k ^ 0x8000u) : (uint16_t)(0xFFFFu ^ k);
}

// ---------- generic tiled f32 GEMM: C[M=4096][N=1024] = A @ W + bias ----------
// mode 0: plain row-major out[m*DD+n]
// mode 1: Q layout  out[((b*HH+h)*SS + s)*HDD + d]
// mode 2: KV-concat out[((b*HH+h)*KTOT + MEMM + s)*HDD + d]
__global__ __launch_bounds__(256) void gemm_kernel(
    const float* __restrict__ A, const float* __restrict__ W,
    const float* __restrict__ bias, float* __restrict__ out, int mode)
{
    __shared__ __align__(16) float As[16][68];
    __shared__ __align__(16) float Bs[16][68];
    const int tid = threadIdx.x;
    const int tx = tid & 15, ty = tid >> 4;
    const int rowBase = blockIdx.y * 64, colBase = blockIdx.x * 64;
    const int aRow = tid >> 2, aK4 = (tid & 3) * 4;
    const int bK = tid >> 4, bN4 = (tid & 15) * 4;

    float acc[4][4];
#pragma unroll
    for (int i = 0; i < 4; ++i)
#pragma unroll
        for (int j = 0; j < 4; ++j) acc[i][j] = 0.f;

    for (int kt = 0; kt < DD; kt += 16) {
        float4 av = *(const float4*)&A[(rowBase + aRow) * DD + kt + aK4];
        float4 bv = *(const float4*)&W[(kt + bK) * DD + colBase + bN4];
        As[aK4 + 0][aRow] = av.x;
        As[aK4 + 1][aRow] = av.y;
        As[aK4 + 2][aRow] = av.z;
        As[aK4 + 3][aRow] = av.w;
        *(float4*)&Bs[bK][bN4] = bv;
        __syncthreads();
#pragma unroll
        for (int kk = 0; kk < 16; ++kk) {
            float4 a4 = *(const float4*)&As[kk][ty * 4];
            float4 b4 = *(const float4*)&Bs[kk][tx * 4];
            float aa[4] = {a4.x, a4.y, a4.z, a4.w};
            float bb[4] = {b4.x, b4.y, b4.z, b4.w};
#pragma unroll
            for (int i = 0; i < 4; ++i)
#pragma unroll
                for (int j = 0; j < 4; ++j) acc[i][j] += aa[i] * bb[j];
        }
        __syncthreads();
    }

#pragma unroll
    for (int i = 0; i < 4; ++i) {
        int m = rowBase + ty * 4 + i;
        int b = m >> 11, s = m & (SS - 1);
#pragma unroll
        for (int j = 0; j < 4; ++j) {
            int n = colBase + tx * 4 + j;
            float v = acc[i][j] + bias[n];
            if (mode == 0) {
                out[m * DD + n] = v;
            } else {
                int h = n >> 6, d = n & 63;
                if (mode == 1)
                    out[((b * HH + h) * SS + s) * HDD + d] = v;
                else
                    out[((b * HH + h) * KTOT + MEMM + s) * HDD + d] = v;
            }
        }
    }
}

// ---------- past copy + new_k/new_v extraction ----------
__global__ __launch_bounds__(256) void copy_kv_kernel(
    const float* __restrict__ past_k, const float* __restrict__ past_v,
    float* __restrict__ kc, float* __restrict__ vc,
    float* __restrict__ nk_out, float* __restrict__ nv_out)
{
    int idx = blockIdx.x * 256 + threadIdx.x;   // covers BB*HH*MEMM*HDD = 1048576
    int bh = idx >> 15;                          // MEMM*HDD = 32768
    int rem = idx & 32767;
    int kcbase = bh * (KTOT * HDD);
    kc[kcbase + rem] = past_k[idx];
    vc[kcbase + rem] = past_v[idx];
    // tail of concat cache (positions 2048..2559), written by the K/V GEMMs
    nk_out[idx] = kc[kcbase + (KTOT - MEMM) * HDD + rem];
    nv_out[idx] = vc[kcbase + (KTOT - MEMM) * HDD + rem];
}

// ---------- attention: scores + quantile-threshold + softmax + PV ----------
__global__ __launch_bounds__(256) void attn_kernel(
    const float* __restrict__ q_ws, const float* __restrict__ kc,
    const float* __restrict__ vc, const int* __restrict__ amask,
    float* __restrict__ attn_out)
{
    __shared__ __align__(16) uint16_t sc[QT][KTOT];   // 81920 B, scores then weights (bf16)
    __shared__ __align__(16) float Qs[QT][HDD];       // 4096 B
    __shared__ __align__(16) char uni[20480];         // union: Kst / hist / kvred
    __shared__ float red[256];
    __shared__ float rowmax[QT], rowsum[QT], thrA[QT], thrB[QT];
    __shared__ uint32_t selbin[QT], selrem[QT];

    float (*Kst)[65]        = (float (*)[65])uni;          // 64 x 65 x4 = 16640 B
    uint32_t (*hist)[256]   = (uint32_t (*)[256])uni;      // 16 x 256 x4 = 16384 B
    float (*kvred)[HDD][5]  = (float (*)[HDD][5])uni;      // 16 x 64 x 5 x4 = 20480 B

    const int tid = threadIdx.x;
    const int qt = blockIdx.x, h = blockIdx.y, b = blockIdx.z;
    const int q0 = qt * QT;
    const int bh = b * HH + h;
    const float* kbase = kc + (size_t)bh * KTOT * HDD;
    const float* vbase = vc + (size_t)bh * KTOT * HDD;

    // ---- load Q tile ----
    {
        const float* qbase = q_ws + ((size_t)bh * SS + q0) * HDD;
        for (int t = tid; t < QT * HDD; t += 256)
            Qs[t >> 6][t & 63] = qbase[t];
    }

    // ---- scores: sc[r][k] = bf16( 0.125 * dot(Q[r], K[k]) ) ----
    const int iLane = tid & 63, rb = tid >> 6;
    for (int kt = 0; kt < KTOT; kt += 64) {
        __syncthreads();  // Qs ready (1st iter) / previous compute done with Kst
        for (int t = tid; t < 64 * HDD; t += 256) {
            int i = t >> 6, d = t & 63;
            Kst[d][i] = kbase[(kt + i) * HDD + d];
        }
        __syncthreads();
        float a0 = 0.f, a1 = 0.f, a2 = 0.f, a3 = 0.f;
#pragma unroll
        for (int c = 0; c < 16; ++c) {
            float k0 = Kst[4 * c + 0][iLane];
            float k1 = Kst[4 * c + 1][iLane];
            float k2 = Kst[4 * c + 2][iLane];
            float k3 = Kst[4 * c + 3][iLane];
            float4 q0v = *(const float4*)&Qs[rb * 4 + 0][4 * c];
            a0 += q0v.x * k0 + q0v.y * k1 + q0v.z * k2 + q0v.w * k3;
            float4 q1v = *(const float4*)&Qs[rb * 4 + 1][4 * c];
            a1 += q1v.x * k0 + q1v.y * k1 + q1v.z * k2 + q1v.w * k3;
            float4 q2v = *(const float4*)&Qs[rb * 4 + 2][4 * c];
            a2 += q2v.x * k0 + q2v.y * k1 + q2v.z * k2 + q2v.w * k3;
            float4 q3v = *(const float4*)&Qs[rb * 4 + 3][4 * c];
            a3 += q3v.x * k0 + q3v.y * k1 + q3v.z * k2 + q3v.w * k3;
        }
        sc[rb * 4 + 0][kt + iLane] = f2bf(a0 * 0.125f);
        sc[rb * 4 + 1][kt + iLane] = f2bf(a1 * 0.125f);
        sc[rb * 4 + 2][kt + iLane] = f2bf(a2 * 0.125f);
        sc[rb * 4 + 3][kt + iLane] = f2bf(a3 * 0.125f);
    }
    __syncthreads();

    // ---- row max ----
    {
        int r = tid >> 4, l = tid & 15;
        float m = -1e30f;
        for (int i = l; i < KTOT; i += 16) m = fmaxf(m, bf2f(sc[r][i]));
        red[tid] = m;
        __syncthreads();
        if (tid < QT) {
            float mm = red[tid * 16];
            for (int t = 1; t < 16; ++t) mm = fmaxf(mm, red[tid * 16 + t]);
            rowmax[tid] = mm;
        }
        __syncthreads();
    }

    // ---- row-parallel radix select: ranks 255 (pass 0) and 256 (pass 1) ----
    for (int pass = 0; pass < 2; ++pass) {
        const uint32_t krank = 255u + (uint32_t)pass;
        for (int t = tid; t < QT * 256; t += 256) ((uint32_t*)uni)[t] = 0u;
        __syncthreads();
        for (int i = tid; i < KTOT; i += 256) {
#pragma unroll
            for (int r = 0; r < QT; ++r) {
                uint32_t key = mapkey(sc[r][i]);
                atomicAdd(&hist[r][key >> 8], 1u);
            }
        }
        __syncthreads();
        if (tid < QT) {
            uint32_t cum = 0;
            for (int bn = 0; bn < 256; ++bn) {
                uint32_t c = hist[tid][bn];
                if (cum + c > krank) { selbin[tid] = (uint32_t)bn; selrem[tid] = krank - cum; break; }
                cum += c;
            }
        }
        __syncthreads();
        for (int t = tid; t < QT * 256; t += 256) ((uint32_t*)uni)[t] = 0u;
        __syncthreads();
        for (int i = tid; i < KTOT; i += 256) {
#pragma unroll
            for (int r = 0; r < QT; ++r) {
                uint32_t key = mapkey(sc[r][i]);
                if ((key >> 8) == selbin[r]) atomicAdd(&hist[r][key & 255u], 1u);
            }
        }
        __syncthreads();
        if (tid < QT) {
            uint32_t cum = 0, rem = selrem[tid];
            for (int bn = 0; bn < 256; ++bn) {
                uint32_t c = hist[tid][bn];
                if (cum + c > rem) {
                    uint32_t key16 = (selbin[tid] << 8) | (uint32_t)bn;
                    float v = bf2f(unmapkey(key16));
                    if (pass == 0) thrA[tid] = v; else thrB[tid] = v;
                    break;
                }
                cum += c;
            }
        }
        __syncthreads();
    }

    // ---- weights: sc[r][i] <- bf16( keep ? exp(s - max) : 0 ), rowsum ----
    {
        int r = tid >> 4, l = tid & 15;
        float thr = thrA[r] + 0.9f * (thrB[r] - thrA[r]);
        float mx = rowmax[r];
        const int* am = amask + b * SS;
        float sum = 0.f;
        for (int i = l; i < KTOT; i += 16) {
            float s = bf2f(sc[r][i]);
            bool keep = (s >= thr);
            if (i >= MEMM) keep = keep && (am[i - MEMM] != 0);
            float w = keep ? __expf(s - mx) : 0.f;
            uint16_t wb = f2bf(w);
            sc[r][i] = wb;
            sum += bf2f(wb);
        }
        red[tid] = sum;
        __syncthreads();
        if (tid < QT) {
            float ssum = 0.f;
            for (int t = 0; t < 16; ++t) ssum += red[tid * 16 + t];
            rowsum[tid] = ssum;
        }
        __syncthreads();
    }

    // ---- PV: out[r][d] = sum_k w[r][k] * V[k][d] / rowsum[r] ----
    {
        const int d = tid & 63, g = tid >> 6;
        float acc[QT];
#pragma unroll
        for (int r = 0; r < QT; ++r) acc[r] = 0.f;
        for (int k = g * 640; k < (g + 1) * 640; k += 8) {
            float vv[8];
#pragma unroll
            for (int j = 0; j < 8; ++j) vv[j] = vbase[(k + j) * HDD + d];
#pragma unroll
            for (int r = 0; r < QT; ++r) {
                const uint4 wv = *(const uint4*)&sc[r][k];
                acc[r] += __uint_as_float(wv.x << 16) * vv[0]
                        + __uint_as_float(wv.x & 0xFFFF0000u) * vv[1]
                        + __uint_as_float(wv.y << 16) * vv[2]
                        + __uint_as_float(wv.y & 0xFFFF0000u) * vv[3]
                        + __uint_as_float(wv.z << 16) * vv[4]
                        + __uint_as_float(wv.z & 0xFFFF0000u) * vv[5]
                        + __uint_as_float(wv.w << 16) * vv[6]
                        + __uint_as_float(wv.w & 0xFFFF0000u) * vv[7];
            }
        }
        __syncthreads();  // hist/Kst phase fully done; uni now reused as kvred
#pragma unroll
        for (int r = 0; r < QT; ++r) kvred[r][d][g] = acc[r];
        __syncthreads();
        for (int t = tid; t < QT * HDD; t += 256) {
            int r = t >> 6, dd = t & 63;
            float s = kvred[r][dd][0] + kvred[r][dd][1] + kvred[r][dd][2] + kvred[r][dd][3];
            float val = s / rowsum[r];
            attn_out[((size_t)(b * SS) + q0 + r) * DD + h * HDD + dd] = val;
        }
    }
}

extern "C" void kernel_launch(void* const* d_in, const int* in_sizes, int n_in,
                              void* d_out, int out_size, void* d_ws, size_t ws_size,
                              hipStream_t stream)
{
    const float* hidden = (const float*)d_in[0];
    const int*   amask  = (const int*)d_in[1];
    const float* past_k = (const float*)d_in[2];
    const float* past_v = (const float*)d_in[3];
    const float* Wq = (const float*)d_in[4];
    const float* bq = (const float*)d_in[5];
    const float* Wk = (const float*)d_in[6];
    const float* bk = (const float*)d_in[7];
    const float* Wv = (const float*)d_in[8];
    const float* bv = (const float*)d_in[9];
    const float* Wo = (const float*)d_in[10];
    const float* bo = (const float*)d_in[11];

    float* out    = (float*)d_out;
    float* nk_out = out + (size_t)BB * SS * DD;           // 4,194,304
    float* nv_out = nk_out + (size_t)BB * HH * MEMM * HDD; // +1,048,576

    float* q_ws    = (float*)d_ws;                         // 4,194,304 f
    float* kc      = q_ws + (size_t)BB * HH * SS * HDD;    // 5,242,880 f
    float* vc      = kc + (size_t)BB * HH * KTOT * HDD;    // 5,242,880 f
    float* attn_ws = vc + (size_t)BB * HH * KTOT * HDD;    // 4,194,304 f
    // total workspace: 75,497,472 bytes

    dim3 blk(256);
    dim3 ggrid(DD / 64, (BB * SS) / 64);   // (16, 64)

    gemm_kernel<<<ggrid, blk, 0, stream>>>(hidden, Wq, bq, q_ws, 1);
    gemm_kernel<<<ggrid, blk, 0, stream>>>(hidden, Wk, bk, kc, 2);
    gemm_kernel<<<ggrid, blk, 0, stream>>>(hidden, Wv, bv, vc, 2);
    copy_kv_kernel<<<dim3(4096), blk, 0, stream>>>(past_k, past_v, kc, vc, nk_out, nv_out);
    attn_kernel<<<dim3(SS / QT, HH, BB), blk, 0, stream>>>(q_ws, kc, vc, amask, attn_ws);
    gemm_kernel<<<ggrid, blk, 0, stream>>>(attn_ws, Wo, bo, out, 0);
}

// Round 2
// 1496.039 us; speedup vs baseline: 3.0495x; 3.0495x over previous
//
#include <hip/hip_runtime.h>
#include <stdint.h>

typedef unsigned short ushort_t;
typedef __attribute__((ext_vector_type(8))) short bf16x8;
typedef __attribute__((ext_vector_type(4))) float f32x4;

#define BB 2
#define SS 2048
#define DD 1024
#define HH 16
#define HDD 64
#define MEMM 512
#define KTOT 2560   // MEMM + SS
#define NROWS (BB*HH*SS)   // 65536 score rows

// ---------- helpers ----------
__device__ __forceinline__ float bf2f(uint32_t u) {
    return __uint_as_float(u << 16);
}
__device__ __forceinline__ ushort_t f2bf(float f) {
    uint32_t u = __float_as_uint(f);
    uint32_t r = (u + 0x7FFFu + ((u >> 16) & 1u)) >> 16;
    return (ushort_t)r;
}
// monotone map bf16 bits -> u16 order key
__device__ __forceinline__ uint32_t mapkey(uint32_t u) {
    return (u & 0x8000u) ? (0xFFFFu ^ u) : (u | 0x8000u);
}
__device__ __forceinline__ uint32_t unmapkey(uint32_t k) {
    return (k & 0x8000u) ? (k ^ 0x8000u) : (0xFFFFu ^ k);
}

// ---------- f32 tiled GEMM: C[4096][1024] = A @ W + bias ----------
// mode 0: f32 row-major outf[m*DD+n]
// mode 1: bf16 Q layout outbf[((b*HH+h)*SS+s)*HDD+d]
// mode 2: bf16 KV layout outbf[((b*HH+h)*KTOT+MEMM+s)*HDD+d]; if s>=SS-MEMM
//         also f32 outf[((b*HH+h)*MEMM+(s-(SS-MEMM)))*HDD+d]  (new_k/new_v)
__global__ __launch_bounds__(256) void gemm_kernel(
    const float* __restrict__ A, const float* __restrict__ W,
    const float* __restrict__ bias, float* __restrict__ outf,
    ushort_t* __restrict__ outbf, int mode)
{
    __shared__ __align__(16) float As[16][68];
    __shared__ __align__(16) float Bs[16][68];
    const int tid = threadIdx.x;
    const int tx = tid & 15, ty = tid >> 4;
    const int rowBase = blockIdx.y * 64, colBase = blockIdx.x * 64;
    const int aRow = tid >> 2, aK4 = (tid & 3) * 4;
    const int bK = tid >> 4, bN4 = (tid & 15) * 4;

    float acc[4][4];
#pragma unroll
    for (int i = 0; i < 4; ++i)
#pragma unroll
        for (int j = 0; j < 4; ++j) acc[i][j] = 0.f;

    for (int kt = 0; kt < DD; kt += 16) {
        float4 av = *(const float4*)&A[(rowBase + aRow) * DD + kt + aK4];
        float4 bv = *(const float4*)&W[(kt + bK) * DD + colBase + bN4];
        As[aK4 + 0][aRow] = av.x;
        As[aK4 + 1][aRow] = av.y;
        As[aK4 + 2][aRow] = av.z;
        As[aK4 + 3][aRow] = av.w;
        *(float4*)&Bs[bK][bN4] = bv;
        __syncthreads();
#pragma unroll
        for (int kk = 0; kk < 16; ++kk) {
            float4 a4 = *(const float4*)&As[kk][ty * 4];
            float4 b4 = *(const float4*)&Bs[kk][tx * 4];
            float aa[4] = {a4.x, a4.y, a4.z, a4.w};
            float bb[4] = {b4.x, b4.y, b4.z, b4.w};
#pragma unroll
            for (int i = 0; i < 4; ++i)
#pragma unroll
                for (int j = 0; j < 4; ++j) acc[i][j] += aa[i] * bb[j];
        }
        __syncthreads();
    }

#pragma unroll
    for (int i = 0; i < 4; ++i) {
        int m = rowBase + ty * 4 + i;
        int b = m >> 11, s = m & (SS - 1);
#pragma unroll
        for (int j = 0; j < 4; ++j) {
            int n = colBase + tx * 4 + j;
            float v = acc[i][j] + bias[n];
            if (mode == 0) {
                outf[(size_t)m * DD + n] = v;
            } else {
                int h = n >> 6, d = n & 63;
                size_t bh = (size_t)b * HH + h;
                if (mode == 1) {
                    outbf[(bh * SS + s) * HDD + d] = f2bf(v);
                } else {
                    outbf[(bh * KTOT + MEMM + s) * HDD + d] = f2bf(v);
                    if (s >= SS - MEMM)
                        outf[(bh * MEMM + (s - (SS - MEMM))) * HDD + d] = v;
                }
            }
        }
    }
}

// ---------- cast past_k/past_v f32 -> bf16 cache heads ----------
__global__ __launch_bounds__(256) void cast_past_kernel(
    const float* __restrict__ pk, const float* __restrict__ pv,
    ushort_t* __restrict__ kbf, ushort_t* __restrict__ vbf)
{
    int idx = blockIdx.x * 256 + threadIdx.x;  // BB*HH*MEMM*HDD = 1048576
    int bh = idx >> 15;                        // MEMM*HDD = 32768
    int rem = idx & 32767;
    size_t dst = (size_t)bh * KTOT * HDD + rem;
    kbf[dst] = f2bf(pk[idx]);
    vbf[dst] = f2bf(pv[idx]);
}

// ---------- transpose V: vbf[bh][k][d] -> vt[bh][d][k] ----------
__global__ __launch_bounds__(256) void transpose_v_kernel(
    const ushort_t* __restrict__ vbf, ushort_t* __restrict__ vt)
{
    __shared__ ushort_t T[64][72];
    const int k0 = blockIdx.x * 64;
    const int bh = blockIdx.y;
    const int t = threadIdx.x;
    const int rr = t >> 3, cc = (t & 7) * 8;
#pragma unroll
    for (int p = 0; p < 2; ++p) {
        int kk = p * 32 + rr;
        *(uint4*)&T[kk][cc] =
            *(const uint4*)(vbf + ((size_t)bh * KTOT + k0 + kk) * HDD + cc);
    }
    __syncthreads();
#pragma unroll
    for (int p = 0; p < 2; ++p) {
        int d = p * 32 + rr;
        ushort_t tmp[8];
#pragma unroll
        for (int j = 0; j < 8; ++j) tmp[j] = T[cc + j][d];
        *(uint4*)(vt + ((size_t)bh * HDD + d) * KTOT + k0 + cc) = *(uint4*)tmp;
    }
}

// ---------- scores: sbuf[lbh][q][k] = bf16(0.125 * Q.K), MFMA, no LDS ----------
__global__ __launch_bounds__(256) void score_kernel(
    const ushort_t* __restrict__ qbf, const ushort_t* __restrict__ kbf,
    ushort_t* __restrict__ sbuf, int bh0)
{
    const int w = threadIdx.x >> 6, lane = threadIdx.x & 63;
    const int kt = blockIdx.x, qt = blockIdx.y;
    const int lbh = blockIdx.z, bh = bh0 + lbh;
    const int m0 = qt * 64 + w * 16;
    const int row16 = lane & 15, quad = lane >> 4;

    const ushort_t* qrow = qbf + ((size_t)bh * SS + m0 + row16) * HDD + quad * 8;
    bf16x8 a0 = *(const bf16x8*)qrow;
    bf16x8 a1 = *(const bf16x8*)(qrow + 32);
    const ushort_t* kbase = kbf + ((size_t)bh * KTOT + kt * 256 + row16) * HDD + quad * 8;
    ushort_t* sb = sbuf + ((size_t)lbh * SS + m0) * KTOT + kt * 256;

#pragma unroll
    for (int nt = 0; nt < 16; ++nt) {
        const ushort_t* kr = kbase + nt * 16 * HDD;
        bf16x8 b0 = *(const bf16x8*)kr;
        bf16x8 b1 = *(const bf16x8*)(kr + 32);
        f32x4 acc = {0.f, 0.f, 0.f, 0.f};
        acc = __builtin_amdgcn_mfma_f32_16x16x32_bf16(a0, b0, acc, 0, 0, 0);
        acc = __builtin_amdgcn_mfma_f32_16x16x32_bf16(a1, b1, acc, 0, 0, 0);
#pragma unroll
        for (int r = 0; r < 4; ++r) {
            int mrow = quad * 4 + r;
            sb[(size_t)mrow * KTOT + nt * 16 + row16] = f2bf(acc[r] * 0.125f);
        }
    }
}

// ---------- wave helpers ----------
__device__ __forceinline__ uint32_t wave_iscan(uint32_t x, int lane) {
#pragma unroll
    for (int d = 1; d < 64; d <<= 1) {
        uint32_t t = __shfl_up(x, d, 64);
        if (lane >= d) x += t;
    }
    return x;
}
// select index of rank R from a 256-bin wave-shared histogram
__device__ __forceinline__ void select_from_hist(
    volatile uint32_t* hist, uint32_t R, int lane, uint32_t* bin_out, uint32_t* rem_out)
{
    uint32_t c[4];
    uint32_t s = 0;
#pragma unroll
    for (int i = 0; i < 4; ++i) { c[i] = hist[lane * 4 + i]; s += c[i]; }
    uint32_t incl = wave_iscan(s, lane);
    uint32_t excl = incl - s;
    uint64_t bal = __ballot(incl > R);
    int fl = __ffsll((unsigned long long)bal) - 1;
    uint32_t exf = __shfl(excl, fl, 64);
    uint32_t c0 = __shfl(c[0], fl, 64), c1 = __shfl(c[1], fl, 64);
    uint32_t c2 = __shfl(c[2], fl, 64), c3 = __shfl(c[3], fl, 64);
    uint32_t cc[4] = {c0, c1, c2, c3};
    uint32_t cum = exf, bin = fl * 4, rem = 0;
#pragma unroll
    for (int i = 0; i < 4; ++i) {
        if (cum + cc[i] > R) { bin = fl * 4 + i; rem = R - cum; break; }
        cum += cc[i];
    }
    *bin_out = bin;
    *rem_out = rem;
}

// ---------- per-row quantile (ranks 255,256) + rowmax; 1 wave per row ----------
__global__ __launch_bounds__(256) void quant_kernel(
    const ushort_t* __restrict__ sbuf, float* __restrict__ thr_out,
    float* __restrict__ max_out, int bh0)
{
    __shared__ uint32_t histA[4][256];
    __shared__ uint32_t histB[4][256];
    const int w = threadIdx.x >> 6, lane = threadIdx.x & 63;
    const int lrow = blockIdx.x * 4 + w;
    const size_t grow = (size_t)bh0 * SS + lrow;
    const ushort_t* src = sbuf + (size_t)lrow * KTOT;

    // load 40 keys (mapped) into regs, track max
    uint32_t key[40];
    uint32_t maxkey = 0;
#pragma unroll
    for (int c = 0; c < 5; ++c) {
        uint4 p = *(const uint4*)(src + c * 512 + lane * 8);
        uint32_t u[8] = {p.x & 0xFFFFu, p.x >> 16, p.y & 0xFFFFu, p.y >> 16,
                         p.z & 0xFFFFu, p.z >> 16, p.w & 0xFFFFu, p.w >> 16};
#pragma unroll
        for (int j = 0; j < 8; ++j) {
            uint32_t k = mapkey(u[j]);
            key[c * 8 + j] = k;
            maxkey = max(maxkey, k);
        }
    }
#pragma unroll
    for (int d = 1; d < 64; d <<= 1)
        maxkey = max(maxkey, (uint32_t)__shfl_xor(maxkey, d, 64));

    // pass 1: top-byte histogram
    for (int i = 0; i < 4; ++i) histA[w][lane * 4 + i] = 0u;
    __syncthreads();
#pragma unroll
    for (int i = 0; i < 40; ++i) atomicAdd(&histA[w][key[i] >> 8], 1u);
    __syncthreads();
    uint32_t binA, remA, binB, remB;
    select_from_hist(histA[w], 255u, lane, &binA, &remA);
    select_from_hist(histA[w], 256u, lane, &binB, &remB);
    __syncthreads();

    // pass 2: low-byte histograms of the selected top bins
    for (int i = 0; i < 4; ++i) { histA[w][lane * 4 + i] = 0u; histB[w][lane * 4 + i] = 0u; }
    __syncthreads();
#pragma unroll
    for (int i = 0; i < 40; ++i) {
        uint32_t k = key[i];
        uint32_t top = k >> 8;
        if (top == binA) atomicAdd(&histA[w][k & 255u], 1u);
        if (top == binB) atomicAdd(&histB[w][k & 255u], 1u);
    }
    __syncthreads();
    uint32_t lowA, rA, lowB, rB;
    select_from_hist(histA[w], remA, lane, &lowA, &rA);
    select_from_hist(histB[w], remB, lane, &lowB, &rB);

    if (lane == 0) {
        float thrA = bf2f(unmapkey((binA << 8) | lowA));
        float thrB = bf2f(unmapkey((binB << 8) | lowB));
        thr_out[grow] = thrA + 0.9f * (thrB - thrA);
        max_out[grow] = bf2f(unmapkey(maxkey));
    }
    __syncthreads();  // keep block in lockstep before exit (uniform)
}

// ---------- softmax weights + PV via MFMA ----------
__global__ __launch_bounds__(256) void pv_kernel(
    const ushort_t* __restrict__ sbuf, const ushort_t* __restrict__ vt,
    const float* __restrict__ thr_arr, const float* __restrict__ max_arr,
    const int* __restrict__ amask, float* __restrict__ attn_out, int bh0)
{
    __shared__ __align__(16) ushort_t Wt[64][264];
    __shared__ float psum_red[64][33];
    __shared__ float thr_s[64], max_s[64], rsum[64];

    const int tid = threadIdx.x;
    const int qt = blockIdx.x;
    const int lbh = blockIdx.y, bh = bh0 + lbh;
    const int b = bh >> 4, h = bh & 15;
    const int q0 = qt * 64;
    const int lane = tid & 63, w = tid >> 6;
    const int colg = tid & 31, rowg = tid >> 5;
    const int row16 = lane & 15, quad = lane >> 4;

    if (tid < 64) {
        thr_s[tid] = thr_arr[(size_t)bh * SS + q0 + tid];
        max_s[tid] = max_arr[(size_t)bh * SS + q0 + tid];
    }
    __syncthreads();

    float psum[8];
#pragma unroll
    for (int i = 0; i < 8; ++i) psum[i] = 0.f;
    f32x4 acc[4];
#pragma unroll
    for (int i = 0; i < 4; ++i) acc[i] = (f32x4){0.f, 0.f, 0.f, 0.f};

    const ushort_t* srow_base = sbuf + ((size_t)lbh * SS + q0) * KTOT;
    const int* am = amask + b * SS;

    for (int kt = 0; kt < 10; ++kt) {
        // stage: scores -> thresholded exp weights (bf16) in LDS
#pragma unroll
        for (int rg = 0; rg < 8; ++rg) {
            int r = rg * 8 + rowg;
            uint4 p = *(const uint4*)(srow_base + (size_t)r * KTOT + kt * 256 + colg * 8);
            float tr = thr_s[r], mx = max_s[r];
            uint32_t u[8] = {p.x & 0xFFFFu, p.x >> 16, p.y & 0xFFFFu, p.y >> 16,
                             p.z & 0xFFFFu, p.z >> 16, p.w & 0xFFFFu, p.w >> 16};
            ushort_t wb[8];
            float ps = 0.f;
#pragma unroll
            for (int j = 0; j < 8; ++j) {
                float s = bf2f(u[j]);
                bool keep = (s >= tr);
                if (kt >= 2) {
                    int col = kt * 256 + colg * 8 + j;
                    keep = keep && (am[col - MEMM] != 0);
                }
                float wv = keep ? __expf(s - mx) : 0.f;
                ushort_t wbb = f2bf(wv);
                wb[j] = wbb;
                ps += bf2f((uint32_t)wbb);
            }
            psum[rg] += ps;
            uint4 q;
            q.x = (uint32_t)wb[0] | ((uint32_t)wb[1] << 16);
            q.y = (uint32_t)wb[2] | ((uint32_t)wb[3] << 16);
            q.z = (uint32_t)wb[4] | ((uint32_t)wb[5] << 16);
            q.w = (uint32_t)wb[6] | ((uint32_t)wb[7] << 16);
            *(uint4*)&Wt[r][colg * 8] = q;
        }
        __syncthreads();
        // MFMA: O[16w..16w+16][0..64] += W_tile @ V_tile
#pragma unroll
        for (int kk = 0; kk < 8; ++kk) {
            bf16x8 a = *(const bf16x8*)&Wt[w * 16 + row16][kk * 32 + quad * 8];
#pragma unroll
            for (int nt = 0; nt < 4; ++nt) {
                const ushort_t* vp = vt + ((size_t)bh * HDD + nt * 16 + row16) * KTOT
                                   + kt * 256 + kk * 32 + quad * 8;
                bf16x8 bfr = *(const bf16x8*)vp;
                acc[nt] = __builtin_amdgcn_mfma_f32_16x16x32_bf16(a, bfr, acc[nt], 0, 0, 0);
            }
        }
        __syncthreads();
    }

    // row sums
#pragma unroll
    for (int rg = 0; rg < 8; ++rg) psum_red[rg * 8 + rowg][colg] = psum[rg];
    __syncthreads();
    if (tid < 64) {
        float s = 0.f;
        for (int i = 0; i < 32; ++i) s += psum_red[tid][i];
        rsum[tid] = s;
    }
    __syncthreads();

    // write O / rowsum, f32, layout (b, s, h*64+d)
#pragma unroll
    for (int nt = 0; nt < 4; ++nt) {
#pragma unroll
        for (int r = 0; r < 4; ++r) {
            int mr = w * 16 + quad * 4 + r;
            float val = acc[nt][r] / rsum[mr];
            attn_out[((size_t)b * SS + q0 + mr) * DD + h * HDD + nt * 16 + row16] = val;
        }
    }
}

extern "C" void kernel_launch(void* const* d_in, const int* in_sizes, int n_in,
                              void* d_out, int out_size, void* d_ws, size_t ws_size,
                              hipStream_t stream)
{
    const float* hidden = (const float*)d_in[0];
    const int*   amask  = (const int*)d_in[1];
    const float* past_k = (const float*)d_in[2];
    const float* past_v = (const float*)d_in[3];
    const float* Wq = (const float*)d_in[4];
    const float* bq = (const float*)d_in[5];
    const float* Wk = (const float*)d_in[6];
    const float* bk = (const float*)d_in[7];
    const float* Wv = (const float*)d_in[8];
    const float* bv = (const float*)d_in[9];
    const float* Wo = (const float*)d_in[10];
    const float* bo = (const float*)d_in[11];

    float* out    = (float*)d_out;
    float* nk_out = out + (size_t)BB * SS * DD;
    float* nv_out = nk_out + (size_t)BB * HH * MEMM * HDD;

    // workspace carve-up (all offsets 256B-aligned)
    char* base = (char*)d_ws;
    size_t off = 0;
    auto alloc = [&](size_t bytes) {
        char* p = base + off;
        off += (bytes + 255) & ~(size_t)255;
        return p;
    };
    ushort_t* q_bf = (ushort_t*)alloc((size_t)BB * HH * SS * HDD * 2);       // 8 MB
    ushort_t* kbf  = (ushort_t*)alloc((size_t)BB * HH * KTOT * HDD * 2);     // 10 MB
    ushort_t* vbf  = (ushort_t*)alloc((size_t)BB * HH * KTOT * HDD * 2);     // 10 MB
    ushort_t* vt   = (ushort_t*)alloc((size_t)BB * HH * HDD * KTOT * 2);     // 10 MB
    float* attn_ws = (float*)alloc((size_t)BB * SS * DD * 4);                // 16 MB
    float* thr_arr = (float*)alloc((size_t)NROWS * 4);                       // 256 KB
    float* max_arr = (float*)alloc((size_t)NROWS * 4);                       // 256 KB
    size_t fixed = off;
    const size_t sbuf_full = (size_t)BB * HH * SS * KTOT * 2;                // 335.5 MB
    int nchunks = 32;
    for (int c = 1; c <= 32; c <<= 1) {
        if (fixed + sbuf_full / c + 256 <= ws_size) { nchunks = c; break; }
    }
    ushort_t* sbuf = (ushort_t*)alloc(sbuf_full / nchunks);
    const int bhpc = (BB * HH) / nchunks;

    dim3 blk(256);
    dim3 ggrid(DD / 64, (BB * SS) / 64);

    gemm_kernel<<<ggrid, blk, 0, stream>>>(hidden, Wq, bq, nullptr, q_bf, 1);
    gemm_kernel<<<ggrid, blk, 0, stream>>>(hidden, Wk, bk, nk_out, kbf, 2);
    gemm_kernel<<<ggrid, blk, 0, stream>>>(hidden, Wv, bv, nv_out, vbf, 2);
    cast_past_kernel<<<dim3(4096), blk, 0, stream>>>(past_k, past_v, kbf, vbf);
    transpose_v_kernel<<<dim3(KTOT / 64, BB * HH), blk, 0, stream>>>(vbf, vt);

    for (int ci = 0; ci < nchunks; ++ci) {
        int bh0 = ci * bhpc;
        score_kernel<<<dim3(KTOT / 256, SS / 64, bhpc), blk, 0, stream>>>(q_bf, kbf, sbuf, bh0);
        quant_kernel<<<dim3(bhpc * (SS / 4)), blk, 0, stream>>>(sbuf, thr_arr, max_arr, bh0);
        pv_kernel<<<dim3(SS / 64, bhpc), blk, 0, stream>>>(sbuf, vt, thr_arr, max_arr,
                                                           amask, attn_ws, bh0);
    }
    gemm_kernel<<<ggrid, blk, 0, stream>>>(attn_ws, Wo, bo, out, nullptr, 0);
}

// Round 4
// 1179.797 us; speedup vs baseline: 3.8669x; 1.2680x over previous
//
#include <hip/hip_runtime.h>
#include <stdint.h>

typedef unsigned short ushort_t;
typedef __attribute__((ext_vector_type(8))) short bf16x8;
typedef __attribute__((ext_vector_type(4))) float f32x4;

#define BB 2
#define SS 2048
#define DD 1024
#define HH 16
#define HDD 64
#define MEMM 512
#define KTOT 2560   // MEMM + SS
#define NROWS (BB*HH*SS)   // 65536 score rows

// ---------- helpers ----------
__device__ __forceinline__ float bf2f(uint32_t u) {
    return __uint_as_float(u << 16);
}
__device__ __forceinline__ ushort_t f2bf(float f) {
    uint32_t u = __float_as_uint(f);
    uint32_t r = (u + 0x7FFFu + ((u >> 16) & 1u)) >> 16;
    return (ushort_t)r;
}
__device__ __forceinline__ uint32_t mapkey(uint32_t u) {
    return (u & 0x8000u) ? (0xFFFFu ^ u) : (u | 0x8000u);
}
__device__ __forceinline__ uint32_t unmapkey(uint32_t k) {
    return (k & 0x8000u) ? (k ^ 0x8000u) : (0xFFFFu ^ k);
}

// ---------- cast hidden f32 -> bf16 ----------
__global__ __launch_bounds__(256) void cast_hidden_kernel(
    const float* __restrict__ h, ushort_t* __restrict__ hb)
{
    size_t i0 = ((size_t)blockIdx.x * 256 + threadIdx.x) * 16;  // 4M elems / 16
    ushort_t o[16];
#pragma unroll
    for (int j = 0; j < 4; ++j) {
        float4 v = *(const float4*)&h[i0 + j * 4];
        o[j * 4 + 0] = f2bf(v.x); o[j * 4 + 1] = f2bf(v.y);
        o[j * 4 + 2] = f2bf(v.z); o[j * 4 + 3] = f2bf(v.w);
    }
    *(uint4*)&hb[i0] = *(uint4*)&o[0];
    *(uint4*)&hb[i0 + 8] = *(uint4*)&o[8];
}

// ---------- transpose+cast weights: W[k][n] f32 -> Wt[n][k] bf16 ----------
__global__ __launch_bounds__(256) void transw_kernel(
    const float* __restrict__ Wq, const float* __restrict__ Wk,
    const float* __restrict__ Wv, const float* __restrict__ Wo,
    ushort_t* __restrict__ WtAll)
{
    __shared__ ushort_t T[64][66];
    const int z = blockIdx.z;
    const float* W = (z == 0) ? Wq : (z == 1) ? Wk : (z == 2) ? Wv : Wo;
    ushort_t* dst = WtAll + (size_t)z * DD * DD;
    const int k0 = blockIdx.x * 64, n0 = blockIdx.y * 64;
    const int t = threadIdx.x;
    const int kk = t >> 2, c4 = (t & 3) * 16;
#pragma unroll
    for (int j = 0; j < 4; ++j) {
        float4 v = *(const float4*)&W[(size_t)(k0 + kk) * DD + n0 + c4 + j * 4];
        T[kk][c4 + j * 4 + 0] = f2bf(v.x);
        T[kk][c4 + j * 4 + 1] = f2bf(v.y);
        T[kk][c4 + j * 4 + 2] = f2bf(v.z);
        T[kk][c4 + j * 4 + 3] = f2bf(v.w);
    }
    __syncthreads();
    const int nn = t >> 2, kc = (t & 3) * 16;
    ushort_t tmp[16];
#pragma unroll
    for (int j = 0; j < 16; ++j) tmp[j] = T[kc + j][nn];
    *(uint4*)&dst[(size_t)(n0 + nn) * DD + k0 + kc] = *(uint4*)&tmp[0];
    *(uint4*)&dst[(size_t)(n0 + nn) * DD + k0 + kc + 8] = *(uint4*)&tmp[8];
}

// ---------- fused QKV bf16 MFMA GEMM ----------
// grid (24, 64): blockIdx.x>>3 selects Q/K/V; tile 64m x 128n per block (wave=16m x 128n)
__global__ __launch_bounds__(256) void qkv_gemm_kernel(
    const ushort_t* __restrict__ hb, const ushort_t* __restrict__ WtAll,
    const float* __restrict__ bq, const float* __restrict__ bk, const float* __restrict__ bv,
    ushort_t* __restrict__ q_bf, ushort_t* __restrict__ kbf, ushort_t* __restrict__ vbf,
    float* __restrict__ nk, float* __restrict__ nv)
{
    const int w = threadIdx.x >> 6, lane = threadIdx.x & 63;
    const int row16 = lane & 15, quad = lane >> 4;
    const int sel = blockIdx.x >> 3;
    const int n0 = (blockIdx.x & 7) * 128;
    const int m0 = blockIdx.y * 64 + w * 16;
    const ushort_t* Wt = WtAll + (size_t)sel * DD * DD;
    const float* bias = (sel == 0) ? bq : (sel == 1) ? bk : bv;

    const ushort_t* arow = hb + (size_t)(m0 + row16) * DD + quad * 8;
    const ushort_t* brow = Wt + (size_t)(n0 + row16) * DD + quad * 8;

    f32x4 acc[8];
#pragma unroll
    for (int i = 0; i < 8; ++i) acc[i] = (f32x4){0.f, 0.f, 0.f, 0.f};

    bf16x8 a_cur = *(const bf16x8*)arow;
    bf16x8 b_cur[8];
#pragma unroll
    for (int nt = 0; nt < 8; ++nt) b_cur[nt] = *(const bf16x8*)(brow + (size_t)nt * 16 * DD);

    for (int k = 32; k < DD; k += 32) {
        bf16x8 a_nxt = *(const bf16x8*)(arow + k);
        bf16x8 b_nxt[8];
#pragma unroll
        for (int nt = 0; nt < 8; ++nt)
            b_nxt[nt] = *(const bf16x8*)(brow + (size_t)nt * 16 * DD + k);
#pragma unroll
        for (int nt = 0; nt < 8; ++nt)
            acc[nt] = __builtin_amdgcn_mfma_f32_16x16x32_bf16(a_cur, b_cur[nt], acc[nt], 0, 0, 0);
        a_cur = a_nxt;
#pragma unroll
        for (int nt = 0; nt < 8; ++nt) b_cur[nt] = b_nxt[nt];
    }
#pragma unroll
    for (int nt = 0; nt < 8; ++nt)
        acc[nt] = __builtin_amdgcn_mfma_f32_16x16x32_bf16(a_cur, b_cur[nt], acc[nt], 0, 0, 0);

#pragma unroll
    for (int nt = 0; nt < 8; ++nt) {
#pragma unroll
        for (int r = 0; r < 4; ++r) {
            int m = m0 + quad * 4 + r;
            int n = n0 + nt * 16 + row16;
            float v = acc[nt][r] + bias[n];
            int b = m >> 11, s = m & (SS - 1);
            int h = n >> 6, d = n & 63;
            size_t bh = (size_t)b * HH + h;
            if (sel == 0) {
                q_bf[(bh * SS + s) * HDD + d] = f2bf(v);
            } else {
                ushort_t* dst = (sel == 1) ? kbf : vbf;
                dst[(bh * KTOT + MEMM + s) * HDD + d] = f2bf(v);
                if (s >= SS - MEMM) {
                    float* nf = (sel == 1) ? nk : nv;
                    nf[(bh * MEMM + (s - (SS - MEMM))) * HDD + d] = v;
                }
            }
        }
    }
}

// ---------- O-projection bf16 MFMA GEMM: out f32 = attn_bf @ WoT + bo ----------
__global__ __launch_bounds__(256) void o_gemm_kernel(
    const ushort_t* __restrict__ abf, const ushort_t* __restrict__ WtAll,
    const float* __restrict__ bo, float* __restrict__ outf)
{
    const int w = threadIdx.x >> 6, lane = threadIdx.x & 63;
    const int row16 = lane & 15, quad = lane >> 4;
    const int n0 = blockIdx.x * 128;
    const int m0 = blockIdx.y * 64 + w * 16;
    const ushort_t* Wt = WtAll + (size_t)3 * DD * DD;

    const ushort_t* arow = abf + (size_t)(m0 + row16) * DD + quad * 8;
    const ushort_t* brow = Wt + (size_t)(n0 + row16) * DD + quad * 8;

    f32x4 acc[8];
#pragma unroll
    for (int i = 0; i < 8; ++i) acc[i] = (f32x4){0.f, 0.f, 0.f, 0.f};

    bf16x8 a_cur = *(const bf16x8*)arow;
    bf16x8 b_cur[8];
#pragma unroll
    for (int nt = 0; nt < 8; ++nt) b_cur[nt] = *(const bf16x8*)(brow + (size_t)nt * 16 * DD);

    for (int k = 32; k < DD; k += 32) {
        bf16x8 a_nxt = *(const bf16x8*)(arow + k);
        bf16x8 b_nxt[8];
#pragma unroll
        for (int nt = 0; nt < 8; ++nt)
            b_nxt[nt] = *(const bf16x8*)(brow + (size_t)nt * 16 * DD + k);
#pragma unroll
        for (int nt = 0; nt < 8; ++nt)
            acc[nt] = __builtin_amdgcn_mfma_f32_16x16x32_bf16(a_cur, b_cur[nt], acc[nt], 0, 0, 0);
        a_cur = a_nxt;
#pragma unroll
        for (int nt = 0; nt < 8; ++nt) b_cur[nt] = b_nxt[nt];
    }
#pragma unroll
    for (int nt = 0; nt < 8; ++nt)
        acc[nt] = __builtin_amdgcn_mfma_f32_16x16x32_bf16(a_cur, b_cur[nt], acc[nt], 0, 0, 0);

#pragma unroll
    for (int nt = 0; nt < 8; ++nt) {
#pragma unroll
        for (int r = 0; r < 4; ++r) {
            int m = m0 + quad * 4 + r;
            int n = n0 + nt * 16 + row16;
            outf[(size_t)m * DD + n] = acc[nt][r] + bo[n];
        }
    }
}

// ---------- cast past_k/past_v f32 -> bf16 cache heads ----------
__global__ __launch_bounds__(256) void cast_past_kernel(
    const float* __restrict__ pk, const float* __restrict__ pv,
    ushort_t* __restrict__ kbf, ushort_t* __restrict__ vbf)
{
    int idx = blockIdx.x * 256 + threadIdx.x;  // BB*HH*MEMM*HDD = 1048576
    int bh = idx >> 15;
    int rem = idx & 32767;
    size_t dst = (size_t)bh * KTOT * HDD + rem;
    kbf[dst] = f2bf(pk[idx]);
    vbf[dst] = f2bf(pv[idx]);
}

// ---------- transpose V: vbf[bh][k][d] -> vt[bh][d][k] ----------
__global__ __launch_bounds__(256) void transpose_v_kernel(
    const ushort_t* __restrict__ vbf, ushort_t* __restrict__ vt)
{
    __shared__ ushort_t T[64][72];
    const int k0 = blockIdx.x * 64;
    const int bh = blockIdx.y;
    const int t = threadIdx.x;
    const int rr = t >> 3, cc = (t & 7) * 8;
#pragma unroll
    for (int p = 0; p < 2; ++p) {
        int kk = p * 32 + rr;
        *(uint4*)&T[kk][cc] =
            *(const uint4*)(vbf + ((size_t)bh * KTOT + k0 + kk) * HDD + cc);
    }
    __syncthreads();
#pragma unroll
    for (int p = 0; p < 2; ++p) {
        int d = p * 32 + rr;
        ushort_t tmp[8];
#pragma unroll
        for (int j = 0; j < 8; ++j) tmp[j] = T[cc + j][d];
        *(uint4*)(vt + ((size_t)bh * HDD + d) * KTOT + k0 + cc) = *(uint4*)tmp;
    }
}

// ---------- scores: MFMA + LDS transpose + coalesced store ----------
__global__ __launch_bounds__(256) void score_kernel(
    const ushort_t* __restrict__ qbf, const ushort_t* __restrict__ kbf,
    ushort_t* __restrict__ sbuf, int bh0)
{
    __shared__ __align__(16) ushort_t Ts[64][264];
    const int w = threadIdx.x >> 6, lane = threadIdx.x & 63;
    const int kt = blockIdx.x, qt = blockIdx.y;
    const int lbh = blockIdx.z, bh = bh0 + lbh;
    const int m0 = qt * 64 + w * 16;
    const int row16 = lane & 15, quad = lane >> 4;

    const ushort_t* qrow = qbf + ((size_t)bh * SS + m0 + row16) * HDD + quad * 8;
    bf16x8 a0 = *(const bf16x8*)qrow;
    bf16x8 a1 = *(const bf16x8*)(qrow + 32);
    const ushort_t* kbase = kbf + ((size_t)bh * KTOT + kt * 256 + row16) * HDD + quad * 8;

#pragma unroll
    for (int nt = 0; nt < 16; ++nt) {
        const ushort_t* kr = kbase + (size_t)nt * 16 * HDD;
        bf16x8 b0 = *(const bf16x8*)kr;
        bf16x8 b1 = *(const bf16x8*)(kr + 32);
        f32x4 acc = {0.f, 0.f, 0.f, 0.f};
        acc = __builtin_amdgcn_mfma_f32_16x16x32_bf16(a0, b0, acc, 0, 0, 0);
        acc = __builtin_amdgcn_mfma_f32_16x16x32_bf16(a1, b1, acc, 0, 0, 0);
#pragma unroll
        for (int r = 0; r < 4; ++r)
            Ts[w * 16 + quad * 4 + r][nt * 16 + row16] = f2bf(acc[r] * 0.125f);
    }
    __syncthreads();
    // coalesced store: thread t -> row t>>2, 64-col chunk (t&3)*64
    const int r = threadIdx.x >> 2, c0 = (threadIdx.x & 3) * 64;
    ushort_t* dst = sbuf + ((size_t)lbh * SS + qt * 64 + r) * KTOT + kt * 256 + c0;
#pragma unroll
    for (int j = 0; j < 8; ++j)
        *(uint4*)&dst[j * 8] = *(const uint4*)&Ts[r][c0 + j * 8];
}

// ---------- wave helpers ----------
__device__ __forceinline__ uint32_t wave_iscan(uint32_t x, int lane) {
#pragma unroll
    for (int d = 1; d < 64; d <<= 1) {
        uint32_t t = __shfl_up(x, d, 64);
        if (lane >= d) x += t;
    }
    return x;
}
__device__ __forceinline__ void select_from_hist(
    volatile uint32_t* hist, uint32_t R, int lane, uint32_t* bin_out, uint32_t* rem_out)
{
    uint32_t c[4];
    uint32_t s = 0;
#pragma unroll
    for (int i = 0; i < 4; ++i) { c[i] = hist[lane * 4 + i]; s += c[i]; }
    uint32_t incl = wave_iscan(s, lane);
    uint32_t excl = incl - s;
    uint64_t bal = __ballot(incl > R);
    int fl = __ffsll((unsigned long long)bal) - 1;
    uint32_t exf = __shfl(excl, fl, 64);
    uint32_t c0 = __shfl(c[0], fl, 64), c1 = __shfl(c[1], fl, 64);
    uint32_t c2 = __shfl(c[2], fl, 64), c3 = __shfl(c[3], fl, 64);
    uint32_t cc[4] = {c0, c1, c2, c3};
    uint32_t cum = exf, bin = fl * 4, rem = 0;
#pragma unroll
    for (int i = 0; i < 4; ++i) {
        if (cum + cc[i] > R) { bin = fl * 4 + i; rem = R - cum; break; }
        cum += cc[i];
    }
    *bin_out = bin;
    *rem_out = rem;
}

// ---------- per-row quantile (ranks 255,256) + rowmax; 1 wave per row ----------
__global__ __launch_bounds__(256) void quant_kernel(
    const ushort_t* __restrict__ sbuf, float* __restrict__ thr_out,
    float* __restrict__ max_out, int bh0)
{
    __shared__ uint32_t histA[4][256];
    __shared__ uint32_t histB[4][256];
    const int w = threadIdx.x >> 6, lane = threadIdx.x & 63;
    const int lrow = blockIdx.x * 4 + w;
    const size_t grow = (size_t)bh0 * SS + lrow;
    const ushort_t* src = sbuf + (size_t)lrow * KTOT;

    uint32_t key[40];
    uint32_t maxkey = 0;
#pragma unroll
    for (int c = 0; c < 5; ++c) {
        uint4 p = *(const uint4*)(src + c * 512 + lane * 8);
        uint32_t u[8] = {p.x & 0xFFFFu, p.x >> 16, p.y & 0xFFFFu, p.y >> 16,
                         p.z & 0xFFFFu, p.z >> 16, p.w & 0xFFFFu, p.w >> 16};
#pragma unroll
        for (int j = 0; j < 8; ++j) {
            uint32_t k = mapkey(u[j]);
            key[c * 8 + j] = k;
            maxkey = max(maxkey, k);
        }
    }
#pragma unroll
    for (int d = 1; d < 64; d <<= 1)
        maxkey = max(maxkey, (uint32_t)__shfl_xor(maxkey, d, 64));

    for (int i = 0; i < 4; ++i) histA[w][lane * 4 + i] = 0u;
    __syncthreads();
#pragma unroll
    for (int i = 0; i < 40; ++i) atomicAdd(&histA[w][key[i] >> 8], 1u);
    __syncthreads();
    uint32_t binA, remA, binB, remB;
    select_from_hist(histA[w], 255u, lane, &binA, &remA);
    select_from_hist(histA[w], 256u, lane, &binB, &remB);
    __syncthreads();

    for (int i = 0; i < 4; ++i) { histA[w][lane * 4 + i] = 0u; histB[w][lane * 4 + i] = 0u; }
    __syncthreads();
#pragma unroll
    for (int i = 0; i < 40; ++i) {
        uint32_t k = key[i];
        uint32_t top = k >> 8;
        if (top == binA) atomicAdd(&histA[w][k & 255u], 1u);
        if (top == binB) atomicAdd(&histB[w][k & 255u], 1u);
    }
    __syncthreads();
    uint32_t lowA, rA, lowB, rB;
    select_from_hist(histA[w], remA, lane, &lowA, &rA);
    select_from_hist(histB[w], remB, lane, &lowB, &rB);

    if (lane == 0) {
        float thrA = bf2f(unmapkey((binA << 8) | lowA));
        float thrB = bf2f(unmapkey((binB << 8) | lowB));
        thr_out[grow] = thrA + 0.9f * (thrB - thrA);
        max_out[grow] = bf2f(unmapkey(maxkey));
    }
}

// ---------- softmax weights + PV via MFMA (waves split n; prefetched scores) ----------
__global__ __launch_bounds__(256) void pv_kernel(
    const ushort_t* __restrict__ sbuf, const ushort_t* __restrict__ vt,
    const float* __restrict__ thr_arr, const float* __restrict__ max_arr,
    const int* __restrict__ amask, ushort_t* __restrict__ attn_bf, int bh0)
{
    __shared__ __align__(16) ushort_t Wt[64][264];
    __shared__ float psum_red[64][33];
    __shared__ float thr_s[64], max_s[64], rsum[64];

    const int tid = threadIdx.x;
    const int qt = blockIdx.x;
    const int lbh = blockIdx.y, bh = bh0 + lbh;
    const int b = bh >> 4, h = bh & 15;
    const int q0 = qt * 64;
    const int lane = tid & 63, w = tid >> 6;
    const int colg = tid & 31, rowg = tid >> 5;
    const int row16 = lane & 15, quad = lane >> 4;

    if (tid < 64) {
        thr_s[tid] = thr_arr[(size_t)bh * SS + q0 + tid];
        max_s[tid] = max_arr[(size_t)bh * SS + q0 + tid];
    }
    __syncthreads();

    float psum[8];
#pragma unroll
    for (int i = 0; i < 8; ++i) psum[i] = 0.f;
    f32x4 acc[4];
#pragma unroll
    for (int i = 0; i < 4; ++i) acc[i] = (f32x4){0.f, 0.f, 0.f, 0.f};

    const ushort_t* srow = sbuf + ((size_t)lbh * SS + q0) * KTOT;
    const ushort_t* vwave = vt + ((size_t)bh * HDD + w * 16 + row16) * KTOT;
    const int* am = amask + b * SS;

    uint4 p[8];
#pragma unroll
    for (int rg = 0; rg < 8; ++rg)
        p[rg] = *(const uint4*)(srow + (size_t)(rg * 8 + rowg) * KTOT + colg * 8);

    for (int kt = 0; kt < 10; ++kt) {
        // stage: thresholded exp weights (bf16) into LDS
#pragma unroll
        for (int rg = 0; rg < 8; ++rg) {
            int r = rg * 8 + rowg;
            float tr = thr_s[r], mx = max_s[r];
            uint4 pp = p[rg];
            uint32_t u[8] = {pp.x & 0xFFFFu, pp.x >> 16, pp.y & 0xFFFFu, pp.y >> 16,
                             pp.z & 0xFFFFu, pp.z >> 16, pp.w & 0xFFFFu, pp.w >> 16};
            ushort_t wb[8];
            float ps = 0.f;
#pragma unroll
            for (int j = 0; j < 8; ++j) {
                float s = bf2f(u[j]);
                bool keep = (s >= tr);
                if (kt >= 2) {
                    int col = kt * 256 + colg * 8 + j;
                    keep = keep && (am[col - MEMM] != 0);
                }
                float wv = keep ? __expf(s - mx) : 0.f;
                ushort_t wbb = f2bf(wv);
                wb[j] = wbb;
                ps += bf2f((uint32_t)wbb);
            }
            psum[rg] += ps;
            uint4 q;
            q.x = (uint32_t)wb[0] | ((uint32_t)wb[1] << 16);
            q.y = (uint32_t)wb[2] | ((uint32_t)wb[3] << 16);
            q.z = (uint32_t)wb[4] | ((uint32_t)wb[5] << 16);
            q.w = (uint32_t)wb[6] | ((uint32_t)wb[7] << 16);
            *(uint4*)&Wt[r][colg * 8] = q;
        }
        __syncthreads();
        // prefetch next k-tile's scores (overlaps MFMA phase)
        if (kt < 9) {
#pragma unroll
            for (int rg = 0; rg < 8; ++rg)
                p[rg] = *(const uint4*)(srow + (size_t)(rg * 8 + rowg) * KTOT
                                        + (kt + 1) * 256 + colg * 8);
        }
        // MFMA: each wave owns n-tile w (16 cols of V); B loaded once per kk
#pragma unroll
        for (int kk = 0; kk < 8; ++kk) {
            bf16x8 bv = *(const bf16x8*)(vwave + kt * 256 + kk * 32 + quad * 8);
#pragma unroll
            for (int mt = 0; mt < 4; ++mt) {
                bf16x8 a = *(const bf16x8*)&Wt[mt * 16 + row16][kk * 32 + quad * 8];
                acc[mt] = __builtin_amdgcn_mfma_f32_16x16x32_bf16(a, bv, acc[mt], 0, 0, 0);
            }
        }
        __syncthreads();
    }

#pragma unroll
    for (int rg = 0; rg < 8; ++rg) psum_red[rg * 8 + rowg][colg] = psum[rg];
    __syncthreads();
    if (tid < 64) {
        float s = 0.f;
        for (int i = 0; i < 32; ++i) s += psum_red[tid][i];
        rsum[tid] = s;
    }
    __syncthreads();

#pragma unroll
    for (int mt = 0; mt < 4; ++mt) {
#pragma unroll
        for (int r = 0; r < 4; ++r) {
            int m = mt * 16 + quad * 4 + r;
            float val = acc[mt][r] / rsum[m];
            attn_bf[((size_t)b * SS + q0 + m) * DD + h * HDD + w * 16 + row16] = f2bf(val);
        }
    }
}

extern "C" void kernel_launch(void* const* d_in, const int* in_sizes, int n_in,
                              void* d_out, int out_size, void* d_ws, size_t ws_size,
                              hipStream_t stream)
{
    const float* hidden = (const float*)d_in[0];
    const int*   amask  = (const int*)d_in[1];
    const float* past_k = (const float*)d_in[2];
    const float* past_v = (const float*)d_in[3];
    const float* Wq = (const float*)d_in[4];
    const float* bq = (const float*)d_in[5];
    const float* Wk = (const float*)d_in[6];
    const float* bk = (const float*)d_in[7];
    const float* Wv = (const float*)d_in[8];
    const float* bv = (const float*)d_in[9];
    const float* Wo = (const float*)d_in[10];
    const float* bo = (const float*)d_in[11];

    float* out    = (float*)d_out;
    float* nk_out = out + (size_t)BB * SS * DD;
    float* nv_out = nk_out + (size_t)BB * HH * MEMM * HDD;

    char* base = (char*)d_ws;
    size_t off = 0;
    auto alloc = [&](size_t bytes) {
        char* p = base + off;
        off += (bytes + 255) & ~(size_t)255;
        return p;
    };
    ushort_t* hb    = (ushort_t*)alloc((size_t)BB * SS * DD * 2);            // 8 MB
    ushort_t* WtAll = (ushort_t*)alloc((size_t)4 * DD * DD * 2);             // 8 MB
    ushort_t* q_bf  = (ushort_t*)alloc((size_t)BB * HH * SS * HDD * 2);      // 8 MB
    ushort_t* kbf   = (ushort_t*)alloc((size_t)BB * HH * KTOT * HDD * 2);    // 10 MB
    ushort_t* vbf   = (ushort_t*)alloc((size_t)BB * HH * KTOT * HDD * 2);    // 10 MB
    ushort_t* vt    = (ushort_t*)alloc((size_t)BB * HH * HDD * KTOT * 2);    // 10 MB
    ushort_t* abf   = (ushort_t*)alloc((size_t)BB * SS * DD * 2);            // 8 MB
    float* thr_arr  = (float*)alloc((size_t)NROWS * 4);
    float* max_arr  = (float*)alloc((size_t)NROWS * 4);
    size_t fixed = off;
    const size_t sbuf_full = (size_t)BB * HH * SS * KTOT * 2;                // 335.5 MB
    int nchunks = 32;
    for (int c = 1; c <= 32; c <<= 1) {
        if (fixed + sbuf_full / c + 256 <= ws_size) { nchunks = c; break; }
    }
    ushort_t* sbuf = (ushort_t*)alloc(sbuf_full / nchunks);
    const int bhpc = (BB * HH) / nchunks;

    dim3 blk(256);

    cast_hidden_kernel<<<dim3(1024), blk, 0, stream>>>(hidden, hb);
    transw_kernel<<<dim3(16, 16, 4), blk, 0, stream>>>(Wq, Wk, Wv, Wo, WtAll);
    qkv_gemm_kernel<<<dim3(24, 64), blk, 0, stream>>>(hb, WtAll, bq, bk, bv,
                                                      q_bf, kbf, vbf, nk_out, nv_out);
    cast_past_kernel<<<dim3(4096), blk, 0, stream>>>(past_k, past_v, kbf, vbf);
    transpose_v_kernel<<<dim3(KTOT / 64, BB * HH), blk, 0, stream>>>(vbf, vt);

    for (int ci = 0; ci < nchunks; ++ci) {
        int bh0 = ci * bhpc;
        score_kernel<<<dim3(KTOT / 256, SS / 64, bhpc), blk, 0, stream>>>(q_bf, kbf, sbuf, bh0);
        quant_kernel<<<dim3(bhpc * (SS / 4)), blk, 0, stream>>>(sbuf, thr_arr, max_arr, bh0);
        pv_kernel<<<dim3(SS / 64, bhpc), blk, 0, stream>>>(sbuf, vt, thr_arr, max_arr,
                                                           amask, abf, bh0);
    }
    o_gemm_kernel<<<dim3(8, 64), blk, 0, stream>>>(abf, WtAll, bo, out);
}

// Round 5
// 1003.497 us; speedup vs baseline: 4.5463x; 1.1757x over previous
//
#include <hip/hip_runtime.h>
#include <stdint.h>

typedef unsigned short ushort_t;
typedef __attribute__((ext_vector_type(8))) short bf16x8;
typedef __attribute__((ext_vector_type(4))) float f32x4;

#define BB 2
#define SS 2048
#define DD 1024
#define HH 16
#define HDD 64
#define MEMM 512
#define KTOT 2560   // MEMM + SS
#define NROWS (BB*HH*SS)   // 65536 score rows

// ---------- helpers ----------
__device__ __forceinline__ float bf2f(uint32_t u) {
    return __uint_as_float(u << 16);
}
__device__ __forceinline__ ushort_t f2bf(float f) {
    uint32_t u = __float_as_uint(f);
    uint32_t r = (u + 0x7FFFu + ((u >> 16) & 1u)) >> 16;
    return (ushort_t)r;
}
__device__ __forceinline__ uint32_t mapkey(uint32_t u) {
    return (u & 0x8000u) ? (0xFFFFu ^ u) : (u | 0x8000u);
}
__device__ __forceinline__ uint32_t unmapkey(uint32_t k) {
    return (k & 0x8000u) ? (k ^ 0x8000u) : (0xFFFFu ^ k);
}

// ---------- cast hidden f32 -> bf16 ----------
__global__ __launch_bounds__(256) void cast_hidden_kernel(
    const float* __restrict__ h, ushort_t* __restrict__ hb)
{
    size_t i0 = ((size_t)blockIdx.x * 256 + threadIdx.x) * 16;  // 4M elems / 16
    ushort_t o[16];
#pragma unroll
    for (int j = 0; j < 4; ++j) {
        float4 v = *(const float4*)&h[i0 + j * 4];
        o[j * 4 + 0] = f2bf(v.x); o[j * 4 + 1] = f2bf(v.y);
        o[j * 4 + 2] = f2bf(v.z); o[j * 4 + 3] = f2bf(v.w);
    }
    *(uint4*)&hb[i0] = *(uint4*)&o[0];
    *(uint4*)&hb[i0 + 8] = *(uint4*)&o[8];
}

// ---------- transpose+cast weights: W[k][n] f32 -> Wt[n][k] bf16 ----------
__global__ __launch_bounds__(256) void transw_kernel(
    const float* __restrict__ Wq, const float* __restrict__ Wk,
    const float* __restrict__ Wv, const float* __restrict__ Wo,
    ushort_t* __restrict__ WtAll)
{
    __shared__ ushort_t T[64][66];
    const int z = blockIdx.z;
    const float* W = (z == 0) ? Wq : (z == 1) ? Wk : (z == 2) ? Wv : Wo;
    ushort_t* dst = WtAll + (size_t)z * DD * DD;
    const int k0 = blockIdx.x * 64, n0 = blockIdx.y * 64;
    const int t = threadIdx.x;
    const int kk = t >> 2, c4 = (t & 3) * 16;
#pragma unroll
    for (int j = 0; j < 4; ++j) {
        float4 v = *(const float4*)&W[(size_t)(k0 + kk) * DD + n0 + c4 + j * 4];
        T[kk][c4 + j * 4 + 0] = f2bf(v.x);
        T[kk][c4 + j * 4 + 1] = f2bf(v.y);
        T[kk][c4 + j * 4 + 2] = f2bf(v.z);
        T[kk][c4 + j * 4 + 3] = f2bf(v.w);
    }
    __syncthreads();
    const int nn = t >> 2, kc = (t & 3) * 16;
    ushort_t tmp[16];
#pragma unroll
    for (int j = 0; j < 16; ++j) tmp[j] = T[kc + j][nn];
    *(uint4*)&dst[(size_t)(n0 + nn) * DD + k0 + kc] = *(uint4*)&tmp[0];
    *(uint4*)&dst[(size_t)(n0 + nn) * DD + k0 + kc + 8] = *(uint4*)&tmp[8];
}

// ---------- 128x128-tile bf16 MFMA GEMM (m93-style LDS staging) ----------
// A [4096][1024] bf16 row-major; Bt [N][1024] bf16 (n-major). K=1024. BK=32.
// 4 waves: wave w owns 64x64 quadrant (wm=w>>1, wn=w&1), 4x4 accs of 16x16.
// mode 0: outf[m*DD+n] = acc + bq[n]  (bq carries bo)
// mode 1: fused QKV epilogue (N=3072; sel = n>>10)
__global__ __launch_bounds__(256) void gemm128_kernel(
    const ushort_t* __restrict__ A, const ushort_t* __restrict__ Bt, int mode,
    const float* __restrict__ bq, const float* __restrict__ bk, const float* __restrict__ bv,
    float* __restrict__ outf,
    ushort_t* __restrict__ q_bf, ushort_t* __restrict__ kbf, ushort_t* __restrict__ vbf,
    float* __restrict__ nk, float* __restrict__ nv)
{
    __shared__ __align__(16) ushort_t As[128 * 32];
    __shared__ __align__(16) ushort_t Bs[128 * 32];
    const int tid = threadIdx.x;
    const int lane = tid & 63, w = tid >> 6;
    const int wm = w >> 1, wn = w & 1;
    const int row16 = lane & 15, quad = lane >> 4;
    const int n0 = blockIdx.x * 128, m0 = blockIdx.y * 128;

    // staging chunk ids (8 bf16 per chunk, 512 chunks per tile, 2 per thread)
    const int r0 = tid >> 2, c0 = (tid & 3) * 8;
    const int r1 = (tid + 256) >> 2, c1 = ((tid + 256) & 3) * 8;

    f32x4 acc[4][4];
#pragma unroll
    for (int i = 0; i < 4; ++i)
#pragma unroll
        for (int j = 0; j < 4; ++j) acc[i][j] = (f32x4){0.f, 0.f, 0.f, 0.f};

    for (int k0 = 0; k0 < DD; k0 += 32) {
        *(uint4*)&As[tid * 8]         = *(const uint4*)&A [(size_t)(m0 + r0) * DD + k0 + c0];
        *(uint4*)&As[(tid + 256) * 8] = *(const uint4*)&A [(size_t)(m0 + r1) * DD + k0 + c1];
        *(uint4*)&Bs[tid * 8]         = *(const uint4*)&Bt[(size_t)(n0 + r0) * DD + k0 + c0];
        *(uint4*)&Bs[(tid + 256) * 8] = *(const uint4*)&Bt[(size_t)(n0 + r1) * DD + k0 + c1];
        __syncthreads();
        bf16x8 af[4], bfr[4];
#pragma unroll
        for (int mt = 0; mt < 4; ++mt)
            af[mt] = *(const bf16x8*)&As[(wm * 64 + mt * 16 + row16) * 32 + quad * 8];
#pragma unroll
        for (int nt = 0; nt < 4; ++nt)
            bfr[nt] = *(const bf16x8*)&Bs[(wn * 64 + nt * 16 + row16) * 32 + quad * 8];
#pragma unroll
        for (int mt = 0; mt < 4; ++mt)
#pragma unroll
            for (int nt = 0; nt < 4; ++nt)
                acc[mt][nt] = __builtin_amdgcn_mfma_f32_16x16x32_bf16(
                    af[mt], bfr[nt], acc[mt][nt], 0, 0, 0);
        __syncthreads();
    }

    // epilogue
#pragma unroll
    for (int nt = 0; nt < 4; ++nt) {
        const int nb = n0 + wn * 64 + nt * 16;       // tile-uniform
        if (mode == 0) {
#pragma unroll
            for (int mt = 0; mt < 4; ++mt) {
#pragma unroll
                for (int r = 0; r < 4; ++r) {
                    int m = m0 + wm * 64 + mt * 16 + quad * 4 + r;
                    int n = nb + row16;
                    outf[(size_t)m * DD + n] = acc[mt][nt][r] + bq[n];
                }
            }
        } else {
            const int sel = nb >> 10;
            const float* bias = (sel == 0) ? bq : (sel == 1) ? bk : bv;
#pragma unroll
            for (int mt = 0; mt < 4; ++mt) {
#pragma unroll
                for (int r = 0; r < 4; ++r) {
                    int m = m0 + wm * 64 + mt * 16 + quad * 4 + r;
                    int nn = (nb + row16) & 1023;
                    float v = acc[mt][nt][r] + bias[nn];
                    int b = m >> 11, s = m & (SS - 1);
                    int h = nn >> 6, d = nn & 63;
                    size_t bh = (size_t)b * HH + h;
                    if (sel == 0) {
                        q_bf[(bh * SS + s) * HDD + d] = f2bf(v);
                    } else {
                        ushort_t* dst = (sel == 1) ? kbf : vbf;
                        dst[(bh * KTOT + MEMM + s) * HDD + d] = f2bf(v);
                        if (s >= SS - MEMM) {
                            float* nf = (sel == 1) ? nk : nv;
                            nf[(bh * MEMM + (s - (SS - MEMM))) * HDD + d] = v;
                        }
                    }
                }
            }
        }
    }
}

// ---------- cast past_k/past_v f32 -> bf16 cache heads ----------
__global__ __launch_bounds__(256) void cast_past_kernel(
    const float* __restrict__ pk, const float* __restrict__ pv,
    ushort_t* __restrict__ kbf, ushort_t* __restrict__ vbf)
{
    int idx = blockIdx.x * 256 + threadIdx.x;  // BB*HH*MEMM*HDD = 1048576
    int bh = idx >> 15;
    int rem = idx & 32767;
    size_t dst = (size_t)bh * KTOT * HDD + rem;
    kbf[dst] = f2bf(pk[idx]);
    vbf[dst] = f2bf(pv[idx]);
}

// ---------- transpose V: vbf[bh][k][d] -> vt[bh][d][k] ----------
__global__ __launch_bounds__(256) void transpose_v_kernel(
    const ushort_t* __restrict__ vbf, ushort_t* __restrict__ vt)
{
    __shared__ ushort_t T[64][72];
    const int k0 = blockIdx.x * 64;
    const int bh = blockIdx.y;
    const int t = threadIdx.x;
    const int rr = t >> 3, cc = (t & 7) * 8;
#pragma unroll
    for (int p = 0; p < 2; ++p) {
        int kk = p * 32 + rr;
        *(uint4*)&T[kk][cc] =
            *(const uint4*)(vbf + ((size_t)bh * KTOT + k0 + kk) * HDD + cc);
    }
    __syncthreads();
#pragma unroll
    for (int p = 0; p < 2; ++p) {
        int d = p * 32 + rr;
        ushort_t tmp[8];
#pragma unroll
        for (int j = 0; j < 8; ++j) tmp[j] = T[cc + j][d];
        *(uint4*)(vt + ((size_t)bh * HDD + d) * KTOT + k0 + cc) = *(uint4*)tmp;
    }
}

// ---------- scores: MFMA + LDS transpose + coalesced store ----------
__global__ __launch_bounds__(256) void score_kernel(
    const ushort_t* __restrict__ qbf, const ushort_t* __restrict__ kbf,
    ushort_t* __restrict__ sbuf, int bh0)
{
    __shared__ __align__(16) ushort_t Ts[64][264];
    const int w = threadIdx.x >> 6, lane = threadIdx.x & 63;
    const int kt = blockIdx.x, qt = blockIdx.y;
    const int lbh = blockIdx.z, bh = bh0 + lbh;
    const int m0 = qt * 64 + w * 16;
    const int row16 = lane & 15, quad = lane >> 4;

    const ushort_t* qrow = qbf + ((size_t)bh * SS + m0 + row16) * HDD + quad * 8;
    bf16x8 a0 = *(const bf16x8*)qrow;
    bf16x8 a1 = *(const bf16x8*)(qrow + 32);
    const ushort_t* kbase = kbf + ((size_t)bh * KTOT + kt * 256 + row16) * HDD + quad * 8;

#pragma unroll
    for (int nt = 0; nt < 16; ++nt) {
        const ushort_t* kr = kbase + (size_t)nt * 16 * HDD;
        bf16x8 b0 = *(const bf16x8*)kr;
        bf16x8 b1 = *(const bf16x8*)(kr + 32);
        f32x4 acc = {0.f, 0.f, 0.f, 0.f};
        acc = __builtin_amdgcn_mfma_f32_16x16x32_bf16(a0, b0, acc, 0, 0, 0);
        acc = __builtin_amdgcn_mfma_f32_16x16x32_bf16(a1, b1, acc, 0, 0, 0);
#pragma unroll
        for (int r = 0; r < 4; ++r)
            Ts[w * 16 + quad * 4 + r][nt * 16 + row16] = f2bf(acc[r] * 0.125f);
    }
    __syncthreads();
    // coalesced store: thread t -> row t>>2, 64-col chunk (t&3)*64
    const int r = threadIdx.x >> 2, c0 = (threadIdx.x & 3) * 64;
    ushort_t* dst = sbuf + ((size_t)lbh * SS + qt * 64 + r) * KTOT + kt * 256 + c0;
#pragma unroll
    for (int j = 0; j < 8; ++j)
        *(uint4*)&dst[j * 8] = *(const uint4*)&Ts[r][c0 + j * 8];
}

// ---------- wave helpers ----------
__device__ __forceinline__ uint32_t wave_iscan(uint32_t x, int lane) {
#pragma unroll
    for (int d = 1; d < 64; d <<= 1) {
        uint32_t t = __shfl_up(x, d, 64);
        if (lane >= d) x += t;
    }
    return x;
}
__device__ __forceinline__ void select_from_hist(
    volatile uint32_t* hist, uint32_t R, int lane, uint32_t* bin_out, uint32_t* rem_out)
{
    uint32_t c[4];
    uint32_t s = 0;
#pragma unroll
    for (int i = 0; i < 4; ++i) { c[i] = hist[lane * 4 + i]; s += c[i]; }
    uint32_t incl = wave_iscan(s, lane);
    uint32_t excl = incl - s;
    uint64_t bal = __ballot(incl > R);
    int fl = __ffsll((unsigned long long)bal) - 1;
    uint32_t exf = __shfl(excl, fl, 64);
    uint32_t c0 = __shfl(c[0], fl, 64), c1 = __shfl(c[1], fl, 64);
    uint32_t c2 = __shfl(c[2], fl, 64), c3 = __shfl(c[3], fl, 64);
    uint32_t cc[4] = {c0, c1, c2, c3};
    uint32_t cum = exf, bin = fl * 4, rem = 0;
#pragma unroll
    for (int i = 0; i < 4; ++i) {
        if (cum + cc[i] > R) { bin = fl * 4 + i; rem = R - cum; break; }
        cum += cc[i];
    }
    *bin_out = bin;
    *rem_out = rem;
}

// ---------- per-row quantile (ranks 255,256) + rowmax; 1 wave per row ----------
__global__ __launch_bounds__(256) void quant_kernel(
    const ushort_t* __restrict__ sbuf, float* __restrict__ thr_out,
    float* __restrict__ max_out, int bh0)
{
    __shared__ uint32_t histA[4][256];
    __shared__ uint32_t histB[4][256];
    const int w = threadIdx.x >> 6, lane = threadIdx.x & 63;
    const int lrow = blockIdx.x * 4 + w;
    const size_t grow = (size_t)bh0 * SS + lrow;
    const ushort_t* src = sbuf + (size_t)lrow * KTOT;

    uint32_t key[40];
    uint32_t maxkey = 0;
#pragma unroll
    for (int c = 0; c < 5; ++c) {
        uint4 p = *(const uint4*)(src + c * 512 + lane * 8);
        uint32_t u[8] = {p.x & 0xFFFFu, p.x >> 16, p.y & 0xFFFFu, p.y >> 16,
                         p.z & 0xFFFFu, p.z >> 16, p.w & 0xFFFFu, p.w >> 16};
#pragma unroll
        for (int j = 0; j < 8; ++j) {
            uint32_t k = mapkey(u[j]);
            key[c * 8 + j] = k;
            maxkey = max(maxkey, k);
        }
    }
#pragma unroll
    for (int d = 1; d < 64; d <<= 1)
        maxkey = max(maxkey, (uint32_t)__shfl_xor(maxkey, d, 64));

    for (int i = 0; i < 4; ++i) histA[w][lane * 4 + i] = 0u;
    __syncthreads();
#pragma unroll
    for (int i = 0; i < 40; ++i) atomicAdd(&histA[w][key[i] >> 8], 1u);
    __syncthreads();
    uint32_t binA, remA, binB, remB;
    select_from_hist(histA[w], 255u, lane, &binA, &remA);
    select_from_hist(histA[w], 256u, lane, &binB, &remB);
    __syncthreads();

    for (int i = 0; i < 4; ++i) { histA[w][lane * 4 + i] = 0u; histB[w][lane * 4 + i] = 0u; }
    __syncthreads();
#pragma unroll
    for (int i = 0; i < 40; ++i) {
        uint32_t k = key[i];
        uint32_t top = k >> 8;
        if (top == binA) atomicAdd(&histA[w][k & 255u], 1u);
        if (top == binB) atomicAdd(&histB[w][k & 255u], 1u);
    }
    __syncthreads();
    uint32_t lowA, rA, lowB, rB;
    select_from_hist(histA[w], remA, lane, &lowA, &rA);
    select_from_hist(histB[w], remB, lane, &lowB, &rB);

    if (lane == 0) {
        float thrA = bf2f(unmapkey((binA << 8) | lowA));
        float thrB = bf2f(unmapkey((binB << 8) | lowB));
        thr_out[grow] = thrA + 0.9f * (thrB - thrA);
        max_out[grow] = bf2f(unmapkey(maxkey));
    }
}

// ---------- softmax weights + PV via MFMA (waves split n; prefetched scores) ----------
__global__ __launch_bounds__(256) void pv_kernel(
    const ushort_t* __restrict__ sbuf, const ushort_t* __restrict__ vt,
    const float* __restrict__ thr_arr, const float* __restrict__ max_arr,
    const int* __restrict__ amask, ushort_t* __restrict__ attn_bf, int bh0)
{
    __shared__ __align__(16) ushort_t Wt[64][264];
    __shared__ float psum_red[64][33];
    __shared__ float thr_s[64], max_s[64], rsum[64];

    const int tid = threadIdx.x;
    const int qt = blockIdx.x;
    const int lbh = blockIdx.y, bh = bh0 + lbh;
    const int b = bh >> 4, h = bh & 15;
    const int q0 = qt * 64;
    const int lane = tid & 63, w = tid >> 6;
    const int colg = tid & 31, rowg = tid >> 5;
    const int row16 = lane & 15, quad = lane >> 4;

    if (tid < 64) {
        thr_s[tid] = thr_arr[(size_t)bh * SS + q0 + tid];
        max_s[tid] = max_arr[(size_t)bh * SS + q0 + tid];
    }
    __syncthreads();

    float psum[8];
#pragma unroll
    for (int i = 0; i < 8; ++i) psum[i] = 0.f;
    f32x4 acc[4];
#pragma unroll
    for (int i = 0; i < 4; ++i) acc[i] = (f32x4){0.f, 0.f, 0.f, 0.f};

    const ushort_t* srow = sbuf + ((size_t)lbh * SS + q0) * KTOT;
    const ushort_t* vwave = vt + ((size_t)bh * HDD + w * 16 + row16) * KTOT;
    const int* am = amask + b * SS;

    uint4 p[8];
#pragma unroll
    for (int rg = 0; rg < 8; ++rg)
        p[rg] = *(const uint4*)(srow + (size_t)(rg * 8 + rowg) * KTOT + colg * 8);

    for (int kt = 0; kt < 10; ++kt) {
        // stage: thresholded exp weights (bf16) into LDS
#pragma unroll
        for (int rg = 0; rg < 8; ++rg) {
            int r = rg * 8 + rowg;
            float tr = thr_s[r], mx = max_s[r];
            uint4 pp = p[rg];
            uint32_t u[8] = {pp.x & 0xFFFFu, pp.x >> 16, pp.y & 0xFFFFu, pp.y >> 16,
                             pp.z & 0xFFFFu, pp.z >> 16, pp.w & 0xFFFFu, pp.w >> 16};
            ushort_t wb[8];
            float ps = 0.f;
#pragma unroll
            for (int j = 0; j < 8; ++j) {
                float s = bf2f(u[j]);
                bool keep = (s >= tr);
                if (kt >= 2) {
                    int col = kt * 256 + colg * 8 + j;
                    keep = keep && (am[col - MEMM] != 0);
                }
                float wv = keep ? __expf(s - mx) : 0.f;
                ushort_t wbb = f2bf(wv);
                wb[j] = wbb;
                ps += bf2f((uint32_t)wbb);
            }
            psum[rg] += ps;
            uint4 q;
            q.x = (uint32_t)wb[0] | ((uint32_t)wb[1] << 16);
            q.y = (uint32_t)wb[2] | ((uint32_t)wb[3] << 16);
            q.z = (uint32_t)wb[4] | ((uint32_t)wb[5] << 16);
            q.w = (uint32_t)wb[6] | ((uint32_t)wb[7] << 16);
            *(uint4*)&Wt[r][colg * 8] = q;
        }
        __syncthreads();
        // prefetch next k-tile's scores (overlaps MFMA phase)
        if (kt < 9) {
#pragma unroll
            for (int rg = 0; rg < 8; ++rg)
                p[rg] = *(const uint4*)(srow + (size_t)(rg * 8 + rowg) * KTOT
                                        + (kt + 1) * 256 + colg * 8);
        }
        // MFMA: each wave owns n-tile w (16 cols of V); B loaded once per kk
#pragma unroll
        for (int kk = 0; kk < 8; ++kk) {
            bf16x8 bv = *(const bf16x8*)(vwave + kt * 256 + kk * 32 + quad * 8);
#pragma unroll
            for (int mt = 0; mt < 4; ++mt) {
                bf16x8 a = *(const bf16x8*)&Wt[mt * 16 + row16][kk * 32 + quad * 8];
                acc[mt] = __builtin_amdgcn_mfma_f32_16x16x32_bf16(a, bv, acc[mt], 0, 0, 0);
            }
        }
        __syncthreads();
    }

#pragma unroll
    for (int rg = 0; rg < 8; ++rg) psum_red[rg * 8 + rowg][colg] = psum[rg];
    __syncthreads();
    if (tid < 64) {
        float s = 0.f;
        for (int i = 0; i < 32; ++i) s += psum_red[tid][i];
        rsum[tid] = s;
    }
    __syncthreads();

#pragma unroll
    for (int mt = 0; mt < 4; ++mt) {
#pragma unroll
        for (int r = 0; r < 4; ++r) {
            int m = mt * 16 + quad * 4 + r;
            float val = acc[mt][r] / rsum[m];
            attn_bf[((size_t)b * SS + q0 + m) * DD + h * HDD + w * 16 + row16] = f2bf(val);
        }
    }
}

extern "C" void kernel_launch(void* const* d_in, const int* in_sizes, int n_in,
                              void* d_out, int out_size, void* d_ws, size_t ws_size,
                              hipStream_t stream)
{
    const float* hidden = (const float*)d_in[0];
    const int*   amask  = (const int*)d_in[1];
    const float* past_k = (const float*)d_in[2];
    const float* past_v = (const float*)d_in[3];
    const float* Wq = (const float*)d_in[4];
    const float* bq = (const float*)d_in[5];
    const float* Wk = (const float*)d_in[6];
    const float* bk = (const float*)d_in[7];
    const float* Wv = (const float*)d_in[8];
    const float* bv = (const float*)d_in[9];
    const float* Wo = (const float*)d_in[10];
    const float* bo = (const float*)d_in[11];

    float* out    = (float*)d_out;
    float* nk_out = out + (size_t)BB * SS * DD;
    float* nv_out = nk_out + (size_t)BB * HH * MEMM * HDD;

    char* base = (char*)d_ws;
    size_t off = 0;
    auto alloc = [&](size_t bytes) {
        char* p = base + off;
        off += (bytes + 255) & ~(size_t)255;
        return p;
    };
    ushort_t* hb    = (ushort_t*)alloc((size_t)BB * SS * DD * 2);            // 8 MB
    ushort_t* WtAll = (ushort_t*)alloc((size_t)4 * DD * DD * 2);             // 8 MB
    ushort_t* q_bf  = (ushort_t*)alloc((size_t)BB * HH * SS * HDD * 2);      // 8 MB
    ushort_t* kbf   = (ushort_t*)alloc((size_t)BB * HH * KTOT * HDD * 2);    // 10 MB
    ushort_t* vbf   = (ushort_t*)alloc((size_t)BB * HH * KTOT * HDD * 2);    // 10 MB
    ushort_t* vt    = (ushort_t*)alloc((size_t)BB * HH * HDD * KTOT * 2);    // 10 MB
    ushort_t* abf   = (ushort_t*)alloc((size_t)BB * SS * DD * 2);            // 8 MB
    float* thr_arr  = (float*)alloc((size_t)NROWS * 4);
    float* max_arr  = (float*)alloc((size_t)NROWS * 4);
    size_t fixed = off;
    const size_t sbuf_full = (size_t)BB * HH * SS * KTOT * 2;                // 335.5 MB
    int nchunks = 32;
    for (int c = 1; c <= 32; c <<= 1) {
        if (fixed + sbuf_full / c + 256 <= ws_size) { nchunks = c; break; }
    }
    ushort_t* sbuf = (ushort_t*)alloc(sbuf_full / nchunks);
    const int bhpc = (BB * HH) / nchunks;

    dim3 blk(256);

    cast_hidden_kernel<<<dim3(1024), blk, 0, stream>>>(hidden, hb);
    transw_kernel<<<dim3(16, 16, 4), blk, 0, stream>>>(Wq, Wk, Wv, Wo, WtAll);
    // fused QKV: one GEMM, N=3072 (Wq|Wk|Wv transposes adjacent in WtAll)
    gemm128_kernel<<<dim3(24, 32), blk, 0, stream>>>(
        hb, WtAll, 1, bq, bk, bv, nullptr, q_bf, kbf, vbf, nk_out, nv_out);
    cast_past_kernel<<<dim3(4096), blk, 0, stream>>>(past_k, past_v, kbf, vbf);
    transpose_v_kernel<<<dim3(KTOT / 64, BB * HH), blk, 0, stream>>>(vbf, vt);

    for (int ci = 0; ci < nchunks; ++ci) {
        int bh0 = ci * bhpc;
        score_kernel<<<dim3(KTOT / 256, SS / 64, bhpc), blk, 0, stream>>>(q_bf, kbf, sbuf, bh0);
        quant_kernel<<<dim3(bhpc * (SS / 4)), blk, 0, stream>>>(sbuf, thr_arr, max_arr, bh0);
        pv_kernel<<<dim3(SS / 64, bhpc), blk, 0, stream>>>(sbuf, vt, thr_arr, max_arr,
                                                           amask, abf, bh0);
    }
    // O-projection
    gemm128_kernel<<<dim3(8, 32), blk, 0, stream>>>(
        abf, WtAll + (size_t)3 * DD * DD, 0, bo, nullptr, nullptr, out,
        nullptr, nullptr, nullptr, nullptr, nullptr);
}

// Round 6
// 980.251 us; speedup vs baseline: 4.6541x; 1.0237x over previous
//
#include <hip/hip_runtime.h>
#include <stdint.h>

typedef unsigned short ushort_t;
typedef __attribute__((ext_vector_type(8))) short bf16x8;
typedef __attribute__((ext_vector_type(4))) float f32x4;

#define BB 2
#define SS 2048
#define DD 1024
#define HH 16
#define HDD 64
#define MEMM 512
#define KTOT 2560   // MEMM + SS
#define NROWS (BB*HH*SS)   // 65536 score rows

// ---------- helpers ----------
__device__ __forceinline__ float bf2f(uint32_t u) {
    return __uint_as_float(u << 16);
}
__device__ __forceinline__ ushort_t f2bf(float f) {
    uint32_t u = __float_as_uint(f);
    uint32_t r = (u + 0x7FFFu + ((u >> 16) & 1u)) >> 16;
    return (ushort_t)r;
}
__device__ __forceinline__ uint32_t mapkey(uint32_t u) {
    return (u & 0x8000u) ? (0xFFFFu ^ u) : (u | 0x8000u);
}
__device__ __forceinline__ uint32_t unmapkey(uint32_t k) {
    return (k & 0x8000u) ? (k ^ 0x8000u) : (0xFFFFu ^ k);
}

// ---------- cast hidden f32 -> bf16 ----------
__global__ __launch_bounds__(256) void cast_hidden_kernel(
    const float* __restrict__ h, ushort_t* __restrict__ hb)
{
    size_t i0 = ((size_t)blockIdx.x * 256 + threadIdx.x) * 16;  // 4M elems / 16
    ushort_t o[16];
#pragma unroll
    for (int j = 0; j < 4; ++j) {
        float4 v = *(const float4*)&h[i0 + j * 4];
        o[j * 4 + 0] = f2bf(v.x); o[j * 4 + 1] = f2bf(v.y);
        o[j * 4 + 2] = f2bf(v.z); o[j * 4 + 3] = f2bf(v.w);
    }
    *(uint4*)&hb[i0] = *(uint4*)&o[0];
    *(uint4*)&hb[i0 + 8] = *(uint4*)&o[8];
}

// ---------- transpose+cast weights: W[k][n] f32 -> Wt[n][k] bf16 ----------
__global__ __launch_bounds__(256) void transw_kernel(
    const float* __restrict__ Wq, const float* __restrict__ Wk,
    const float* __restrict__ Wv, const float* __restrict__ Wo,
    ushort_t* __restrict__ WtAll)
{
    __shared__ ushort_t T[64][66];
    const int z = blockIdx.z;
    const float* W = (z == 0) ? Wq : (z == 1) ? Wk : (z == 2) ? Wv : Wo;
    ushort_t* dst = WtAll + (size_t)z * DD * DD;
    const int k0 = blockIdx.x * 64, n0 = blockIdx.y * 64;
    const int t = threadIdx.x;
    const int kk = t >> 2, c4 = (t & 3) * 16;
#pragma unroll
    for (int j = 0; j < 4; ++j) {
        float4 v = *(const float4*)&W[(size_t)(k0 + kk) * DD + n0 + c4 + j * 4];
        T[kk][c4 + j * 4 + 0] = f2bf(v.x);
        T[kk][c4 + j * 4 + 1] = f2bf(v.y);
        T[kk][c4 + j * 4 + 2] = f2bf(v.z);
        T[kk][c4 + j * 4 + 3] = f2bf(v.w);
    }
    __syncthreads();
    const int nn = t >> 2, kc = (t & 3) * 16;
    ushort_t tmp[16];
#pragma unroll
    for (int j = 0; j < 16; ++j) tmp[j] = T[kc + j][nn];
    *(uint4*)&dst[(size_t)(n0 + nn) * DD + k0 + kc] = *(uint4*)&tmp[0];
    *(uint4*)&dst[(size_t)(n0 + nn) * DD + k0 + kc + 8] = *(uint4*)&tmp[8];
}

// ---------- 128x128-tile bf16 MFMA GEMM (m93-style LDS staging) ----------
// A [4096][1024] bf16 row-major; Bt [N][1024] bf16 (n-major). K=1024. BK=32.
// 4 waves: wave w owns 64x64 quadrant (wm=w>>1, wn=w&1), 4x4 accs of 16x16.
// mode 0: outf[m*DD+n] = acc + bq[n]  (bq carries bo)
// mode 1: fused QKV epilogue (N=3072; sel = n>>10)
__global__ __launch_bounds__(256) void gemm128_kernel(
    const ushort_t* __restrict__ A, const ushort_t* __restrict__ Bt, int mode,
    const float* __restrict__ bq, const float* __restrict__ bk, const float* __restrict__ bv,
    float* __restrict__ outf,
    ushort_t* __restrict__ q_bf, ushort_t* __restrict__ kbf, ushort_t* __restrict__ vbf,
    float* __restrict__ nk, float* __restrict__ nv)
{
    __shared__ __align__(16) ushort_t As[128 * 32];
    __shared__ __align__(16) ushort_t Bs[128 * 32];
    const int tid = threadIdx.x;
    const int lane = tid & 63, w = tid >> 6;
    const int wm = w >> 1, wn = w & 1;
    const int row16 = lane & 15, quad = lane >> 4;
    const int n0 = blockIdx.x * 128, m0 = blockIdx.y * 128;

    // staging chunk ids (8 bf16 per chunk, 512 chunks per tile, 2 per thread)
    const int r0 = tid >> 2, c0 = (tid & 3) * 8;
    const int r1 = (tid + 256) >> 2, c1 = ((tid + 256) & 3) * 8;

    f32x4 acc[4][4];
#pragma unroll
    for (int i = 0; i < 4; ++i)
#pragma unroll
        for (int j = 0; j < 4; ++j) acc[i][j] = (f32x4){0.f, 0.f, 0.f, 0.f};

    for (int k0 = 0; k0 < DD; k0 += 32) {
        *(uint4*)&As[tid * 8]         = *(const uint4*)&A [(size_t)(m0 + r0) * DD + k0 + c0];
        *(uint4*)&As[(tid + 256) * 8] = *(const uint4*)&A [(size_t)(m0 + r1) * DD + k0 + c1];
        *(uint4*)&Bs[tid * 8]         = *(const uint4*)&Bt[(size_t)(n0 + r0) * DD + k0 + c0];
        *(uint4*)&Bs[(tid + 256) * 8] = *(const uint4*)&Bt[(size_t)(n0 + r1) * DD + k0 + c1];
        __syncthreads();
        bf16x8 af[4], bfr[4];
#pragma unroll
        for (int mt = 0; mt < 4; ++mt)
            af[mt] = *(const bf16x8*)&As[(wm * 64 + mt * 16 + row16) * 32 + quad * 8];
#pragma unroll
        for (int nt = 0; nt < 4; ++nt)
            bfr[nt] = *(const bf16x8*)&Bs[(wn * 64 + nt * 16 + row16) * 32 + quad * 8];
#pragma unroll
        for (int mt = 0; mt < 4; ++mt)
#pragma unroll
            for (int nt = 0; nt < 4; ++nt)
                acc[mt][nt] = __builtin_amdgcn_mfma_f32_16x16x32_bf16(
                    af[mt], bfr[nt], acc[mt][nt], 0, 0, 0);
        __syncthreads();
    }

    // epilogue
#pragma unroll
    for (int nt = 0; nt < 4; ++nt) {
        const int nb = n0 + wn * 64 + nt * 16;       // tile-uniform
        if (mode == 0) {
#pragma unroll
            for (int mt = 0; mt < 4; ++mt) {
#pragma unroll
                for (int r = 0; r < 4; ++r) {
                    int m = m0 + wm * 64 + mt * 16 + quad * 4 + r;
                    int n = nb + row16;
                    outf[(size_t)m * DD + n] = acc[mt][nt][r] + bq[n];
                }
            }
        } else {
            const int sel = nb >> 10;
            const float* bias = (sel == 0) ? bq : (sel == 1) ? bk : bv;
#pragma unroll
            for (int mt = 0; mt < 4; ++mt) {
#pragma unroll
                for (int r = 0; r < 4; ++r) {
                    int m = m0 + wm * 64 + mt * 16 + quad * 4 + r;
                    int nn = (nb + row16) & 1023;
                    float v = acc[mt][nt][r] + bias[nn];
                    int b = m >> 11, s = m & (SS - 1);
                    int h = nn >> 6, d = nn & 63;
                    size_t bh = (size_t)b * HH + h;
                    if (sel == 0) {
                        q_bf[(bh * SS + s) * HDD + d] = f2bf(v);
                    } else {
                        ushort_t* dst = (sel == 1) ? kbf : vbf;
                        dst[(bh * KTOT + MEMM + s) * HDD + d] = f2bf(v);
                        if (s >= SS - MEMM) {
                            float* nf = (sel == 1) ? nk : nv;
                            nf[(bh * MEMM + (s - (SS - MEMM))) * HDD + d] = v;
                        }
                    }
                }
            }
        }
    }
}

// ---------- cast past_k/past_v f32 -> bf16 cache heads ----------
__global__ __launch_bounds__(256) void cast_past_kernel(
    const float* __restrict__ pk, const float* __restrict__ pv,
    ushort_t* __restrict__ kbf, ushort_t* __restrict__ vbf)
{
    int idx = blockIdx.x * 256 + threadIdx.x;  // BB*HH*MEMM*HDD = 1048576
    int bh = idx >> 15;
    int rem = idx & 32767;
    size_t dst = (size_t)bh * KTOT * HDD + rem;
    kbf[dst] = f2bf(pk[idx]);
    vbf[dst] = f2bf(pv[idx]);
}

// ---------- transpose V: vbf[bh][k][d] -> vt[bh][d][k] ----------
__global__ __launch_bounds__(256) void transpose_v_kernel(
    const ushort_t* __restrict__ vbf, ushort_t* __restrict__ vt)
{
    __shared__ ushort_t T[64][72];
    const int k0 = blockIdx.x * 64;
    const int bh = blockIdx.y;
    const int t = threadIdx.x;
    const int rr = t >> 3, cc = (t & 7) * 8;
#pragma unroll
    for (int p = 0; p < 2; ++p) {
        int kk = p * 32 + rr;
        *(uint4*)&T[kk][cc] =
            *(const uint4*)(vbf + ((size_t)bh * KTOT + k0 + kk) * HDD + cc);
    }
    __syncthreads();
#pragma unroll
    for (int p = 0; p < 2; ++p) {
        int d = p * 32 + rr;
        ushort_t tmp[8];
#pragma unroll
        for (int j = 0; j < 8; ++j) tmp[j] = T[cc + j][d];
        *(uint4*)(vt + ((size_t)bh * HDD + d) * KTOT + k0 + cc) = *(uint4*)tmp;
    }
}

// ---------- scores: MFMA + LDS transpose + coalesced store ----------
__global__ __launch_bounds__(256) void score_kernel(
    const ushort_t* __restrict__ qbf, const ushort_t* __restrict__ kbf,
    ushort_t* __restrict__ sbuf, int bh0)
{
    __shared__ __align__(16) ushort_t Ts[64][264];
    const int w = threadIdx.x >> 6, lane = threadIdx.x & 63;
    const int kt = blockIdx.x, qt = blockIdx.y;
    const int lbh = blockIdx.z, bh = bh0 + lbh;
    const int m0 = qt * 64 + w * 16;
    const int row16 = lane & 15, quad = lane >> 4;

    const ushort_t* qrow = qbf + ((size_t)bh * SS + m0 + row16) * HDD + quad * 8;
    bf16x8 a0 = *(const bf16x8*)qrow;
    bf16x8 a1 = *(const bf16x8*)(qrow + 32);
    const ushort_t* kbase = kbf + ((size_t)bh * KTOT + kt * 256 + row16) * HDD + quad * 8;

#pragma unroll
    for (int nt = 0; nt < 16; ++nt) {
        const ushort_t* kr = kbase + (size_t)nt * 16 * HDD;
        bf16x8 b0 = *(const bf16x8*)kr;
        bf16x8 b1 = *(const bf16x8*)(kr + 32);
        f32x4 acc = {0.f, 0.f, 0.f, 0.f};
        acc = __builtin_amdgcn_mfma_f32_16x16x32_bf16(a0, b0, acc, 0, 0, 0);
        acc = __builtin_amdgcn_mfma_f32_16x16x32_bf16(a1, b1, acc, 0, 0, 0);
#pragma unroll
        for (int r = 0; r < 4; ++r)
            Ts[w * 16 + quad * 4 + r][nt * 16 + row16] = f2bf(acc[r] * 0.125f);
    }
    __syncthreads();
    // coalesced store: thread t -> row t>>2, 64-col chunk (t&3)*64
    const int r = threadIdx.x >> 2, c0 = (threadIdx.x & 3) * 64;
    ushort_t* dst = sbuf + ((size_t)lbh * SS + qt * 64 + r) * KTOT + kt * 256 + c0;
#pragma unroll
    for (int j = 0; j < 8; ++j)
        *(uint4*)&dst[j * 8] = *(const uint4*)&Ts[r][c0 + j * 8];
}

// ---------- wave helpers ----------
__device__ __forceinline__ uint32_t wave_iscan(uint32_t x, int lane) {
#pragma unroll
    for (int d = 1; d < 64; d <<= 1) {
        uint32_t t = __shfl_up(x, d, 64);
        if (lane >= d) x += t;
    }
    return x;
}
// select rank R given per-lane counts c[0..3] for bins lane*4..lane*4+3
__device__ __forceinline__ void select_from_counts(
    const uint32_t* c, uint32_t R, int lane, uint32_t* bin_out, uint32_t* rem_out)
{
    uint32_t s = c[0] + c[1] + c[2] + c[3];
    uint32_t incl = wave_iscan(s, lane);
    uint32_t excl = incl - s;
    uint64_t bal = __ballot(incl > R);
    int fl = __ffsll((unsigned long long)bal) - 1;
    uint32_t exf = __shfl(excl, fl, 64);
    uint32_t c0 = __shfl(c[0], fl, 64), c1 = __shfl(c[1], fl, 64);
    uint32_t c2 = __shfl(c[2], fl, 64), c3 = __shfl(c[3], fl, 64);
    uint32_t cc[4] = {c0, c1, c2, c3};
    uint32_t cum = exf, bin = fl * 4, rem = 0;
#pragma unroll
    for (int i = 0; i < 4; ++i) {
        if (cum + cc[i] > R) { bin = fl * 4 + i; rem = R - cum; break; }
        cum += cc[i];
    }
    *bin_out = bin;
    *rem_out = rem;
}

// ---------- per-row quantile (ranks 255,256) + rowmax ----------
// 1 wave per row, waves fully independent (no __syncthreads).
// 4x-replicated histograms (replica = lane>>4, stride 257 words -> distinct banks)
__global__ __launch_bounds__(256) void quant_kernel(
    const ushort_t* __restrict__ sbuf, float* __restrict__ thr_out,
    float* __restrict__ max_out, int bh0)
{
    __shared__ uint32_t hist[4][1028];   // [wave][replica*257 + bin], 16448 B
    const int w = threadIdx.x >> 6, lane = threadIdx.x & 63;
    const int rep = lane >> 4;
    uint32_t* H = hist[w];
    const int lrow = blockIdx.x * 4 + w;
    const size_t grow = (size_t)bh0 * SS + lrow;
    const ushort_t* src = sbuf + (size_t)lrow * KTOT;

    // load 40 keys (mapped) into regs, track max
    uint32_t key[40];
    uint32_t maxkey = 0;
#pragma unroll
    for (int c = 0; c < 5; ++c) {
        uint4 p = *(const uint4*)(src + c * 512 + lane * 8);
        uint32_t u[8] = {p.x & 0xFFFFu, p.x >> 16, p.y & 0xFFFFu, p.y >> 16,
                         p.z & 0xFFFFu, p.z >> 16, p.w & 0xFFFFu, p.w >> 16};
#pragma unroll
        for (int j = 0; j < 8; ++j) {
            uint32_t k = mapkey(u[j]);
            key[c * 8 + j] = k;
            maxkey = max(maxkey, k);
        }
    }
#pragma unroll
    for (int d = 1; d < 64; d <<= 1)
        maxkey = max(maxkey, (uint32_t)__shfl_xor(maxkey, d, 64));

    // ---- pass 1: top-byte histogram (4 replicas) ----
    for (int i = lane; i < 1028; i += 64) H[i] = 0u;
    __threadfence_block();
#pragma unroll
    for (int i = 0; i < 40; ++i) atomicAdd(&H[rep * 257 + (key[i] >> 8)], 1u);
    __threadfence_block();
    uint32_t c[4];
#pragma unroll
    for (int i = 0; i < 4; ++i)
        c[i] = H[lane * 4 + i] + H[257 + lane * 4 + i]
             + H[514 + lane * 4 + i] + H[771 + lane * 4 + i];
    uint32_t binA, remA, binB, remB;
    select_from_counts(c, 255u, lane, &binA, &remA);
    select_from_counts(c, 256u, lane, &binB, &remB);

    // ---- pass 2: low-byte histogram of binA (reused for binB when equal) ----
    for (int i = lane; i < 1028; i += 64) H[i] = 0u;
    __threadfence_block();
#pragma unroll
    for (int i = 0; i < 40; ++i) {
        uint32_t k = key[i];
        if ((k >> 8) == binA) atomicAdd(&H[rep * 257 + (k & 255u)], 1u);
    }
    __threadfence_block();
#pragma unroll
    for (int i = 0; i < 4; ++i)
        c[i] = H[lane * 4 + i] + H[257 + lane * 4 + i]
             + H[514 + lane * 4 + i] + H[771 + lane * 4 + i];
    uint32_t lowA, rA, lowB, rB;
    select_from_counts(c, remA, lane, &lowA, &rA);
    if (binB == binA) {
        select_from_counts(c, remB, lane, &lowB, &rB);
    } else {
        // rare: rebuild for binB (wave-uniform branch)
        for (int i = lane; i < 1028; i += 64) H[i] = 0u;
        __threadfence_block();
#pragma unroll
        for (int i = 0; i < 40; ++i) {
            uint32_t k = key[i];
            if ((k >> 8) == binB) atomicAdd(&H[rep * 257 + (k & 255u)], 1u);
        }
        __threadfence_block();
#pragma unroll
        for (int i = 0; i < 4; ++i)
            c[i] = H[lane * 4 + i] + H[257 + lane * 4 + i]
                 + H[514 + lane * 4 + i] + H[771 + lane * 4 + i];
        select_from_counts(c, remB, lane, &lowB, &rB);
    }

    if (lane == 0) {
        float thrA = bf2f(unmapkey((binA << 8) | lowA));
        float thrB = bf2f(unmapkey((binB << 8) | lowB));
        thr_out[grow] = thrA + 0.9f * (thrB - thrA);
        max_out[grow] = bf2f(unmapkey(maxkey));
    }
}

// ---------- softmax weights + PV via MFMA (waves split n; prefetched scores) ----------
__global__ __launch_bounds__(256) void pv_kernel(
    const ushort_t* __restrict__ sbuf, const ushort_t* __restrict__ vt,
    const float* __restrict__ thr_arr, const float* __restrict__ max_arr,
    const int* __restrict__ amask, ushort_t* __restrict__ attn_bf, int bh0)
{
    __shared__ __align__(16) ushort_t Wt[64][264];
    __shared__ float psum_red[64][33];
    __shared__ float thr_s[64], max_s[64], rsum[64];

    const int tid = threadIdx.x;
    const int qt = blockIdx.x;
    const int lbh = blockIdx.y, bh = bh0 + lbh;
    const int b = bh >> 4, h = bh & 15;
    const int q0 = qt * 64;
    const int lane = tid & 63, w = tid >> 6;
    const int colg = tid & 31, rowg = tid >> 5;
    const int row16 = lane & 15, quad = lane >> 4;

    if (tid < 64) {
        thr_s[tid] = thr_arr[(size_t)bh * SS + q0 + tid];
        max_s[tid] = max_arr[(size_t)bh * SS + q0 + tid];
    }
    __syncthreads();

    float psum[8];
#pragma unroll
    for (int i = 0; i < 8; ++i) psum[i] = 0.f;
    f32x4 acc[4];
#pragma unroll
    for (int i = 0; i < 4; ++i) acc[i] = (f32x4){0.f, 0.f, 0.f, 0.f};

    const ushort_t* srow = sbuf + ((size_t)lbh * SS + q0) * KTOT;
    const ushort_t* vwave = vt + ((size_t)bh * HDD + w * 16 + row16) * KTOT;
    const int* am = amask + b * SS;

    uint4 p[8];
#pragma unroll
    for (int rg = 0; rg < 8; ++rg)
        p[rg] = *(const uint4*)(srow + (size_t)(rg * 8 + rowg) * KTOT + colg * 8);

    for (int kt = 0; kt < 10; ++kt) {
        // stage: thresholded exp weights (bf16) into LDS
#pragma unroll
        for (int rg = 0; rg < 8; ++rg) {
            int r = rg * 8 + rowg;
            float tr = thr_s[r], mx = max_s[r];
            uint4 pp = p[rg];
            uint32_t u[8] = {pp.x & 0xFFFFu, pp.x >> 16, pp.y & 0xFFFFu, pp.y >> 16,
                             pp.z & 0xFFFFu, pp.z >> 16, pp.w & 0xFFFFu, pp.w >> 16};
            ushort_t wb[8];
            float ps = 0.f;
#pragma unroll
            for (int j = 0; j < 8; ++j) {
                float s = bf2f(u[j]);
                bool keep = (s >= tr);
                if (kt >= 2) {
                    int col = kt * 256 + colg * 8 + j;
                    keep = keep && (am[col - MEMM] != 0);
                }
                float wv = keep ? __expf(s - mx) : 0.f;
                ushort_t wbb = f2bf(wv);
                wb[j] = wbb;
                ps += bf2f((uint32_t)wbb);
            }
            psum[rg] += ps;
            uint4 q;
            q.x = (uint32_t)wb[0] | ((uint32_t)wb[1] << 16);
            q.y = (uint32_t)wb[2] | ((uint32_t)wb[3] << 16);
            q.z = (uint32_t)wb[4] | ((uint32_t)wb[5] << 16);
            q.w = (uint32_t)wb[6] | ((uint32_t)wb[7] << 16);
            *(uint4*)&Wt[r][colg * 8] = q;
        }
        __syncthreads();
        // prefetch next k-tile's scores (overlaps MFMA phase)
        if (kt < 9) {
#pragma unroll
            for (int rg = 0; rg < 8; ++rg)
                p[rg] = *(const uint4*)(srow + (size_t)(rg * 8 + rowg) * KTOT
                                        + (kt + 1) * 256 + colg * 8);
        }
        // MFMA: each wave owns n-tile w (16 cols of V); B loaded once per kk
#pragma unroll
        for (int kk = 0; kk < 8; ++kk) {
            bf16x8 bv = *(const bf16x8*)(vwave + kt * 256 + kk * 32 + quad * 8);
#pragma unroll
            for (int mt = 0; mt < 4; ++mt) {
                bf16x8 a = *(const bf16x8*)&Wt[mt * 16 + row16][kk * 32 + quad * 8];
                acc[mt] = __builtin_amdgcn_mfma_f32_16x16x32_bf16(a, bv, acc[mt], 0, 0, 0);
            }
        }
        __syncthreads();
    }

#pragma unroll
    for (int rg = 0; rg < 8; ++rg) psum_red[rg * 8 + rowg][colg] = psum[rg];
    __syncthreads();
    if (tid < 64) {
        float s = 0.f;
        for (int i = 0; i < 32; ++i) s += psum_red[tid][i];
        rsum[tid] = s;
    }
    __syncthreads();

#pragma unroll
    for (int mt = 0; mt < 4; ++mt) {
#pragma unroll
        for (int r = 0; r < 4; ++r) {
            int m = mt * 16 + quad * 4 + r;
            float val = acc[mt][r] / rsum[m];
            attn_bf[((size_t)b * SS + q0 + m) * DD + h * HDD + w * 16 + row16] = f2bf(val);
        }
    }
}

extern "C" void kernel_launch(void* const* d_in, const int* in_sizes, int n_in,
                              void* d_out, int out_size, void* d_ws, size_t ws_size,
                              hipStream_t stream)
{
    const float* hidden = (const float*)d_in[0];
    const int*   amask  = (const int*)d_in[1];
    const float* past_k = (const float*)d_in[2];
    const float* past_v = (const float*)d_in[3];
    const float* Wq = (const float*)d_in[4];
    const float* bq = (const float*)d_in[5];
    const float* Wk = (const float*)d_in[6];
    const float* bk = (const float*)d_in[7];
    const float* Wv = (const float*)d_in[8];
    const float* bv = (const float*)d_in[9];
    const float* Wo = (const float*)d_in[10];
    const float* bo = (const float*)d_in[11];

    float* out    = (float*)d_out;
    float* nk_out = out + (size_t)BB * SS * DD;
    float* nv_out = nk_out + (size_t)BB * HH * MEMM * HDD;

    char* base = (char*)d_ws;
    size_t off = 0;
    auto alloc = [&](size_t bytes) {
        char* p = base + off;
        off += (bytes + 255) & ~(size_t)255;
        return p;
    };
    ushort_t* hb    = (ushort_t*)alloc((size_t)BB * SS * DD * 2);            // 8 MB
    ushort_t* WtAll = (ushort_t*)alloc((size_t)4 * DD * DD * 2);             // 8 MB
    ushort_t* q_bf  = (ushort_t*)alloc((size_t)BB * HH * SS * HDD * 2);      // 8 MB
    ushort_t* kbf   = (ushort_t*)alloc((size_t)BB * HH * KTOT * HDD * 2);    // 10 MB
    ushort_t* vbf   = (ushort_t*)alloc((size_t)BB * HH * KTOT * HDD * 2);    // 10 MB
    ushort_t* vt    = (ushort_t*)alloc((size_t)BB * HH * HDD * KTOT * 2);    // 10 MB
    ushort_t* abf   = (ushort_t*)alloc((size_t)BB * SS * DD * 2);            // 8 MB
    float* thr_arr  = (float*)alloc((size_t)NROWS * 4);
    float* max_arr  = (float*)alloc((size_t)NROWS * 4);
    size_t fixed = off;
    const size_t sbuf_full = (size_t)BB * HH * SS * KTOT * 2;                // 335.5 MB
    int nchunks = 32;
    for (int c = 1; c <= 32; c <<= 1) {
        if (fixed + sbuf_full / c + 256 <= ws_size) { nchunks = c; break; }
    }
    ushort_t* sbuf = (ushort_t*)alloc(sbuf_full / nchunks);
    const int bhpc = (BB * HH) / nchunks;

    dim3 blk(256);

    cast_hidden_kernel<<<dim3(1024), blk, 0, stream>>>(hidden, hb);
    transw_kernel<<<dim3(16, 16, 4), blk, 0, stream>>>(Wq, Wk, Wv, Wo, WtAll);
    // fused QKV: one GEMM, N=3072 (Wq|Wk|Wv transposes adjacent in WtAll)
    gemm128_kernel<<<dim3(24, 32), blk, 0, stream>>>(
        hb, WtAll, 1, bq, bk, bv, nullptr, q_bf, kbf, vbf, nk_out, nv_out);
    cast_past_kernel<<<dim3(4096), blk, 0, stream>>>(past_k, past_v, kbf, vbf);
    transpose_v_kernel<<<dim3(KTOT / 64, BB * HH), blk, 0, stream>>>(vbf, vt);

    for (int ci = 0; ci < nchunks; ++ci) {
        int bh0 = ci * bhpc;
        score_kernel<<<dim3(KTOT / 256, SS / 64, bhpc), blk, 0, stream>>>(q_bf, kbf, sbuf, bh0);
        quant_kernel<<<dim3(bhpc * (SS / 4)), blk, 0, stream>>>(sbuf, thr_arr, max_arr, bh0);
        pv_kernel<<<dim3(SS / 64, bhpc), blk, 0, stream>>>(sbuf, vt, thr_arr, max_arr,
                                                           amask, abf, bh0);
    }
    // O-projection
    gemm128_kernel<<<dim3(8, 32), blk, 0, stream>>>(
        abf, WtAll + (size_t)3 * DD * DD, 0, bo, nullptr, nullptr, out,
        nullptr, nullptr, nullptr, nullptr, nullptr);
}

// Round 7
// 897.140 us; speedup vs baseline: 5.0852x; 1.0926x over previous
//
#include <hip/hip_runtime.h>
#include <stdint.h>

typedef unsigned short ushort_t;
typedef __attribute__((ext_vector_type(8))) short bf16x8;
typedef __attribute__((ext_vector_type(4))) float f32x4;

#define BB 2
#define SS 2048
#define DD 1024
#define HH 16
#define HDD 64
#define MEMM 512
#define KTOT 2560   // MEMM + SS
#define NROWS (BB*HH*SS)   // 65536 score rows

// ---------- helpers ----------
__device__ __forceinline__ float bf2f(uint32_t u) {
    return __uint_as_float(u << 16);
}
__device__ __forceinline__ ushort_t f2bf(float f) {
    uint32_t u = __float_as_uint(f);
    uint32_t r = (u + 0x7FFFu + ((u >> 16) & 1u)) >> 16;
    return (ushort_t)r;
}
__device__ __forceinline__ uint32_t mapkey(uint32_t u) {
    return (u & 0x8000u) ? (0xFFFFu ^ u) : (u | 0x8000u);
}
__device__ __forceinline__ uint32_t unmapkey(uint32_t k) {
    return (k & 0x8000u) ? (k ^ 0x8000u) : (0xFFFFu ^ k);
}

// ---------- cast hidden f32 -> bf16 ----------
__global__ __launch_bounds__(256) void cast_hidden_kernel(
    const float* __restrict__ h, ushort_t* __restrict__ hb)
{
    size_t i0 = ((size_t)blockIdx.x * 256 + threadIdx.x) * 16;  // 4M elems / 16
    ushort_t o[16];
#pragma unroll
    for (int j = 0; j < 4; ++j) {
        float4 v = *(const float4*)&h[i0 + j * 4];
        o[j * 4 + 0] = f2bf(v.x); o[j * 4 + 1] = f2bf(v.y);
        o[j * 4 + 2] = f2bf(v.z); o[j * 4 + 3] = f2bf(v.w);
    }
    *(uint4*)&hb[i0] = *(uint4*)&o[0];
    *(uint4*)&hb[i0 + 8] = *(uint4*)&o[8];
}

// ---------- transpose+cast weights: W[k][n] f32 -> Wt[n][k] bf16 ----------
__global__ __launch_bounds__(256) void transw_kernel(
    const float* __restrict__ Wq, const float* __restrict__ Wk,
    const float* __restrict__ Wv, const float* __restrict__ Wo,
    ushort_t* __restrict__ WtAll)
{
    __shared__ ushort_t T[64][66];
    const int z = blockIdx.z;
    const float* W = (z == 0) ? Wq : (z == 1) ? Wk : (z == 2) ? Wv : Wo;
    ushort_t* dst = WtAll + (size_t)z * DD * DD;
    const int k0 = blockIdx.x * 64, n0 = blockIdx.y * 64;
    const int t = threadIdx.x;
    const int kk = t >> 2, c4 = (t & 3) * 16;
#pragma unroll
    for (int j = 0; j < 4; ++j) {
        float4 v = *(const float4*)&W[(size_t)(k0 + kk) * DD + n0 + c4 + j * 4];
        T[kk][c4 + j * 4 + 0] = f2bf(v.x);
        T[kk][c4 + j * 4 + 1] = f2bf(v.y);
        T[kk][c4 + j * 4 + 2] = f2bf(v.z);
        T[kk][c4 + j * 4 + 3] = f2bf(v.w);
    }
    __syncthreads();
    const int nn = t >> 2, kc = (t & 3) * 16;
    ushort_t tmp[16];
#pragma unroll
    for (int j = 0; j < 16; ++j) tmp[j] = T[kc + j][nn];
    *(uint4*)&dst[(size_t)(n0 + nn) * DD + k0 + kc] = *(uint4*)&tmp[0];
    *(uint4*)&dst[(size_t)(n0 + nn) * DD + k0 + kc + 8] = *(uint4*)&tmp[8];
}

// ---------- 128x128-tile bf16 MFMA GEMM (m93-style LDS staging) ----------
__global__ __launch_bounds__(256) void gemm128_kernel(
    const ushort_t* __restrict__ A, const ushort_t* __restrict__ Bt, int mode,
    const float* __restrict__ bq, const float* __restrict__ bk, const float* __restrict__ bv,
    float* __restrict__ outf,
    ushort_t* __restrict__ q_bf, ushort_t* __restrict__ kbf, ushort_t* __restrict__ vbf,
    float* __restrict__ nk, float* __restrict__ nv)
{
    __shared__ __align__(16) ushort_t As[128 * 32];
    __shared__ __align__(16) ushort_t Bs[128 * 32];
    const int tid = threadIdx.x;
    const int lane = tid & 63, w = tid >> 6;
    const int wm = w >> 1, wn = w & 1;
    const int row16 = lane & 15, quad = lane >> 4;
    const int n0 = blockIdx.x * 128, m0 = blockIdx.y * 128;

    const int r0 = tid >> 2, c0 = (tid & 3) * 8;
    const int r1 = (tid + 256) >> 2, c1 = ((tid + 256) & 3) * 8;

    f32x4 acc[4][4];
#pragma unroll
    for (int i = 0; i < 4; ++i)
#pragma unroll
        for (int j = 0; j < 4; ++j) acc[i][j] = (f32x4){0.f, 0.f, 0.f, 0.f};

    for (int k0 = 0; k0 < DD; k0 += 32) {
        *(uint4*)&As[tid * 8]         = *(const uint4*)&A [(size_t)(m0 + r0) * DD + k0 + c0];
        *(uint4*)&As[(tid + 256) * 8] = *(const uint4*)&A [(size_t)(m0 + r1) * DD + k0 + c1];
        *(uint4*)&Bs[tid * 8]         = *(const uint4*)&Bt[(size_t)(n0 + r0) * DD + k0 + c0];
        *(uint4*)&Bs[(tid + 256) * 8] = *(const uint4*)&Bt[(size_t)(n0 + r1) * DD + k0 + c1];
        __syncthreads();
        bf16x8 af[4], bfr[4];
#pragma unroll
        for (int mt = 0; mt < 4; ++mt)
            af[mt] = *(const bf16x8*)&As[(wm * 64 + mt * 16 + row16) * 32 + quad * 8];
#pragma unroll
        for (int nt = 0; nt < 4; ++nt)
            bfr[nt] = *(const bf16x8*)&Bs[(wn * 64 + nt * 16 + row16) * 32 + quad * 8];
#pragma unroll
        for (int mt = 0; mt < 4; ++mt)
#pragma unroll
            for (int nt = 0; nt < 4; ++nt)
                acc[mt][nt] = __builtin_amdgcn_mfma_f32_16x16x32_bf16(
                    af[mt], bfr[nt], acc[mt][nt], 0, 0, 0);
        __syncthreads();
    }

#pragma unroll
    for (int nt = 0; nt < 4; ++nt) {
        const int nb = n0 + wn * 64 + nt * 16;       // tile-uniform
        if (mode == 0) {
#pragma unroll
            for (int mt = 0; mt < 4; ++mt) {
#pragma unroll
                for (int r = 0; r < 4; ++r) {
                    int m = m0 + wm * 64 + mt * 16 + quad * 4 + r;
                    int n = nb + row16;
                    outf[(size_t)m * DD + n] = acc[mt][nt][r] + bq[n];
                }
            }
        } else {
            const int sel = nb >> 10;
            const float* bias = (sel == 0) ? bq : (sel == 1) ? bk : bv;
#pragma unroll
            for (int mt = 0; mt < 4; ++mt) {
#pragma unroll
                for (int r = 0; r < 4; ++r) {
                    int m = m0 + wm * 64 + mt * 16 + quad * 4 + r;
                    int nn = (nb + row16) & 1023;
                    float v = acc[mt][nt][r] + bias[nn];
                    int b = m >> 11, s = m & (SS - 1);
                    int h = nn >> 6, d = nn & 63;
                    size_t bh = (size_t)b * HH + h;
                    if (sel == 0) {
                        q_bf[(bh * SS + s) * HDD + d] = f2bf(v);
                    } else {
                        ushort_t* dst = (sel == 1) ? kbf : vbf;
                        dst[(bh * KTOT + MEMM + s) * HDD + d] = f2bf(v);
                        if (s >= SS - MEMM) {
                            float* nf = (sel == 1) ? nk : nv;
                            nf[(bh * MEMM + (s - (SS - MEMM))) * HDD + d] = v;
                        }
                    }
                }
            }
        }
    }
}

// ---------- cast past_k/past_v f32 -> bf16 cache heads ----------
__global__ __launch_bounds__(256) void cast_past_kernel(
    const float* __restrict__ pk, const float* __restrict__ pv,
    ushort_t* __restrict__ kbf, ushort_t* __restrict__ vbf)
{
    int idx = blockIdx.x * 256 + threadIdx.x;  // BB*HH*MEMM*HDD = 1048576
    int bh = idx >> 15;
    int rem = idx & 32767;
    size_t dst = (size_t)bh * KTOT * HDD + rem;
    kbf[dst] = f2bf(pk[idx]);
    vbf[dst] = f2bf(pv[idx]);
}

// ---------- transpose V: vbf[bh][k][d] -> vt[bh][d][k] ----------
__global__ __launch_bounds__(256) void transpose_v_kernel(
    const ushort_t* __restrict__ vbf, ushort_t* __restrict__ vt)
{
    __shared__ ushort_t T[64][72];
    const int k0 = blockIdx.x * 64;
    const int bh = blockIdx.y;
    const int t = threadIdx.x;
    const int rr = t >> 3, cc = (t & 7) * 8;
#pragma unroll
    for (int p = 0; p < 2; ++p) {
        int kk = p * 32 + rr;
        *(uint4*)&T[kk][cc] =
            *(const uint4*)(vbf + ((size_t)bh * KTOT + k0 + kk) * HDD + cc);
    }
    __syncthreads();
#pragma unroll
    for (int p = 0; p < 2; ++p) {
        int d = p * 32 + rr;
        ushort_t tmp[8];
#pragma unroll
        for (int j = 0; j < 8; ++j) tmp[j] = T[cc + j][d];
        *(uint4*)(vt + ((size_t)bh * HDD + d) * KTOT + k0 + cc) = *(uint4*)tmp;
    }
}

// ---------- scores: MFMA (K prefetch) + LDS transpose + coalesced store ----------
__global__ __launch_bounds__(256) void score_kernel(
    const ushort_t* __restrict__ qbf, const ushort_t* __restrict__ kbf,
    ushort_t* __restrict__ sbuf, int bh0)
{
    __shared__ __align__(16) ushort_t Ts[64][264];
    const int w = threadIdx.x >> 6, lane = threadIdx.x & 63;
    const int kt = blockIdx.x, qt = blockIdx.y;
    const int lbh = blockIdx.z, bh = bh0 + lbh;
    const int m0 = qt * 64 + w * 16;
    const int row16 = lane & 15, quad = lane >> 4;

    const ushort_t* qrow = qbf + ((size_t)bh * SS + m0 + row16) * HDD + quad * 8;
    bf16x8 a0 = *(const bf16x8*)qrow;
    bf16x8 a1 = *(const bf16x8*)(qrow + 32);
    const ushort_t* kbase = kbf + ((size_t)bh * KTOT + kt * 256 + row16) * HDD + quad * 8;

    bf16x8 b0c = *(const bf16x8*)kbase;
    bf16x8 b1c = *(const bf16x8*)(kbase + 32);
#pragma unroll
    for (int nt = 0; nt < 16; ++nt) {
        bf16x8 b0n, b1n;
        if (nt < 15) {
            const ushort_t* kr = kbase + (size_t)(nt + 1) * 16 * HDD;
            b0n = *(const bf16x8*)kr;
            b1n = *(const bf16x8*)(kr + 32);
        }
        f32x4 acc = {0.f, 0.f, 0.f, 0.f};
        acc = __builtin_amdgcn_mfma_f32_16x16x32_bf16(a0, b0c, acc, 0, 0, 0);
        acc = __builtin_amdgcn_mfma_f32_16x16x32_bf16(a1, b1c, acc, 0, 0, 0);
#pragma unroll
        for (int r = 0; r < 4; ++r)
            Ts[w * 16 + quad * 4 + r][nt * 16 + row16] = f2bf(acc[r] * 0.125f);
        b0c = b0n; b1c = b1n;
    }
    __syncthreads();
    // coalesced store: thread t -> row t>>2, 64-col chunk (t&3)*64
    const int r = threadIdx.x >> 2, c0 = (threadIdx.x & 3) * 64;
    ushort_t* dst = sbuf + ((size_t)lbh * SS + qt * 64 + r) * KTOT + kt * 256 + c0;
#pragma unroll
    for (int j = 0; j < 8; ++j)
        *(uint4*)&dst[j * 8] = *(const uint4*)&Ts[r][c0 + j * 8];
}

// ---------- wave helpers ----------
__device__ __forceinline__ uint32_t wave_iscan(uint32_t x, int lane) {
#pragma unroll
    for (int d = 1; d < 64; d <<= 1) {
        uint32_t t = __shfl_up(x, d, 64);
        if (lane >= d) x += t;
    }
    return x;
}
__device__ __forceinline__ void select_from_counts(
    const uint32_t* c, uint32_t R, int lane, uint32_t* bin_out, uint32_t* rem_out)
{
    uint32_t s = c[0] + c[1] + c[2] + c[3];
    uint32_t incl = wave_iscan(s, lane);
    uint32_t excl = incl - s;
    uint64_t bal = __ballot(incl > R);
    int fl = __ffsll((unsigned long long)bal) - 1;
    uint32_t exf = __shfl(excl, fl, 64);
    uint32_t c0 = __shfl(c[0], fl, 64), c1 = __shfl(c[1], fl, 64);
    uint32_t c2 = __shfl(c[2], fl, 64), c3 = __shfl(c[3], fl, 64);
    uint32_t cc[4] = {c0, c1, c2, c3};
    uint32_t cum = exf, bin = fl * 4, rem = 0;
#pragma unroll
    for (int i = 0; i < 4; ++i) {
        if (cum + cc[i] > R) { bin = fl * 4 + i; rem = R - cum; break; }
        cum += cc[i];
    }
    *bin_out = bin;
    *rem_out = rem;
}

// ---------- per-row quantile (ranks 255,256) + rowmax ----------
__global__ __launch_bounds__(256) void quant_kernel(
    const ushort_t* __restrict__ sbuf, float* __restrict__ thr_out,
    float* __restrict__ max_out, int bh0)
{
    __shared__ uint32_t hist[4][1028];   // [wave][replica*257 + bin]
    const int w = threadIdx.x >> 6, lane = threadIdx.x & 63;
    const int rep = lane >> 4;
    uint32_t* H = hist[w];
    const int lrow = blockIdx.x * 4 + w;
    const size_t grow = (size_t)bh0 * SS + lrow;
    const ushort_t* src = sbuf + (size_t)lrow * KTOT;

    uint32_t key[40];
    uint32_t maxkey = 0;
#pragma unroll
    for (int c = 0; c < 5; ++c) {
        uint4 p = *(const uint4*)(src + c * 512 + lane * 8);
        uint32_t u[8] = {p.x & 0xFFFFu, p.x >> 16, p.y & 0xFFFFu, p.y >> 16,
                         p.z & 0xFFFFu, p.z >> 16, p.w & 0xFFFFu, p.w >> 16};
#pragma unroll
        for (int j = 0; j < 8; ++j) {
            uint32_t k = mapkey(u[j]);
            key[c * 8 + j] = k;
            maxkey = max(maxkey, k);
        }
    }
#pragma unroll
    for (int d = 1; d < 64; d <<= 1)
        maxkey = max(maxkey, (uint32_t)__shfl_xor(maxkey, d, 64));

    for (int i = lane; i < 1028; i += 64) H[i] = 0u;
    __threadfence_block();
#pragma unroll
    for (int i = 0; i < 40; ++i) atomicAdd(&H[rep * 257 + (key[i] >> 8)], 1u);
    __threadfence_block();
    uint32_t c[4];
#pragma unroll
    for (int i = 0; i < 4; ++i)
        c[i] = H[lane * 4 + i] + H[257 + lane * 4 + i]
             + H[514 + lane * 4 + i] + H[771 + lane * 4 + i];
    uint32_t binA, remA, binB, remB;
    select_from_counts(c, 255u, lane, &binA, &remA);
    select_from_counts(c, 256u, lane, &binB, &remB);

    for (int i = lane; i < 1028; i += 64) H[i] = 0u;
    __threadfence_block();
#pragma unroll
    for (int i = 0; i < 40; ++i) {
        uint32_t k = key[i];
        if ((k >> 8) == binA) atomicAdd(&H[rep * 257 + (k & 255u)], 1u);
    }
    __threadfence_block();
#pragma unroll
    for (int i = 0; i < 4; ++i)
        c[i] = H[lane * 4 + i] + H[257 + lane * 4 + i]
             + H[514 + lane * 4 + i] + H[771 + lane * 4 + i];
    uint32_t lowA, rA, lowB, rB;
    select_from_counts(c, remA, lane, &lowA, &rA);
    if (binB == binA) {
        select_from_counts(c, remB, lane, &lowB, &rB);
    } else {
        for (int i = lane; i < 1028; i += 64) H[i] = 0u;
        __threadfence_block();
#pragma unroll
        for (int i = 0; i < 40; ++i) {
            uint32_t k = key[i];
            if ((k >> 8) == binB) atomicAdd(&H[rep * 257 + (k & 255u)], 1u);
        }
        __threadfence_block();
#pragma unroll
        for (int i = 0; i < 4; ++i)
            c[i] = H[lane * 4 + i] + H[257 + lane * 4 + i]
                 + H[514 + lane * 4 + i] + H[771 + lane * 4 + i];
        select_from_counts(c, remB, lane, &lowB, &rB);
    }

    if (lane == 0) {
        float thrA = bf2f(unmapkey((binA << 8) | lowA));
        float thrB = bf2f(unmapkey((binB << 8) | lowB));
        thr_out[grow] = thrA + 0.9f * (thrB - thrA);
        max_out[grow] = bf2f(unmapkey(maxkey));
    }
}

// ---------- softmax + PV, barrier-free: wave = 16-row stripe, no LDS ----------
// A-frag (m=lane&15, k=quad*8+j) => each lane's 8 scores are one row -> exp
// transform in registers. Register double-buffered A/B/mask prefetch.
__global__ __launch_bounds__(256) void pv_kernel(
    const ushort_t* __restrict__ sbuf, const ushort_t* __restrict__ vt,
    const float* __restrict__ thr_arr, const float* __restrict__ max_arr,
    const int* __restrict__ amask, ushort_t* __restrict__ attn_bf, int bh0)
{
    const int tid = threadIdx.x;
    const int lane = tid & 63, w = tid >> 6;
    const int row16 = lane & 15, quad = lane >> 4;
    const int qt = blockIdx.x;
    const int lbh = blockIdx.y, bh = bh0 + lbh;
    const int b = bh >> 4, h = bh & 15;
    const int m0 = qt * 64 + w * 16;     // this wave's first row

    const ushort_t* arow = sbuf + ((size_t)lbh * SS + m0 + row16) * KTOT + quad * 8;
    const ushort_t* brow = vt + ((size_t)bh * HDD + row16) * KTOT + quad * 8;
    const float thr = thr_arr[(size_t)bh * SS + m0 + row16];
    const float mx  = max_arr[(size_t)bh * SS + m0 + row16];
    const int* amq = amask + b * SS + quad * 8;   // + (k0 - MEMM) per step

    f32x4 acc[4];
#pragma unroll
    for (int i = 0; i < 4; ++i) acc[i] = (f32x4){0.f, 0.f, 0.f, 0.f};
    float psum = 0.f;

    uint4 a_nxt = *(const uint4*)arow;
    uint4 b_nxt[4];
#pragma unroll
    for (int nt = 0; nt < 4; ++nt)
        b_nxt[nt] = *(const uint4*)(brow + (size_t)nt * 16 * KTOT);
    int4 m_nxt0 = {1, 1, 1, 1}, m_nxt1 = {1, 1, 1, 1};

    for (int k0 = 0; k0 < KTOT; k0 += 32) {
        uint4 a_cur = a_nxt;
        uint4 b_cur[4] = {b_nxt[0], b_nxt[1], b_nxt[2], b_nxt[3]};
        int4 mc0 = m_nxt0, mc1 = m_nxt1;
        const int kn = k0 + 32;
        if (kn < KTOT) {
            a_nxt = *(const uint4*)(arow + kn);
#pragma unroll
            for (int nt = 0; nt < 4; ++nt)
                b_nxt[nt] = *(const uint4*)(brow + (size_t)nt * 16 * KTOT + kn);
            if (kn >= MEMM) {
                m_nxt0 = *(const int4*)(amq + kn - MEMM);
                m_nxt1 = *(const int4*)(amq + kn - MEMM + 4);
            }
        }
        // transform: scores -> thresholded exp weights (bf16 A-frag)
        uint32_t u[8] = {a_cur.x & 0xFFFFu, a_cur.x >> 16, a_cur.y & 0xFFFFu, a_cur.y >> 16,
                         a_cur.z & 0xFFFFu, a_cur.z >> 16, a_cur.w & 0xFFFFu, a_cur.w >> 16};
        int mm[8] = {mc0.x, mc0.y, mc0.z, mc0.w, mc1.x, mc1.y, mc1.z, mc1.w};
        const bool masked = (k0 >= MEMM);
        ushort_t wb[8];
        float ps = 0.f;
#pragma unroll
        for (int j = 0; j < 8; ++j) {
            float s = bf2f(u[j]);
            bool keep = (s >= thr);
            if (masked) keep = keep && (mm[j] != 0);
            float wv = keep ? __expf(s - mx) : 0.f;
            ushort_t q = f2bf(wv);
            wb[j] = q;
            ps += bf2f((uint32_t)q);
        }
        psum += ps;
        uint4 aq;
        aq.x = (uint32_t)wb[0] | ((uint32_t)wb[1] << 16);
        aq.y = (uint32_t)wb[2] | ((uint32_t)wb[3] << 16);
        aq.z = (uint32_t)wb[4] | ((uint32_t)wb[5] << 16);
        aq.w = (uint32_t)wb[6] | ((uint32_t)wb[7] << 16);
        bf16x8 af;
        *(uint4*)&af = aq;
#pragma unroll
        for (int nt = 0; nt < 4; ++nt) {
            bf16x8 bf;
            *(uint4*)&bf = b_cur[nt];
            acc[nt] = __builtin_amdgcn_mfma_f32_16x16x32_bf16(af, bf, acc[nt], 0, 0, 0);
        }
    }

    // row sums: lanes {row16, row16+16, +32, +48} hold partials of row row16
    psum += __shfl_xor(psum, 16, 64);
    psum += __shfl_xor(psum, 32, 64);
    // lane L (L<16) now holds rsum for row L (also replicated in L+16,...)

#pragma unroll
    for (int nt = 0; nt < 4; ++nt) {
#pragma unroll
        for (int r = 0; r < 4; ++r) {
            int row = quad * 4 + r;
            float rs = __shfl(psum, row, 64);
            float val = acc[nt][r] / rs;
            attn_bf[((size_t)b * SS + m0 + row) * DD + h * HDD + nt * 16 + row16] = f2bf(val);
        }
    }
}

extern "C" void kernel_launch(void* const* d_in, const int* in_sizes, int n_in,
                              void* d_out, int out_size, void* d_ws, size_t ws_size,
                              hipStream_t stream)
{
    const float* hidden = (const float*)d_in[0];
    const int*   amask  = (const int*)d_in[1];
    const float* past_k = (const float*)d_in[2];
    const float* past_v = (const float*)d_in[3];
    const float* Wq = (const float*)d_in[4];
    const float* bq = (const float*)d_in[5];
    const float* Wk = (const float*)d_in[6];
    const float* bk = (const float*)d_in[7];
    const float* Wv = (const float*)d_in[8];
    const float* bv = (const float*)d_in[9];
    const float* Wo = (const float*)d_in[10];
    const float* bo = (const float*)d_in[11];

    float* out    = (float*)d_out;
    float* nk_out = out + (size_t)BB * SS * DD;
    float* nv_out = nk_out + (size_t)BB * HH * MEMM * HDD;

    char* base = (char*)d_ws;
    size_t off = 0;
    auto alloc = [&](size_t bytes) {
        char* p = base + off;
        off += (bytes + 255) & ~(size_t)255;
        return p;
    };
    ushort_t* hb    = (ushort_t*)alloc((size_t)BB * SS * DD * 2);            // 8 MB
    ushort_t* WtAll = (ushort_t*)alloc((size_t)4 * DD * DD * 2);             // 8 MB
    ushort_t* q_bf  = (ushort_t*)alloc((size_t)BB * HH * SS * HDD * 2);      // 8 MB
    ushort_t* kbf   = (ushort_t*)alloc((size_t)BB * HH * KTOT * HDD * 2);    // 10 MB
    ushort_t* vbf   = (ushort_t*)alloc((size_t)BB * HH * KTOT * HDD * 2);    // 10 MB
    ushort_t* vt    = (ushort_t*)alloc((size_t)BB * HH * HDD * KTOT * 2);    // 10 MB
    ushort_t* abf   = (ushort_t*)alloc((size_t)BB * SS * DD * 2);            // 8 MB
    float* thr_arr  = (float*)alloc((size_t)NROWS * 4);
    float* max_arr  = (float*)alloc((size_t)NROWS * 4);
    size_t fixed = off;
    const size_t sbuf_full = (size_t)BB * HH * SS * KTOT * 2;                // 335.5 MB
    int nchunks = 32;
    for (int c = 1; c <= 32; c <<= 1) {
        if (fixed + sbuf_full / c + 256 <= ws_size) { nchunks = c; break; }
    }
    ushort_t* sbuf = (ushort_t*)alloc(sbuf_full / nchunks);
    const int bhpc = (BB * HH) / nchunks;

    dim3 blk(256);

    cast_hidden_kernel<<<dim3(1024), blk, 0, stream>>>(hidden, hb);
    transw_kernel<<<dim3(16, 16, 4), blk, 0, stream>>>(Wq, Wk, Wv, Wo, WtAll);
    // fused QKV: one GEMM, N=3072 (Wq|Wk|Wv transposes adjacent in WtAll)
    gemm128_kernel<<<dim3(24, 32), blk, 0, stream>>>(
        hb, WtAll, 1, bq, bk, bv, nullptr, q_bf, kbf, vbf, nk_out, nv_out);
    cast_past_kernel<<<dim3(4096), blk, 0, stream>>>(past_k, past_v, kbf, vbf);
    transpose_v_kernel<<<dim3(KTOT / 64, BB * HH), blk, 0, stream>>>(vbf, vt);

    for (int ci = 0; ci < nchunks; ++ci) {
        int bh0 = ci * bhpc;
        score_kernel<<<dim3(KTOT / 256, SS / 64, bhpc), blk, 0, stream>>>(q_bf, kbf, sbuf, bh0);
        quant_kernel<<<dim3(bhpc * (SS / 4)), blk, 0, stream>>>(sbuf, thr_arr, max_arr, bh0);
        pv_kernel<<<dim3(SS / 64, bhpc), blk, 0, stream>>>(sbuf, vt, thr_arr, max_arr,
                                                           amask, abf, bh0);
    }
    // O-projection
    gemm128_kernel<<<dim3(8, 32), blk, 0, stream>>>(
        abf, WtAll + (size_t)3 * DD * DD, 0, bo, nullptr, nullptr, out,
        nullptr, nullptr, nullptr, nullptr, nullptr);
}

// Round 8
// 821.040 us; speedup vs baseline: 5.5566x; 1.0927x over previous
//
#include <hip/hip_runtime.h>
#include <stdint.h>

typedef unsigned short ushort_t;
typedef __attribute__((ext_vector_type(8))) short bf16x8;
typedef __attribute__((ext_vector_type(4))) float f32x4;

#define BB 2
#define SS 2048
#define DD 1024
#define HH 16
#define HDD 64
#define MEMM 512
#define KTOT 2560   // MEMM + SS
#define NROWS (BB*HH*SS)   // 65536 score rows

// ---------- helpers ----------
__device__ __forceinline__ float bf2f(uint32_t u) {
    return __uint_as_float(u << 16);
}
__device__ __forceinline__ ushort_t f2bf(float f) {
    uint32_t u = __float_as_uint(f);
    uint32_t r = (u + 0x7FFFu + ((u >> 16) & 1u)) >> 16;
    return (ushort_t)r;
}
__device__ __forceinline__ uint32_t mapkey(uint32_t u) {
    return (u & 0x8000u) ? (0xFFFFu ^ u) : (u | 0x8000u);
}
__device__ __forceinline__ uint32_t unmapkey(uint32_t k) {
    return (k & 0x8000u) ? (k ^ 0x8000u) : (0xFFFFu ^ k);
}

// ---------- cast hidden f32 -> bf16 ----------
__global__ __launch_bounds__(256) void cast_hidden_kernel(
    const float* __restrict__ h, ushort_t* __restrict__ hb)
{
    size_t i0 = ((size_t)blockIdx.x * 256 + threadIdx.x) * 16;  // 4M elems / 16
    ushort_t o[16];
#pragma unroll
    for (int j = 0; j < 4; ++j) {
        float4 v = *(const float4*)&h[i0 + j * 4];
        o[j * 4 + 0] = f2bf(v.x); o[j * 4 + 1] = f2bf(v.y);
        o[j * 4 + 2] = f2bf(v.z); o[j * 4 + 3] = f2bf(v.w);
    }
    *(uint4*)&hb[i0] = *(uint4*)&o[0];
    *(uint4*)&hb[i0 + 8] = *(uint4*)&o[8];
}

// ---------- transpose+cast weights: W[k][n] f32 -> Wt[n][k] bf16 ----------
__global__ __launch_bounds__(256) void transw_kernel(
    const float* __restrict__ Wq, const float* __restrict__ Wk,
    const float* __restrict__ Wv, const float* __restrict__ Wo,
    ushort_t* __restrict__ WtAll)
{
    __shared__ ushort_t T[64][66];
    const int z = blockIdx.z;
    const float* W = (z == 0) ? Wq : (z == 1) ? Wk : (z == 2) ? Wv : Wo;
    ushort_t* dst = WtAll + (size_t)z * DD * DD;
    const int k0 = blockIdx.x * 64, n0 = blockIdx.y * 64;
    const int t = threadIdx.x;
    const int kk = t >> 2, c4 = (t & 3) * 16;
#pragma unroll
    for (int j = 0; j < 4; ++j) {
        float4 v = *(const float4*)&W[(size_t)(k0 + kk) * DD + n0 + c4 + j * 4];
        T[kk][c4 + j * 4 + 0] = f2bf(v.x);
        T[kk][c4 + j * 4 + 1] = f2bf(v.y);
        T[kk][c4 + j * 4 + 2] = f2bf(v.z);
        T[kk][c4 + j * 4 + 3] = f2bf(v.w);
    }
    __syncthreads();
    const int nn = t >> 2, kc = (t & 3) * 16;
    ushort_t tmp[16];
#pragma unroll
    for (int j = 0; j < 16; ++j) tmp[j] = T[kc + j][nn];
    *(uint4*)&dst[(size_t)(n0 + nn) * DD + k0 + kc] = *(uint4*)&tmp[0];
    *(uint4*)&dst[(size_t)(n0 + nn) * DD + k0 + kc + 8] = *(uint4*)&tmp[8];
}

// ---------- 128x128-tile bf16 MFMA GEMM (m93-style LDS staging) ----------
__global__ __launch_bounds__(256) void gemm128_kernel(
    const ushort_t* __restrict__ A, const ushort_t* __restrict__ Bt, int mode,
    const float* __restrict__ bq, const float* __restrict__ bk, const float* __restrict__ bv,
    float* __restrict__ outf,
    ushort_t* __restrict__ q_bf, ushort_t* __restrict__ kbf, ushort_t* __restrict__ vbf,
    float* __restrict__ nk, float* __restrict__ nv)
{
    __shared__ __align__(16) ushort_t As[128 * 32];
    __shared__ __align__(16) ushort_t Bs[128 * 32];
    const int tid = threadIdx.x;
    const int lane = tid & 63, w = tid >> 6;
    const int wm = w >> 1, wn = w & 1;
    const int row16 = lane & 15, quad = lane >> 4;
    const int n0 = blockIdx.x * 128, m0 = blockIdx.y * 128;

    const int r0 = tid >> 2, c0 = (tid & 3) * 8;
    const int r1 = (tid + 256) >> 2, c1 = ((tid + 256) & 3) * 8;

    f32x4 acc[4][4];
#pragma unroll
    for (int i = 0; i < 4; ++i)
#pragma unroll
        for (int j = 0; j < 4; ++j) acc[i][j] = (f32x4){0.f, 0.f, 0.f, 0.f};

    for (int k0 = 0; k0 < DD; k0 += 32) {
        *(uint4*)&As[tid * 8]         = *(const uint4*)&A [(size_t)(m0 + r0) * DD + k0 + c0];
        *(uint4*)&As[(tid + 256) * 8] = *(const uint4*)&A [(size_t)(m0 + r1) * DD + k0 + c1];
        *(uint4*)&Bs[tid * 8]         = *(const uint4*)&Bt[(size_t)(n0 + r0) * DD + k0 + c0];
        *(uint4*)&Bs[(tid + 256) * 8] = *(const uint4*)&Bt[(size_t)(n0 + r1) * DD + k0 + c1];
        __syncthreads();
        bf16x8 af[4], bfr[4];
#pragma unroll
        for (int mt = 0; mt < 4; ++mt)
            af[mt] = *(const bf16x8*)&As[(wm * 64 + mt * 16 + row16) * 32 + quad * 8];
#pragma unroll
        for (int nt = 0; nt < 4; ++nt)
            bfr[nt] = *(const bf16x8*)&Bs[(wn * 64 + nt * 16 + row16) * 32 + quad * 8];
#pragma unroll
        for (int mt = 0; mt < 4; ++mt)
#pragma unroll
            for (int nt = 0; nt < 4; ++nt)
                acc[mt][nt] = __builtin_amdgcn_mfma_f32_16x16x32_bf16(
                    af[mt], bfr[nt], acc[mt][nt], 0, 0, 0);
        __syncthreads();
    }

#pragma unroll
    for (int nt = 0; nt < 4; ++nt) {
        const int nb = n0 + wn * 64 + nt * 16;       // tile-uniform
        if (mode == 0) {
#pragma unroll
            for (int mt = 0; mt < 4; ++mt) {
#pragma unroll
                for (int r = 0; r < 4; ++r) {
                    int m = m0 + wm * 64 + mt * 16 + quad * 4 + r;
                    int n = nb + row16;
                    outf[(size_t)m * DD + n] = acc[mt][nt][r] + bq[n];
                }
            }
        } else {
            const int sel = nb >> 10;
            const float* bias = (sel == 0) ? bq : (sel == 1) ? bk : bv;
#pragma unroll
            for (int mt = 0; mt < 4; ++mt) {
#pragma unroll
                for (int r = 0; r < 4; ++r) {
                    int m = m0 + wm * 64 + mt * 16 + quad * 4 + r;
                    int nn = (nb + row16) & 1023;
                    float v = acc[mt][nt][r] + bias[nn];
                    int b = m >> 11, s = m & (SS - 1);
                    int h = nn >> 6, d = nn & 63;
                    size_t bh = (size_t)b * HH + h;
                    if (sel == 0) {
                        q_bf[(bh * SS + s) * HDD + d] = f2bf(v);
                    } else {
                        ushort_t* dst = (sel == 1) ? kbf : vbf;
                        dst[(bh * KTOT + MEMM + s) * HDD + d] = f2bf(v);
                        if (s >= SS - MEMM) {
                            float* nf = (sel == 1) ? nk : nv;
                            nf[(bh * MEMM + (s - (SS - MEMM))) * HDD + d] = v;
                        }
                    }
                }
            }
        }
    }
}

// ---------- cast past_k/past_v f32 -> bf16 cache heads ----------
__global__ __launch_bounds__(256) void cast_past_kernel(
    const float* __restrict__ pk, const float* __restrict__ pv,
    ushort_t* __restrict__ kbf, ushort_t* __restrict__ vbf)
{
    int idx = blockIdx.x * 256 + threadIdx.x;  // BB*HH*MEMM*HDD = 1048576
    int bh = idx >> 15;
    int rem = idx & 32767;
    size_t dst = (size_t)bh * KTOT * HDD + rem;
    kbf[dst] = f2bf(pk[idx]);
    vbf[dst] = f2bf(pv[idx]);
}

// ---------- transpose V: vbf[bh][k][d] -> vt[bh][d][k] ----------
__global__ __launch_bounds__(256) void transpose_v_kernel(
    const ushort_t* __restrict__ vbf, ushort_t* __restrict__ vt)
{
    __shared__ ushort_t T[64][72];
    const int k0 = blockIdx.x * 64;
    const int bh = blockIdx.y;
    const int t = threadIdx.x;
    const int rr = t >> 3, cc = (t & 7) * 8;
#pragma unroll
    for (int p = 0; p < 2; ++p) {
        int kk = p * 32 + rr;
        *(uint4*)&T[kk][cc] =
            *(const uint4*)(vbf + ((size_t)bh * KTOT + k0 + kk) * HDD + cc);
    }
    __syncthreads();
#pragma unroll
    for (int p = 0; p < 2; ++p) {
        int d = p * 32 + rr;
        ushort_t tmp[8];
#pragma unroll
        for (int j = 0; j < 8; ++j) tmp[j] = T[cc + j][d];
        *(uint4*)(vt + ((size_t)bh * HDD + d) * KTOT + k0 + cc) = *(uint4*)tmp;
    }
}

// ---------- scores: MFMA (K prefetch) + LDS transpose + coalesced store ----------
__global__ __launch_bounds__(256) void score_kernel(
    const ushort_t* __restrict__ qbf, const ushort_t* __restrict__ kbf,
    ushort_t* __restrict__ sbuf, int bh0)
{
    __shared__ __align__(16) ushort_t Ts[64][264];
    const int w = threadIdx.x >> 6, lane = threadIdx.x & 63;
    const int kt = blockIdx.x, qt = blockIdx.y;
    const int lbh = blockIdx.z, bh = bh0 + lbh;
    const int m0 = qt * 64 + w * 16;
    const int row16 = lane & 15, quad = lane >> 4;

    const ushort_t* qrow = qbf + ((size_t)bh * SS + m0 + row16) * HDD + quad * 8;
    bf16x8 a0 = *(const bf16x8*)qrow;
    bf16x8 a1 = *(const bf16x8*)(qrow + 32);
    const ushort_t* kbase = kbf + ((size_t)bh * KTOT + kt * 256 + row16) * HDD + quad * 8;

    bf16x8 b0c = *(const bf16x8*)kbase;
    bf16x8 b1c = *(const bf16x8*)(kbase + 32);
#pragma unroll
    for (int nt = 0; nt < 16; ++nt) {
        bf16x8 b0n, b1n;
        if (nt < 15) {
            const ushort_t* kr = kbase + (size_t)(nt + 1) * 16 * HDD;
            b0n = *(const bf16x8*)kr;
            b1n = *(const bf16x8*)(kr + 32);
        }
        f32x4 acc = {0.f, 0.f, 0.f, 0.f};
        acc = __builtin_amdgcn_mfma_f32_16x16x32_bf16(a0, b0c, acc, 0, 0, 0);
        acc = __builtin_amdgcn_mfma_f32_16x16x32_bf16(a1, b1c, acc, 0, 0, 0);
#pragma unroll
        for (int r = 0; r < 4; ++r)
            Ts[w * 16 + quad * 4 + r][nt * 16 + row16] = f2bf(acc[r] * 0.125f);
        b0c = b0n; b1c = b1n;
    }
    __syncthreads();
    // coalesced store: thread t -> row t>>2, 64-col chunk (t&3)*64
    const int r = threadIdx.x >> 2, c0 = (threadIdx.x & 3) * 64;
    ushort_t* dst = sbuf + ((size_t)lbh * SS + qt * 64 + r) * KTOT + kt * 256 + c0;
#pragma unroll
    for (int j = 0; j < 8; ++j)
        *(uint4*)&dst[j * 8] = *(const uint4*)&Ts[r][c0 + j * 8];
}

// ---------- wave helpers ----------
__device__ __forceinline__ uint32_t wave_iscan(uint32_t x, int lane) {
#pragma unroll
    for (int d = 1; d < 64; d <<= 1) {
        uint32_t t = __shfl_up(x, d, 64);
        if (lane >= d) x += t;
    }
    return x;
}
__device__ __forceinline__ void select_from_counts(
    const uint32_t* c, uint32_t R, int lane, uint32_t* bin_out, uint32_t* rem_out)
{
    uint32_t s = c[0] + c[1] + c[2] + c[3];
    uint32_t incl = wave_iscan(s, lane);
    uint32_t excl = incl - s;
    uint64_t bal = __ballot(incl > R);
    int fl = __ffsll((unsigned long long)bal) - 1;
    uint32_t exf = __shfl(excl, fl, 64);
    uint32_t c0 = __shfl(c[0], fl, 64), c1 = __shfl(c[1], fl, 64);
    uint32_t c2 = __shfl(c[2], fl, 64), c3 = __shfl(c[3], fl, 64);
    uint32_t cc[4] = {c0, c1, c2, c3};
    uint32_t cum = exf, bin = fl * 4, rem = 0;
#pragma unroll
    for (int i = 0; i < 4; ++i) {
        if (cum + cc[i] > R) { bin = fl * 4 + i; rem = R - cum; break; }
        cum += cc[i];
    }
    *bin_out = bin;
    *rem_out = rem;
}

// ---------- per-row quantile (ranks 255,256) + rowmax ----------
// 1 wave per row, no barriers. Hot bins (|x| in [0.125,8), ~92% of N(0,1)
// mass: mapped top-bytes 0x3F,0x40,0x41,0xBE,0xBF,0xC0) counted in packed
// per-lane registers + shfl reduce -> no LDS same-address serialization.
// Cold keys (~8%) -> 4x-replicated LDS histogram (stride 260 words).
__global__ __launch_bounds__(256) void quant_kernel(
    const ushort_t* __restrict__ sbuf, float* __restrict__ thr_out,
    float* __restrict__ max_out, int bh0)
{
    __shared__ __align__(16) uint32_t hist[4][1040];   // [wave][replica*260 + bin]
    const int w = threadIdx.x >> 6, lane = threadIdx.x & 63;
    const int rep = lane >> 4;
    uint32_t* H = hist[w];
    const int lrow = blockIdx.x * 4 + w;
    const size_t grow = (size_t)bh0 * SS + lrow;
    const ushort_t* src = sbuf + (size_t)lrow * KTOT;

    // load 40 keys (mapped), track max
    uint32_t key[40];
    uint32_t maxkey = 0;
#pragma unroll
    for (int c = 0; c < 5; ++c) {
        uint4 p = *(const uint4*)(src + c * 512 + lane * 8);
        uint32_t u[8] = {p.x & 0xFFFFu, p.x >> 16, p.y & 0xFFFFu, p.y >> 16,
                         p.z & 0xFFFFu, p.z >> 16, p.w & 0xFFFFu, p.w >> 16};
#pragma unroll
        for (int j = 0; j < 8; ++j) {
            uint32_t k = mapkey(u[j]);
            key[c * 8 + j] = k;
            maxkey = max(maxkey, k);
        }
    }
#pragma unroll
    for (int d = 1; d < 64; d <<= 1)
        maxkey = max(maxkey, (uint32_t)__shfl_xor(maxkey, d, 64));

    // ---- zero cold hist (vectorized) ----
    const uint4 z4 = {0u, 0u, 0u, 0u};
#pragma unroll
    for (int i = 0; i < 4; ++i) *(uint4*)&H[lane * 4 + i * 256] = z4;
    if (lane < 4) *(uint4*)&H[1024 + lane * 4] = z4;
    __threadfence_block();

    // ---- pass 1: hot bins in packed regs, cold bins via LDS atomics ----
    uint32_t accN = 0u, accP = 0u;   // 3 x 10-bit fields each
#pragma unroll
    for (int i = 0; i < 40; ++i) {
        uint32_t k = key[i];
        uint32_t t = k >> 8;
        uint32_t iN = t - 0x3Fu;
        uint32_t iP = t - 0xBEu;
        bool hN = (iN <= 2u);
        bool hP = (iP <= 2u);
        accN += hN ? (1u << (min(iN, 3u) * 10u)) : 0u;
        accP += hP ? (1u << (min(iP, 3u) * 10u)) : 0u;
        if (!(hN || hP)) atomicAdd(&H[rep * 260 + t], 1u);
    }
    // unpack + wave-reduce 6 hot counters
    uint32_t hc[6];
    hc[0] = accN & 0x3FFu; hc[1] = (accN >> 10) & 0x3FFu; hc[2] = (accN >> 20) & 0x3FFu;
    hc[3] = accP & 0x3FFu; hc[4] = (accP >> 10) & 0x3FFu; hc[5] = (accP >> 20) & 0x3FFu;
#pragma unroll
    for (int j = 0; j < 6; ++j)
#pragma unroll
        for (int d = 1; d < 64; d <<= 1)
            hc[j] += (uint32_t)__shfl_xor(hc[j], d, 64);
    __threadfence_block();

    // ---- selection counts: cold (LDS, 4 replicas) + hot injections ----
    uint32_t c[4];
#pragma unroll
    for (int i = 0; i < 4; ++i)
        c[i] = H[lane * 4 + i] + H[260 + lane * 4 + i]
             + H[520 + lane * 4 + i] + H[780 + lane * 4 + i];
    // hot bins: 0x3F->(l15,i3) 0x40->(l16,i0) 0x41->(l16,i1)
    //           0xBE->(l47,i2) 0xBF->(l47,i3) 0xC0->(l48,i0)
    c[3] += (lane == 15) ? hc[0] : 0u;
    c[0] += (lane == 16) ? hc[1] : 0u;
    c[1] += (lane == 16) ? hc[2] : 0u;
    c[2] += (lane == 47) ? hc[3] : 0u;
    c[3] += (lane == 47) ? hc[4] : 0u;
    c[0] += (lane == 48) ? hc[5] : 0u;

    uint32_t binA, remA, binB, remB;
    select_from_counts(c, 255u, lane, &binA, &remA);
    select_from_counts(c, 256u, lane, &binB, &remB);

    // ---- pass 2: low-byte histogram of binA (low bytes ~uniform) ----
#pragma unroll
    for (int i = 0; i < 4; ++i) *(uint4*)&H[lane * 4 + i * 256] = z4;
    if (lane < 4) *(uint4*)&H[1024 + lane * 4] = z4;
    __threadfence_block();
#pragma unroll
    for (int i = 0; i < 40; ++i) {
        uint32_t k = key[i];
        if ((k >> 8) == binA) atomicAdd(&H[rep * 260 + (k & 255u)], 1u);
    }
    __threadfence_block();
#pragma unroll
    for (int i = 0; i < 4; ++i)
        c[i] = H[lane * 4 + i] + H[260 + lane * 4 + i]
             + H[520 + lane * 4 + i] + H[780 + lane * 4 + i];
    uint32_t lowA, rA, lowB, rB;
    select_from_counts(c, remA, lane, &lowA, &rA);
    if (binB == binA) {
        select_from_counts(c, remB, lane, &lowB, &rB);
    } else {
        // rare: rebuild for binB (wave-uniform branch)
#pragma unroll
        for (int i = 0; i < 4; ++i) *(uint4*)&H[lane * 4 + i * 256] = z4;
        if (lane < 4) *(uint4*)&H[1024 + lane * 4] = z4;
        __threadfence_block();
#pragma unroll
        for (int i = 0; i < 40; ++i) {
            uint32_t k = key[i];
            if ((k >> 8) == binB) atomicAdd(&H[rep * 260 + (k & 255u)], 1u);
        }
        __threadfence_block();
#pragma unroll
        for (int i = 0; i < 4; ++i)
            c[i] = H[lane * 4 + i] + H[260 + lane * 4 + i]
                 + H[520 + lane * 4 + i] + H[780 + lane * 4 + i];
        select_from_counts(c, remB, lane, &lowB, &rB);
    }

    if (lane == 0) {
        float thrA = bf2f(unmapkey((binA << 8) | lowA));
        float thrB = bf2f(unmapkey((binB << 8) | lowB));
        thr_out[grow] = thrA + 0.9f * (thrB - thrA);
        max_out[grow] = bf2f(unmapkey(maxkey));
    }
}

// ---------- softmax + PV, barrier-free: wave = 16-row stripe, no LDS ----------
__global__ __launch_bounds__(256) void pv_kernel(
    const ushort_t* __restrict__ sbuf, const ushort_t* __restrict__ vt,
    const float* __restrict__ thr_arr, const float* __restrict__ max_arr,
    const int* __restrict__ amask, ushort_t* __restrict__ attn_bf, int bh0)
{
    const int tid = threadIdx.x;
    const int lane = tid & 63, w = tid >> 6;
    const int row16 = lane & 15, quad = lane >> 4;
    const int qt = blockIdx.x;
    const int lbh = blockIdx.y, bh = bh0 + lbh;
    const int b = bh >> 4, h = bh & 15;
    const int m0 = qt * 64 + w * 16;     // this wave's first row

    const ushort_t* arow = sbuf + ((size_t)lbh * SS + m0 + row16) * KTOT + quad * 8;
    const ushort_t* brow = vt + ((size_t)bh * HDD + row16) * KTOT + quad * 8;
    const float thr = thr_arr[(size_t)bh * SS + m0 + row16];
    const float mx  = max_arr[(size_t)bh * SS + m0 + row16];
    const int* amq = amask + b * SS + quad * 8;   // + (k0 - MEMM) per step

    f32x4 acc[4];
#pragma unroll
    for (int i = 0; i < 4; ++i) acc[i] = (f32x4){0.f, 0.f, 0.f, 0.f};
    float psum = 0.f;

    uint4 a_nxt = *(const uint4*)arow;
    uint4 b_nxt[4];
#pragma unroll
    for (int nt = 0; nt < 4; ++nt)
        b_nxt[nt] = *(const uint4*)(brow + (size_t)nt * 16 * KTOT);
    int4 m_nxt0 = {1, 1, 1, 1}, m_nxt1 = {1, 1, 1, 1};

    for (int k0 = 0; k0 < KTOT; k0 += 32) {
        uint4 a_cur = a_nxt;
        uint4 b_cur[4] = {b_nxt[0], b_nxt[1], b_nxt[2], b_nxt[3]};
        int4 mc0 = m_nxt0, mc1 = m_nxt1;
        const int kn = k0 + 32;
        if (kn < KTOT) {
            a_nxt = *(const uint4*)(arow + kn);
#pragma unroll
            for (int nt = 0; nt < 4; ++nt)
                b_nxt[nt] = *(const uint4*)(brow + (size_t)nt * 16 * KTOT + kn);
            if (kn >= MEMM) {
                m_nxt0 = *(const int4*)(amq + kn - MEMM);
                m_nxt1 = *(const int4*)(amq + kn - MEMM + 4);
            }
        }
        uint32_t u[8] = {a_cur.x & 0xFFFFu, a_cur.x >> 16, a_cur.y & 0xFFFFu, a_cur.y >> 16,
                         a_cur.z & 0xFFFFu, a_cur.z >> 16, a_cur.w & 0xFFFFu, a_cur.w >> 16};
        int mm[8] = {mc0.x, mc0.y, mc0.z, mc0.w, mc1.x, mc1.y, mc1.z, mc1.w};
        const bool masked = (k0 >= MEMM);
        ushort_t wb[8];
        float ps = 0.f;
#pragma unroll
        for (int j = 0; j < 8; ++j) {
            float s = bf2f(u[j]);
            bool keep = (s >= thr);
            if (masked) keep = keep && (mm[j] != 0);
            float wv = keep ? __expf(s - mx) : 0.f;
            ushort_t q = f2bf(wv);
            wb[j] = q;
            ps += bf2f((uint32_t)q);
        }
        psum += ps;
        uint4 aq;
        aq.x = (uint32_t)wb[0] | ((uint32_t)wb[1] << 16);
        aq.y = (uint32_t)wb[2] | ((uint32_t)wb[3] << 16);
        aq.z = (uint32_t)wb[4] | ((uint32_t)wb[5] << 16);
        aq.w = (uint32_t)wb[6] | ((uint32_t)wb[7] << 16);
        bf16x8 af;
        *(uint4*)&af = aq;
#pragma unroll
        for (int nt = 0; nt < 4; ++nt) {
            bf16x8 bf;
            *(uint4*)&bf = b_cur[nt];
            acc[nt] = __builtin_amdgcn_mfma_f32_16x16x32_bf16(af, bf, acc[nt], 0, 0, 0);
        }
    }

    psum += __shfl_xor(psum, 16, 64);
    psum += __shfl_xor(psum, 32, 64);

#pragma unroll
    for (int nt = 0; nt < 4; ++nt) {
#pragma unroll
        for (int r = 0; r < 4; ++r) {
            int row = quad * 4 + r;
            float rs = __shfl(psum, row, 64);
            float val = acc[nt][r] / rs;
            attn_bf[((size_t)b * SS + m0 + row) * DD + h * HDD + nt * 16 + row16] = f2bf(val);
        }
    }
}

extern "C" void kernel_launch(void* const* d_in, const int* in_sizes, int n_in,
                              void* d_out, int out_size, void* d_ws, size_t ws_size,
                              hipStream_t stream)
{
    const float* hidden = (const float*)d_in[0];
    const int*   amask  = (const int*)d_in[1];
    const float* past_k = (const float*)d_in[2];
    const float* past_v = (const float*)d_in[3];
    const float* Wq = (const float*)d_in[4];
    const float* bq = (const float*)d_in[5];
    const float* Wk = (const float*)d_in[6];
    const float* bk = (const float*)d_in[7];
    const float* Wv = (const float*)d_in[8];
    const float* bv = (const float*)d_in[9];
    const float* Wo = (const float*)d_in[10];
    const float* bo = (const float*)d_in[11];

    float* out    = (float*)d_out;
    float* nk_out = out + (size_t)BB * SS * DD;
    float* nv_out = nk_out + (size_t)BB * HH * MEMM * HDD;

    char* base = (char*)d_ws;
    size_t off = 0;
    auto alloc = [&](size_t bytes) {
        char* p = base + off;
        off += (bytes + 255) & ~(size_t)255;
        return p;
    };
    ushort_t* hb    = (ushort_t*)alloc((size_t)BB * SS * DD * 2);            // 8 MB
    ushort_t* WtAll = (ushort_t*)alloc((size_t)4 * DD * DD * 2);             // 8 MB
    ushort_t* q_bf  = (ushort_t*)alloc((size_t)BB * HH * SS * HDD * 2);      // 8 MB
    ushort_t* kbf   = (ushort_t*)alloc((size_t)BB * HH * KTOT * HDD * 2);    // 10 MB
    ushort_t* vbf   = (ushort_t*)alloc((size_t)BB * HH * KTOT * HDD * 2);    // 10 MB
    ushort_t* vt    = (ushort_t*)alloc((size_t)BB * HH * HDD * KTOT * 2);    // 10 MB
    ushort_t* abf   = (ushort_t*)alloc((size_t)BB * SS * DD * 2);            // 8 MB
    float* thr_arr  = (float*)alloc((size_t)NROWS * 4);
    float* max_arr  = (float*)alloc((size_t)NROWS * 4);
    size_t fixed = off;
    const size_t sbuf_full = (size_t)BB * HH * SS * KTOT * 2;                // 335.5 MB
    int nchunks = 32;
    for (int c = 1; c <= 32; c <<= 1) {
        if (fixed + sbuf_full / c + 256 <= ws_size) { nchunks = c; break; }
    }
    ushort_t* sbuf = (ushort_t*)alloc(sbuf_full / nchunks);
    const int bhpc = (BB * HH) / nchunks;

    dim3 blk(256);

    cast_hidden_kernel<<<dim3(1024), blk, 0, stream>>>(hidden, hb);
    transw_kernel<<<dim3(16, 16, 4), blk, 0, stream>>>(Wq, Wk, Wv, Wo, WtAll);
    // fused QKV: one GEMM, N=3072 (Wq|Wk|Wv transposes adjacent in WtAll)
    gemm128_kernel<<<dim3(24, 32), blk, 0, stream>>>(
        hb, WtAll, 1, bq, bk, bv, nullptr, q_bf, kbf, vbf, nk_out, nv_out);
    cast_past_kernel<<<dim3(4096), blk, 0, stream>>>(past_k, past_v, kbf, vbf);
    transpose_v_kernel<<<dim3(KTOT / 64, BB * HH), blk, 0, stream>>>(vbf, vt);

    for (int ci = 0; ci < nchunks; ++ci) {
        int bh0 = ci * bhpc;
        score_kernel<<<dim3(KTOT / 256, SS / 64, bhpc), blk, 0, stream>>>(q_bf, kbf, sbuf, bh0);
        quant_kernel<<<dim3(bhpc * (SS / 4)), blk, 0, stream>>>(sbuf, thr_arr, max_arr, bh0);
        pv_kernel<<<dim3(SS / 64, bhpc), blk, 0, stream>>>(sbuf, vt, thr_arr, max_arr,
                                                           amask, abf, bh0);
    }
    // O-projection
    gemm128_kernel<<<dim3(8, 32), blk, 0, stream>>>(
        abf, WtAll + (size_t)3 * DD * DD, 0, bo, nullptr, nullptr, out,
        nullptr, nullptr, nullptr, nullptr, nullptr);
}

// Round 9
// 756.494 us; speedup vs baseline: 6.0307x; 1.0853x over previous
//
#include <hip/hip_runtime.h>
#include <stdint.h>

typedef unsigned short ushort_t;
typedef __attribute__((ext_vector_type(8))) short bf16x8;
typedef __attribute__((ext_vector_type(4))) float f32x4;

#define BB 2
#define SS 2048
#define DD 1024
#define HH 16
#define HDD 64
#define MEMM 512
#define KTOT 2560   // MEMM + SS
#define NROWS (BB*HH*SS)   // 65536 score rows

// ---------- helpers ----------
__device__ __forceinline__ float bf2f(uint32_t u) {
    return __uint_as_float(u << 16);
}
__device__ __forceinline__ ushort_t f2bf(float f) {
    uint32_t u = __float_as_uint(f);
    uint32_t r = (u + 0x7FFFu + ((u >> 16) & 1u)) >> 16;
    return (ushort_t)r;
}
__device__ __forceinline__ uint32_t mapkey(uint32_t u) {
    return (u & 0x8000u) ? (0xFFFFu ^ u) : (u | 0x8000u);
}
__device__ __forceinline__ uint32_t unmapkey(uint32_t k) {
    return (k & 0x8000u) ? (k ^ 0x8000u) : (0xFFFFu ^ k);
}

// ---------- cast hidden f32 -> bf16 ----------
__global__ __launch_bounds__(256) void cast_hidden_kernel(
    const float* __restrict__ h, ushort_t* __restrict__ hb)
{
    size_t i0 = ((size_t)blockIdx.x * 256 + threadIdx.x) * 16;  // 4M elems / 16
    ushort_t o[16];
#pragma unroll
    for (int j = 0; j < 4; ++j) {
        float4 v = *(const float4*)&h[i0 + j * 4];
        o[j * 4 + 0] = f2bf(v.x); o[j * 4 + 1] = f2bf(v.y);
        o[j * 4 + 2] = f2bf(v.z); o[j * 4 + 3] = f2bf(v.w);
    }
    *(uint4*)&hb[i0] = *(uint4*)&o[0];
    *(uint4*)&hb[i0 + 8] = *(uint4*)&o[8];
}

// ---------- transpose+cast weights: W[k][n] f32 -> Wt[n][k] bf16 ----------
__global__ __launch_bounds__(256) void transw_kernel(
    const float* __restrict__ Wq, const float* __restrict__ Wk,
    const float* __restrict__ Wv, const float* __restrict__ Wo,
    ushort_t* __restrict__ WtAll)
{
    __shared__ ushort_t T[64][66];
    const int z = blockIdx.z;
    const float* W = (z == 0) ? Wq : (z == 1) ? Wk : (z == 2) ? Wv : Wo;
    ushort_t* dst = WtAll + (size_t)z * DD * DD;
    const int k0 = blockIdx.x * 64, n0 = blockIdx.y * 64;
    const int t = threadIdx.x;
    const int kk = t >> 2, c4 = (t & 3) * 16;
#pragma unroll
    for (int j = 0; j < 4; ++j) {
        float4 v = *(const float4*)&W[(size_t)(k0 + kk) * DD + n0 + c4 + j * 4];
        T[kk][c4 + j * 4 + 0] = f2bf(v.x);
        T[kk][c4 + j * 4 + 1] = f2bf(v.y);
        T[kk][c4 + j * 4 + 2] = f2bf(v.z);
        T[kk][c4 + j * 4 + 3] = f2bf(v.w);
    }
    __syncthreads();
    const int nn = t >> 2, kc = (t & 3) * 16;
    ushort_t tmp[16];
#pragma unroll
    for (int j = 0; j < 16; ++j) tmp[j] = T[kc + j][nn];
    *(uint4*)&dst[(size_t)(n0 + nn) * DD + k0 + kc] = *(uint4*)&tmp[0];
    *(uint4*)&dst[(size_t)(n0 + nn) * DD + k0 + kc + 8] = *(uint4*)&tmp[8];
}

// ---------- 128x128-tile bf16 MFMA GEMM (m93-style LDS staging) ----------
__global__ __launch_bounds__(256) void gemm128_kernel(
    const ushort_t* __restrict__ A, const ushort_t* __restrict__ Bt, int mode,
    const float* __restrict__ bq, const float* __restrict__ bk, const float* __restrict__ bv,
    float* __restrict__ outf,
    ushort_t* __restrict__ q_bf, ushort_t* __restrict__ kbf, ushort_t* __restrict__ vbf,
    float* __restrict__ nk, float* __restrict__ nv)
{
    __shared__ __align__(16) ushort_t As[128 * 32];
    __shared__ __align__(16) ushort_t Bs[128 * 32];
    const int tid = threadIdx.x;
    const int lane = tid & 63, w = tid >> 6;
    const int wm = w >> 1, wn = w & 1;
    const int row16 = lane & 15, quad = lane >> 4;
    const int n0 = blockIdx.x * 128, m0 = blockIdx.y * 128;

    const int r0 = tid >> 2, c0 = (tid & 3) * 8;
    const int r1 = (tid + 256) >> 2, c1 = ((tid + 256) & 3) * 8;

    f32x4 acc[4][4];
#pragma unroll
    for (int i = 0; i < 4; ++i)
#pragma unroll
        for (int j = 0; j < 4; ++j) acc[i][j] = (f32x4){0.f, 0.f, 0.f, 0.f};

    for (int k0 = 0; k0 < DD; k0 += 32) {
        *(uint4*)&As[tid * 8]         = *(const uint4*)&A [(size_t)(m0 + r0) * DD + k0 + c0];
        *(uint4*)&As[(tid + 256) * 8] = *(const uint4*)&A [(size_t)(m0 + r1) * DD + k0 + c1];
        *(uint4*)&Bs[tid * 8]         = *(const uint4*)&Bt[(size_t)(n0 + r0) * DD + k0 + c0];
        *(uint4*)&Bs[(tid + 256) * 8] = *(const uint4*)&Bt[(size_t)(n0 + r1) * DD + k0 + c1];
        __syncthreads();
        bf16x8 af[4], bfr[4];
#pragma unroll
        for (int mt = 0; mt < 4; ++mt)
            af[mt] = *(const bf16x8*)&As[(wm * 64 + mt * 16 + row16) * 32 + quad * 8];
#pragma unroll
        for (int nt = 0; nt < 4; ++nt)
            bfr[nt] = *(const bf16x8*)&Bs[(wn * 64 + nt * 16 + row16) * 32 + quad * 8];
#pragma unroll
        for (int mt = 0; mt < 4; ++mt)
#pragma unroll
            for (int nt = 0; nt < 4; ++nt)
                acc[mt][nt] = __builtin_amdgcn_mfma_f32_16x16x32_bf16(
                    af[mt], bfr[nt], acc[mt][nt], 0, 0, 0);
        __syncthreads();
    }

#pragma unroll
    for (int nt = 0; nt < 4; ++nt) {
        const int nb = n0 + wn * 64 + nt * 16;       // tile-uniform
        if (mode == 0) {
#pragma unroll
            for (int mt = 0; mt < 4; ++mt) {
#pragma unroll
                for (int r = 0; r < 4; ++r) {
                    int m = m0 + wm * 64 + mt * 16 + quad * 4 + r;
                    int n = nb + row16;
                    outf[(size_t)m * DD + n] = acc[mt][nt][r] + bq[n];
                }
            }
        } else {
            const int sel = nb >> 10;
            const float* bias = (sel == 0) ? bq : (sel == 1) ? bk : bv;
#pragma unroll
            for (int mt = 0; mt < 4; ++mt) {
#pragma unroll
                for (int r = 0; r < 4; ++r) {
                    int m = m0 + wm * 64 + mt * 16 + quad * 4 + r;
                    int nn = (nb + row16) & 1023;
                    float v = acc[mt][nt][r] + bias[nn];
                    int b = m >> 11, s = m & (SS - 1);
                    int h = nn >> 6, d = nn & 63;
                    size_t bh = (size_t)b * HH + h;
                    if (sel == 0) {
                        q_bf[(bh * SS + s) * HDD + d] = f2bf(v);
                    } else {
                        ushort_t* dst = (sel == 1) ? kbf : vbf;
                        dst[(bh * KTOT + MEMM + s) * HDD + d] = f2bf(v);
                        if (s >= SS - MEMM) {
                            float* nf = (sel == 1) ? nk : nv;
                            nf[(bh * MEMM + (s - (SS - MEMM))) * HDD + d] = v;
                        }
                    }
                }
            }
        }
    }
}

// ---------- cast past_k/past_v f32 -> bf16 cache heads ----------
__global__ __launch_bounds__(256) void cast_past_kernel(
    const float* __restrict__ pk, const float* __restrict__ pv,
    ushort_t* __restrict__ kbf, ushort_t* __restrict__ vbf)
{
    int idx = blockIdx.x * 256 + threadIdx.x;  // BB*HH*MEMM*HDD = 1048576
    int bh = idx >> 15;
    int rem = idx & 32767;
    size_t dst = (size_t)bh * KTOT * HDD + rem;
    kbf[dst] = f2bf(pk[idx]);
    vbf[dst] = f2bf(pv[idx]);
}

// ---------- transpose V: vbf[bh][k][d] -> vt[bh][d][k] ----------
__global__ __launch_bounds__(256) void transpose_v_kernel(
    const ushort_t* __restrict__ vbf, ushort_t* __restrict__ vt)
{
    __shared__ ushort_t T[64][72];
    const int k0 = blockIdx.x * 64;
    const int bh = blockIdx.y;
    const int t = threadIdx.x;
    const int rr = t >> 3, cc = (t & 7) * 8;
#pragma unroll
    for (int p = 0; p < 2; ++p) {
        int kk = p * 32 + rr;
        *(uint4*)&T[kk][cc] =
            *(const uint4*)(vbf + ((size_t)bh * KTOT + k0 + kk) * HDD + cc);
    }
    __syncthreads();
#pragma unroll
    for (int p = 0; p < 2; ++p) {
        int d = p * 32 + rr;
        ushort_t tmp[8];
#pragma unroll
        for (int j = 0; j < 8; ++j) tmp[j] = T[cc + j][d];
        *(uint4*)(vt + ((size_t)bh * HDD + d) * KTOT + k0 + cc) = *(uint4*)tmp;
    }
}

// ---------- scores: MFMA (K prefetch), wave-private LDS transpose, ----------
// ---------- fully-contiguous stores, no barriers ----------
__global__ __launch_bounds__(256) void score_kernel(
    const ushort_t* __restrict__ qbf, const ushort_t* __restrict__ kbf,
    ushort_t* __restrict__ sbuf, int bh0)
{
    __shared__ __align__(16) ushort_t Ts[64][264];
    const int w = threadIdx.x >> 6, lane = threadIdx.x & 63;
    const int kt = blockIdx.x, qt = blockIdx.y;
    const int lbh = blockIdx.z, bh = bh0 + lbh;
    const int m0 = qt * 64 + w * 16;
    const int row16 = lane & 15, quad = lane >> 4;

    const ushort_t* qrow = qbf + ((size_t)bh * SS + m0 + row16) * HDD + quad * 8;
    bf16x8 a0 = *(const bf16x8*)qrow;
    bf16x8 a1 = *(const bf16x8*)(qrow + 32);
    const ushort_t* kbase = kbf + ((size_t)bh * KTOT + kt * 256 + row16) * HDD + quad * 8;

    bf16x8 b0c = *(const bf16x8*)kbase;
    bf16x8 b1c = *(const bf16x8*)(kbase + 32);
#pragma unroll
    for (int nt = 0; nt < 16; ++nt) {
        bf16x8 b0n, b1n;
        if (nt < 15) {
            const ushort_t* kr = kbase + (size_t)(nt + 1) * 16 * HDD;
            b0n = *(const bf16x8*)kr;
            b1n = *(const bf16x8*)(kr + 32);
        }
        f32x4 acc = {0.f, 0.f, 0.f, 0.f};
        acc = __builtin_amdgcn_mfma_f32_16x16x32_bf16(a0, b0c, acc, 0, 0, 0);
        acc = __builtin_amdgcn_mfma_f32_16x16x32_bf16(a1, b1c, acc, 0, 0, 0);
#pragma unroll
        for (int r = 0; r < 4; ++r)
            Ts[w * 16 + quad * 4 + r][nt * 16 + row16] = f2bf(acc[r] * 0.125f);
        b0c = b0n; b1c = b1n;
    }
    // wave-private transpose readback: wave w only touches rows w*16..w*16+15,
    // which it alone wrote -> no __syncthreads needed (in-wave lgkmcnt ordering).
    // store: lanes 0-31 -> row (w*16+j*2), lanes 32-63 -> row (+1); each
    // instruction writes 2 x 512 B contiguous segments.
    const int cc = (lane & 31) * 8, rsel = lane >> 5;
    ushort_t* dstb = sbuf + ((size_t)lbh * SS + qt * 64) * KTOT + kt * 256;
#pragma unroll
    for (int j = 0; j < 8; ++j) {
        int r = w * 16 + j * 2 + rsel;
        *(uint4*)&dstb[(size_t)r * KTOT + cc] = *(const uint4*)&Ts[r][cc];
    }
}

// ---------- wave helpers ----------
__device__ __forceinline__ uint32_t wave_iscan(uint32_t x, int lane) {
#pragma unroll
    for (int d = 1; d < 64; d <<= 1) {
        uint32_t t = __shfl_up(x, d, 64);
        if (lane >= d) x += t;
    }
    return x;
}
__device__ __forceinline__ void select_from_counts(
    const uint32_t* c, uint32_t R, int lane, uint32_t* bin_out, uint32_t* rem_out)
{
    uint32_t s = c[0] + c[1] + c[2] + c[3];
    uint32_t incl = wave_iscan(s, lane);
    uint32_t excl = incl - s;
    uint64_t bal = __ballot(incl > R);
    int fl = __ffsll((unsigned long long)bal) - 1;
    uint32_t exf = __shfl(excl, fl, 64);
    uint32_t c0 = __shfl(c[0], fl, 64), c1 = __shfl(c[1], fl, 64);
    uint32_t c2 = __shfl(c[2], fl, 64), c3 = __shfl(c[3], fl, 64);
    uint32_t cc[4] = {c0, c1, c2, c3};
    uint32_t cum = exf, bin = fl * 4, rem = 0;
#pragma unroll
    for (int i = 0; i < 4; ++i) {
        if (cum + cc[i] > R) { bin = fl * 4 + i; rem = R - cum; break; }
        cum += cc[i];
    }
    *bin_out = bin;
    *rem_out = rem;
}

// ---------- per-row quantile (ranks 255,256) + rowmax ----------
// 1 wave per row, no barriers. Hot bins (|x| in [0.125,8)) in packed regs;
// cold keys (~8%) -> 4x-replicated LDS histogram (stride 260 words).
__global__ __launch_bounds__(256) void quant_kernel(
    const ushort_t* __restrict__ sbuf, float* __restrict__ thr_out,
    float* __restrict__ max_out, int bh0)
{
    __shared__ __align__(16) uint32_t hist[4][1040];   // [wave][replica*260 + bin]
    const int w = threadIdx.x >> 6, lane = threadIdx.x & 63;
    const int rep = lane >> 4;
    uint32_t* H = hist[w];
    const int lrow = blockIdx.x * 4 + w;
    const size_t grow = (size_t)bh0 * SS + lrow;
    const ushort_t* src = sbuf + (size_t)lrow * KTOT;

    uint32_t key[40];
    uint32_t maxkey = 0;
#pragma unroll
    for (int c = 0; c < 5; ++c) {
        uint4 p = *(const uint4*)(src + c * 512 + lane * 8);
        uint32_t u[8] = {p.x & 0xFFFFu, p.x >> 16, p.y & 0xFFFFu, p.y >> 16,
                         p.z & 0xFFFFu, p.z >> 16, p.w & 0xFFFFu, p.w >> 16};
#pragma unroll
        for (int j = 0; j < 8; ++j) {
            uint32_t k = mapkey(u[j]);
            key[c * 8 + j] = k;
            maxkey = max(maxkey, k);
        }
    }
#pragma unroll
    for (int d = 1; d < 64; d <<= 1)
        maxkey = max(maxkey, (uint32_t)__shfl_xor(maxkey, d, 64));

    const uint4 z4 = {0u, 0u, 0u, 0u};
#pragma unroll
    for (int i = 0; i < 4; ++i) *(uint4*)&H[lane * 4 + i * 256] = z4;
    if (lane < 4) *(uint4*)&H[1024 + lane * 4] = z4;
    __threadfence_block();

    uint32_t accN = 0u, accP = 0u;   // 3 x 10-bit fields each
#pragma unroll
    for (int i = 0; i < 40; ++i) {
        uint32_t k = key[i];
        uint32_t t = k >> 8;
        uint32_t iN = t - 0x3Fu;
        uint32_t iP = t - 0xBEu;
        bool hN = (iN <= 2u);
        bool hP = (iP <= 2u);
        accN += hN ? (1u << (min(iN, 3u) * 10u)) : 0u;
        accP += hP ? (1u << (min(iP, 3u) * 10u)) : 0u;
        if (!(hN || hP)) atomicAdd(&H[rep * 260 + t], 1u);
    }
    uint32_t hc[6];
    hc[0] = accN & 0x3FFu; hc[1] = (accN >> 10) & 0x3FFu; hc[2] = (accN >> 20) & 0x3FFu;
    hc[3] = accP & 0x3FFu; hc[4] = (accP >> 10) & 0x3FFu; hc[5] = (accP >> 20) & 0x3FFu;
#pragma unroll
    for (int j = 0; j < 6; ++j)
#pragma unroll
        for (int d = 1; d < 64; d <<= 1)
            hc[j] += (uint32_t)__shfl_xor(hc[j], d, 64);
    __threadfence_block();

    uint32_t c[4];
#pragma unroll
    for (int i = 0; i < 4; ++i)
        c[i] = H[lane * 4 + i] + H[260 + lane * 4 + i]
             + H[520 + lane * 4 + i] + H[780 + lane * 4 + i];
    c[3] += (lane == 15) ? hc[0] : 0u;
    c[0] += (lane == 16) ? hc[1] : 0u;
    c[1] += (lane == 16) ? hc[2] : 0u;
    c[2] += (lane == 47) ? hc[3] : 0u;
    c[3] += (lane == 47) ? hc[4] : 0u;
    c[0] += (lane == 48) ? hc[5] : 0u;

    uint32_t binA, remA, binB, remB;
    select_from_counts(c, 255u, lane, &binA, &remA);
    select_from_counts(c, 256u, lane, &binB, &remB);

#pragma unroll
    for (int i = 0; i < 4; ++i) *(uint4*)&H[lane * 4 + i * 256] = z4;
    if (lane < 4) *(uint4*)&H[1024 + lane * 4] = z4;
    __threadfence_block();
#pragma unroll
    for (int i = 0; i < 40; ++i) {
        uint32_t k = key[i];
        if ((k >> 8) == binA) atomicAdd(&H[rep * 260 + (k & 255u)], 1u);
    }
    __threadfence_block();
#pragma unroll
    for (int i = 0; i < 4; ++i)
        c[i] = H[lane * 4 + i] + H[260 + lane * 4 + i]
             + H[520 + lane * 4 + i] + H[780 + lane * 4 + i];
    uint32_t lowA, rA, lowB, rB;
    select_from_counts(c, remA, lane, &lowA, &rA);
    if (binB == binA) {
        select_from_counts(c, remB, lane, &lowB, &rB);
    } else {
#pragma unroll
        for (int i = 0; i < 4; ++i) *(uint4*)&H[lane * 4 + i * 256] = z4;
        if (lane < 4) *(uint4*)&H[1024 + lane * 4] = z4;
        __threadfence_block();
#pragma unroll
        for (int i = 0; i < 40; ++i) {
            uint32_t k = key[i];
            if ((k >> 8) == binB) atomicAdd(&H[rep * 260 + (k & 255u)], 1u);
        }
        __threadfence_block();
#pragma unroll
        for (int i = 0; i < 4; ++i)
            c[i] = H[lane * 4 + i] + H[260 + lane * 4 + i]
                 + H[520 + lane * 4 + i] + H[780 + lane * 4 + i];
        select_from_counts(c, remB, lane, &lowB, &rB);
    }

    if (lane == 0) {
        float thrA = bf2f(unmapkey((binA << 8) | lowA));
        float thrB = bf2f(unmapkey((binB << 8) | lowB));
        thr_out[grow] = thrA + 0.9f * (thrB - thrA);
        max_out[grow] = bf2f(unmapkey(maxkey));
    }
}

// ---------- softmax + PV, barrier-free: wave = 16-row stripe, no LDS ----------
__global__ __launch_bounds__(256) void pv_kernel(
    const ushort_t* __restrict__ sbuf, const ushort_t* __restrict__ vt,
    const float* __restrict__ thr_arr, const float* __restrict__ max_arr,
    const int* __restrict__ amask, ushort_t* __restrict__ attn_bf, int bh0)
{
    const int tid = threadIdx.x;
    const int lane = tid & 63, w = tid >> 6;
    const int row16 = lane & 15, quad = lane >> 4;
    const int qt = blockIdx.x;
    const int lbh = blockIdx.y, bh = bh0 + lbh;
    const int b = bh >> 4, h = bh & 15;
    const int m0 = qt * 64 + w * 16;     // this wave's first row

    const ushort_t* arow = sbuf + ((size_t)lbh * SS + m0 + row16) * KTOT + quad * 8;
    const ushort_t* brow = vt + ((size_t)bh * HDD + row16) * KTOT + quad * 8;
    const float thr = thr_arr[(size_t)bh * SS + m0 + row16];
    const float mx  = max_arr[(size_t)bh * SS + m0 + row16];
    const int* amq = amask + b * SS + quad * 8;   // + (k0 - MEMM) per step

    f32x4 acc[4];
#pragma unroll
    for (int i = 0; i < 4; ++i) acc[i] = (f32x4){0.f, 0.f, 0.f, 0.f};
    float psum = 0.f;

    uint4 a_nxt = *(const uint4*)arow;
    uint4 b_nxt[4];
#pragma unroll
    for (int nt = 0; nt < 4; ++nt)
        b_nxt[nt] = *(const uint4*)(brow + (size_t)nt * 16 * KTOT);
    int4 m_nxt0 = {1, 1, 1, 1}, m_nxt1 = {1, 1, 1, 1};

    for (int k0 = 0; k0 < KTOT; k0 += 32) {
        uint4 a_cur = a_nxt;
        uint4 b_cur[4] = {b_nxt[0], b_nxt[1], b_nxt[2], b_nxt[3]};
        int4 mc0 = m_nxt0, mc1 = m_nxt1;
        const int kn = k0 + 32;
        if (kn < KTOT) {
            a_nxt = *(const uint4*)(arow + kn);
#pragma unroll
            for (int nt = 0; nt < 4; ++nt)
                b_nxt[nt] = *(const uint4*)(brow + (size_t)nt * 16 * KTOT + kn);
            if (kn >= MEMM) {
                m_nxt0 = *(const int4*)(amq + kn - MEMM);
                m_nxt1 = *(const int4*)(amq + kn - MEMM + 4);
            }
        }
        uint32_t u[8] = {a_cur.x & 0xFFFFu, a_cur.x >> 16, a_cur.y & 0xFFFFu, a_cur.y >> 16,
                         a_cur.z & 0xFFFFu, a_cur.z >> 16, a_cur.w & 0xFFFFu, a_cur.w >> 16};
        int mm[8] = {mc0.x, mc0.y, mc0.z, mc0.w, mc1.x, mc1.y, mc1.z, mc1.w};
        const bool masked = (k0 >= MEMM);
        ushort_t wb[8];
        float ps = 0.f;
#pragma unroll
        for (int j = 0; j < 8; ++j) {
            float s = bf2f(u[j]);
            bool keep = (s >= thr);
            if (masked) keep = keep && (mm[j] != 0);
            float wv = keep ? __expf(s - mx) : 0.f;
            ushort_t q = f2bf(wv);
            wb[j] = q;
            ps += bf2f((uint32_t)q);
        }
        psum += ps;
        uint4 aq;
        aq.x = (uint32_t)wb[0] | ((uint32_t)wb[1] << 16);
        aq.y = (uint32_t)wb[2] | ((uint32_t)wb[3] << 16);
        aq.z = (uint32_t)wb[4] | ((uint32_t)wb[5] << 16);
        aq.w = (uint32_t)wb[6] | ((uint32_t)wb[7] << 16);
        bf16x8 af;
        *(uint4*)&af = aq;
#pragma unroll
        for (int nt = 0; nt < 4; ++nt) {
            bf16x8 bf;
            *(uint4*)&bf = b_cur[nt];
            acc[nt] = __builtin_amdgcn_mfma_f32_16x16x32_bf16(af, bf, acc[nt], 0, 0, 0);
        }
    }

    psum += __shfl_xor(psum, 16, 64);
    psum += __shfl_xor(psum, 32, 64);

#pragma unroll
    for (int nt = 0; nt < 4; ++nt) {
#pragma unroll
        for (int r = 0; r < 4; ++r) {
            int row = quad * 4 + r;
            float rs = __shfl(psum, row, 64);
            float val = acc[nt][r] / rs;
            attn_bf[((size_t)b * SS + m0 + row) * DD + h * HDD + nt * 16 + row16] = f2bf(val);
        }
    }
}

extern "C" void kernel_launch(void* const* d_in, const int* in_sizes, int n_in,
                              void* d_out, int out_size, void* d_ws, size_t ws_size,
                              hipStream_t stream)
{
    const float* hidden = (const float*)d_in[0];
    const int*   amask  = (const int*)d_in[1];
    const float* past_k = (const float*)d_in[2];
    const float* past_v = (const float*)d_in[3];
    const float* Wq = (const float*)d_in[4];
    const float* bq = (const float*)d_in[5];
    const float* Wk = (const float*)d_in[6];
    const float* bk = (const float*)d_in[7];
    const float* Wv = (const float*)d_in[8];
    const float* bv = (const float*)d_in[9];
    const float* Wo = (const float*)d_in[10];
    const float* bo = (const float*)d_in[11];

    float* out    = (float*)d_out;
    float* nk_out = out + (size_t)BB * SS * DD;
    float* nv_out = nk_out + (size_t)BB * HH * MEMM * HDD;

    char* base = (char*)d_ws;
    size_t off = 0;
    auto alloc = [&](size_t bytes) {
        char* p = base + off;
        off += (bytes + 255) & ~(size_t)255;
        return p;
    };
    ushort_t* hb    = (ushort_t*)alloc((size_t)BB * SS * DD * 2);            // 8 MB
    ushort_t* WtAll = (ushort_t*)alloc((size_t)4 * DD * DD * 2);             // 8 MB
    ushort_t* q_bf  = (ushort_t*)alloc((size_t)BB * HH * SS * HDD * 2);      // 8 MB
    ushort_t* kbf   = (ushort_t*)alloc((size_t)BB * HH * KTOT * HDD * 2);    // 10 MB
    ushort_t* vbf   = (ushort_t*)alloc((size_t)BB * HH * KTOT * HDD * 2);    // 10 MB
    ushort_t* vt    = (ushort_t*)alloc((size_t)BB * HH * HDD * KTOT * 2);    // 10 MB
    ushort_t* abf   = (ushort_t*)alloc((size_t)BB * SS * DD * 2);            // 8 MB
    float* thr_arr  = (float*)alloc((size_t)NROWS * 4);
    float* max_arr  = (float*)alloc((size_t)NROWS * 4);
    size_t fixed = off;
    const size_t sbuf_full = (size_t)BB * HH * SS * KTOT * 2;                // 335.5 MB
    int nchunks = 32;
    for (int c = 1; c <= 32; c <<= 1) {
        if (fixed + sbuf_full / c + 256 <= ws_size) { nchunks = c; break; }
    }
    ushort_t* sbuf = (ushort_t*)alloc(sbuf_full / nchunks);
    const int bhpc = (BB * HH) / nchunks;

    dim3 blk(256);

    cast_hidden_kernel<<<dim3(1024), blk, 0, stream>>>(hidden, hb);
    transw_kernel<<<dim3(16, 16, 4), blk, 0, stream>>>(Wq, Wk, Wv, Wo, WtAll);
    // fused QKV: one GEMM, N=3072 (Wq|Wk|Wv transposes adjacent in WtAll)
    gemm128_kernel<<<dim3(24, 32), blk, 0, stream>>>(
        hb, WtAll, 1, bq, bk, bv, nullptr, q_bf, kbf, vbf, nk_out, nv_out);
    cast_past_kernel<<<dim3(4096), blk, 0, stream>>>(past_k, past_v, kbf, vbf);
    transpose_v_kernel<<<dim3(KTOT / 64, BB * HH), blk, 0, stream>>>(vbf, vt);

    for (int ci = 0; ci < nchunks; ++ci) {
        int bh0 = ci * bhpc;
        score_kernel<<<dim3(KTOT / 256, SS / 64, bhpc), blk, 0, stream>>>(q_bf, kbf, sbuf, bh0);
        quant_kernel<<<dim3(bhpc * (SS / 4)), blk, 0, stream>>>(sbuf, thr_arr, max_arr, bh0);
        pv_kernel<<<dim3(SS / 64, bhpc), blk, 0, stream>>>(sbuf, vt, thr_arr, max_arr,
                                                           amask, abf, bh0);
    }
    // O-projection
    gemm128_kernel<<<dim3(8, 32), blk, 0, stream>>>(
        abf, WtAll + (size_t)3 * DD * DD, 0, bo, nullptr, nullptr, out,
        nullptr, nullptr, nullptr, nullptr, nullptr);
}